// Round 16
// baseline (211.554 us; speedup 1.0000x reference)
//
#include <hip/hip_runtime.h>
#include <cstdint>
#include <cstddef>

// Problem constants (from reference)
#define NN 50000
#define NE 800000
#define FIN 256
#define HD 128
#define NEG_SLOPE 0.2f

// CSR-build binning parameters
#define NBK 196          // buckets of 256 nodes: ceil(50000/256)
#define NCH 98           // edge chunks
#define NCHP 104         // padded chunk count (mult of 4 for int4 scan)
#define CHUNK 8192       // edges per chunk (98*8192 >= 800000)

typedef short s16x8 __attribute__((ext_vector_type(8)));   // 8 bf16 (4 VGPRs)
typedef float f32x4 __attribute__((ext_vector_type(4)));   // MFMA accumulator

__device__ inline ushort f2bf(float f) {                   // fp32 -> bf16 RTN-even
    uint32_t u = __float_as_uint(f);
    u += 0x7FFFu + ((u >> 16) & 1u);
    return (ushort)(u >> 16);
}
__device__ inline float bf2f(ushort h) {
    return __uint_as_float(((uint32_t)h) << 16);
}

// ------------------------------------------------------------- CSR build
// bucket = dst >> 8. No global atomics anywhere.

__global__ __launch_bounds__(1024) void k_bhist(const int* __restrict__ dst,
                                                int* __restrict__ bhist) {
    __shared__ int hist[NBK];
    const int tid = threadIdx.x, blk = blockIdx.x;
    if (tid < NBK) hist[tid] = 0;
    __syncthreads();
    const int e0 = blk * CHUNK;
    #pragma unroll
    for (int u = 0; u < CHUNK / 1024; ++u) {
        int e = e0 + u * 1024 + tid;
        if (e < NE) atomicAdd(&hist[dst[e] >> 8], 1);
    }
    __syncthreads();
    if (tid < NBK) {
        bhist[tid * NCHP + blk] = hist[tid];
        if (blk == 0)                          // zero the scan padding once
            for (int c = NCH; c < NCHP; ++c) bhist[tid * NCHP + c] = 0;
    }
}

__global__ __launch_bounds__(256) void k_bscan(int* __restrict__ bhist,
                                               int* __restrict__ bbeg,
                                               int* __restrict__ row_ptr) {
    __shared__ int wsum[4];
    const int tid = threadIdx.x;
    int4 buf[NCHP / 4];
    int tot = 0;
    if (tid < NBK) {
        const int4* rp = reinterpret_cast<const int4*>(bhist + tid * NCHP);
        #pragma unroll
        for (int u = 0; u < NCHP / 4; ++u) buf[u] = rp[u];     // independent loads
        #pragma unroll
        for (int u = 0; u < NCHP / 4; ++u) {                   // exclusive scan in regs
            int4 v = buf[u], o;
            o.x = tot; tot += v.x;
            o.y = tot; tot += v.y;
            o.z = tot; tot += v.z;
            o.w = tot; tot += v.w;
            buf[u] = o;
        }
    }
    const int lane = tid & 63, wid = tid >> 6;
    int x = tot;
    #pragma unroll
    for (int o = 1; o < 64; o <<= 1) {
        int t = __shfl_up(x, o);
        if (lane >= o) x += t;
    }
    if (lane == 63) wsum[wid] = x;
    __syncthreads();
    int wo = 0;
    for (int k = 0; k < wid; ++k) wo += wsum[k];
    const int excl = x - tot + wo;                // bucket start offset
    if (tid < NBK) {
        bbeg[tid] = excl;
        int4* rp = reinterpret_cast<int4*>(bhist + tid * NCHP);
        #pragma unroll
        for (int u = 0; u < NCHP / 4; ++u) {
            int4 v = buf[u];
            v.x += excl; v.y += excl; v.z += excl; v.w += excl;
            rp[u] = v;
        }
    }
    if (tid == 0) { bbeg[NBK] = NE; row_ptr[NN] = NE; }
}

__global__ __launch_bounds__(1024) void k_binscatter(const int* __restrict__ src,
                                                     const int* __restrict__ dst,
                                                     const float* __restrict__ ew,
                                                     const int* __restrict__ bhist,
                                                     uint2* __restrict__ epk) {
    __shared__ int base[NBK];
    __shared__ int lcur[NBK];
    const int tid = threadIdx.x, blk = blockIdx.x;
    if (tid < NBK) { base[tid] = bhist[tid * NCHP + blk]; lcur[tid] = 0; }
    __syncthreads();
    const int e0 = blk * CHUNK;
    #pragma unroll
    for (int u = 0; u < CHUNK / 1024; ++u) {
        int e = e0 + u * 1024 + tid;
        if (e < NE) {
            int d = dst[e];
            int s = src[e];
            float w = ew[e];
            int b = d >> 8;
            int pos = base[b] + atomicAdd(&lcur[b], 1);   // LDS atomic only
            epk[pos] = make_uint2((uint32_t)s | ((uint32_t)(d & 255) << 16),
                                  __float_as_uint(w));
        }
    }
}

__global__ __launch_bounds__(256) void k_build(const uint2* __restrict__ epk,
                                               const int* __restrict__ bbeg,
                                               int* __restrict__ row_ptr,
                                               unsigned int* __restrict__ cw) {
    __shared__ int cnt[256];
    __shared__ int cur[256];
    __shared__ int wsum[4];
    const int tid = threadIdx.x, b = blockIdx.x;
    const int n0 = b << 8;
    const int ebeg = bbeg[b], eend = bbeg[b + 1];
    cnt[tid] = 0;
    __syncthreads();
    for (int e = ebeg + tid; e < eend; e += 256)
        atomicAdd(&cnt[(epk[e].x >> 16) & 255], 1);
    __syncthreads();
    const int v = cnt[tid];
    const int lane = tid & 63, wid = tid >> 6;
    int x = v;
    #pragma unroll
    for (int o = 1; o < 64; o <<= 1) {
        int t = __shfl_up(x, o);
        if (lane >= o) x += t;
    }
    if (lane == 63) wsum[wid] = x;
    __syncthreads();
    int wo = 0;
    for (int k = 0; k < wid; ++k) wo += wsum[k];
    const int excl = ebeg + x - v + wo;           // node segment start
    if (n0 + tid < NN) row_ptr[n0 + tid] = excl;
    cur[tid] = excl;
    __syncthreads();
    for (int e = ebeg + tid; e < eend; e += 256) {
        uint2 p = epk[e];
        int dl = (p.x >> 16) & 255;
        int pos = atomicAdd(&cur[dl], 1);
        // packed edge: low16 = src, high16 = bf16(edge_weight)
        cw[pos] = (p.x & 0xFFFFu) |
                  ((unsigned int)f2bf(__uint_as_float(p.y)) << 16);
    }
}

// -------------------------------------- fused weight transpose + bf16 split

__global__ void k_split_all(const float* __restrict__ Wlin,
                            const float* __restrict__ Wc,
                            ushort* __restrict__ Th, ushort* __restrict__ Tl) {
    int idx = blockIdx.x * blockDim.x + threadIdx.x;
    const int NLIN = HD * FIN;
    float f;
    if (idx < NLIN) {
        int n = idx / FIN, k = idx - n * FIN;
        f = Wlin[(size_t)k * HD + n];
    } else if (idx < NLIN + 3 * HD * HD) {
        int r = idx - NLIN;
        int l = r / (HD * HD);
        int rr = r - l * (HD * HD);
        int n = rr / HD, k = rr - n * HD;
        f = Wc[(size_t)l * HD * HD + (size_t)k * HD + n];
    } else return;
    ushort hi = f2bf(f);
    Th[idx] = hi;
    Tl[idx] = f2bf(f - bf2f(hi));
}

// ----------------------------------------------------- MFMA split-bf16 GEMM
// C[M][128] = A[M][K] @ B[K][128] (+bias), 16x16x32 bf16 MFMA.
// ABF16=false: A fp32, split hi/lo in-flight (3 MFMA). ABF16=true: A bf16
// exact (2 MFMA). OUT8=false: bf16 out. OUT8=true: uint8 per-row-scaled out
// (u = rint(val*127/rowmax) + 128, u in [1,255] -> enables v_cvt_f32_ubyte
// single-op unpack in k_agg) + sig[row] = rowmax/127; as_/ad_ exact.
// B^T hi/lo whole-BK=128 K-tile staged once into 64 KB LDS (XOR-swizzled),
// barrier-free main loop, 4 waves x 32 rows, grid 391.

template <int K, bool ATT, bool ABF16, bool OUT8>
__global__ __launch_bounds__(256) void k_gemm_mfma(
    const float*  __restrict__ Af,     // fp32 A (ABF16=false)
    const ushort* __restrict__ Ab,     // bf16 A (ABF16=true)
    const ushort* __restrict__ Bh,     // [HD][K]
    const ushort* __restrict__ Bl,     // [HD][K]
    const float*  __restrict__ bias,   // null if none
    ushort*       __restrict__ Cb,     // bf16 out (OUT8=false)
    unsigned char* __restrict__ C8,    // uint8 out (OUT8=true)
    float*        __restrict__ sig,    // per-row scale (OUT8=true)
    const float*  __restrict__ att_s, const float* __restrict__ att_d,
    float* __restrict__ as_, float* __restrict__ ad_,
    int M)
{
    constexpr int BK = 128;
    constexpr int NT = K / BK;
    __shared__ ushort Bs[32768];                  // 64 KB: hi [0..16383], lo +16384

    const int tid  = threadIdx.x;
    const int lane = tid & 63;
    const int wid  = tid >> 6;
    const int fl   = lane & 15;
    const int fg   = lane >> 4;
    const int rowBase = blockIdx.x * 128 + wid * 32;

    f32x4 acc[2][8] = {};

    for (int t = 0; t < NT; ++t) {
        if (t) __syncthreads();
        #pragma unroll
        for (int u = 0; u < 8; ++u) {
            const int id  = u * 256 + tid;
            const int bcol = id >> 4, c = id & 15;
            const size_t g = (size_t)bcol * K + t * BK + c * 8;
            const int lidx = bcol * 128 + ((c ^ (bcol & 15)) << 3);
            *reinterpret_cast<uint4*>(&Bs[lidx]) =
                *reinterpret_cast<const uint4*>(Bh + g);
            *reinterpret_cast<uint4*>(&Bs[16384 + lidx]) =
                *reinterpret_cast<const uint4*>(Bl + g);
        }
        __syncthreads();

        #pragma unroll
        for (int kt = 0; kt < BK / 32; ++kt) {
            s16x8 a_h[2], a_l[2];
            #pragma unroll
            for (int rt = 0; rt < 2; ++rt) {
                int r = rowBase + rt * 16 + fl;
                if (r >= M) r = M - 1;            // harmless clamp (stores guarded)
                if (ABF16) {
                    a_h[rt] = *reinterpret_cast<const s16x8*>(
                        Ab + (size_t)r * K + t * BK + kt * 32 + fg * 8);
                } else {
                    const float* ap = Af + (size_t)r * K + t * BK + kt * 32 + fg * 8;
                    float4 t0 = *reinterpret_cast<const float4*>(ap);
                    float4 t1 = *reinterpret_cast<const float4*>(ap + 4);
                    float v[8] = {t0.x, t0.y, t0.z, t0.w, t1.x, t1.y, t1.z, t1.w};
                    #pragma unroll
                    for (int u = 0; u < 8; ++u) {
                        ushort h0 = f2bf(v[u]);
                        a_h[rt][u] = (short)h0;
                        a_l[rt][u] = (short)f2bf(v[u] - bf2f(h0));
                    }
                }
            }
            #pragma unroll
            for (int ct = 0; ct < 8; ++ct) {
                const int lidx = (ct * 16 + fl) * 128 + (((kt * 4 + fg) ^ fl) << 3);
                s16x8 b_h = *reinterpret_cast<const s16x8*>(&Bs[lidx]);
                s16x8 b_l = *reinterpret_cast<const s16x8*>(&Bs[16384 + lidx]);
                #pragma unroll
                for (int rt = 0; rt < 2; ++rt) {
                    acc[rt][ct] = __builtin_amdgcn_mfma_f32_16x16x32_bf16(a_h[rt], b_h, acc[rt][ct], 0, 0, 0);
                    acc[rt][ct] = __builtin_amdgcn_mfma_f32_16x16x32_bf16(a_h[rt], b_l, acc[rt][ct], 0, 0, 0);
                    if (!ABF16)
                        acc[rt][ct] = __builtin_amdgcn_mfma_f32_16x16x32_bf16(a_l[rt], b_h, acc[rt][ct], 0, 0, 0);
                }
            }
        }
    }

    // ---- epilogue: C/D layout col = ct*16 + fl, row = base + fg*4 + reg ----
    float bval[8];
    #pragma unroll
    for (int ct = 0; ct < 8; ++ct) bval[ct] = bias ? bias[ct * 16 + fl] : 0.f;
    float asv[8], adv[8];
    if (ATT) {
        #pragma unroll
        for (int ct = 0; ct < 8; ++ct) {
            asv[ct] = att_s[ct * 16 + fl];
            adv[ct] = att_d[ct * 16 + fl];
        }
    }

    #pragma unroll
    for (int rt = 0; rt < 2; ++rt) {
        const int rbase = rowBase + rt * 16 + fg * 4;
        #pragma unroll
        for (int r = 0; r < 4; ++r) {
            const int row = rbase + r;
            const bool ok = row < M;
            float sv = 0.f, dv = 0.f, m = 0.f;
            float val[8];
            #pragma unroll
            for (int ct = 0; ct < 8; ++ct) {
                val[ct] = acc[rt][ct][r] + bval[ct];
                if (ATT) { sv = fmaf(val[ct], asv[ct], sv); dv = fmaf(val[ct], adv[ct], dv); }
                if (OUT8) m = fmaxf(m, fabsf(val[ct]));
            }
            if (OUT8) {
                #pragma unroll
                for (int o = 1; o < 16; o <<= 1) m = fmaxf(m, __shfl_xor(m, o));
                const float qs = 127.f / fmaxf(m, 1e-30f);
                #pragma unroll
                for (int ct = 0; ct < 8; ++ct) {
                    int qv = (int)rintf(val[ct] * qs);
                    qv = qv < -127 ? -127 : (qv > 127 ? 127 : qv);
                    if (ok) C8[(size_t)row * HD + ct * 16 + fl] =
                        (unsigned char)(qv + 128);           // biased uint8
                }
                if (fl == 0 && ok) sig[row] = m * (1.f / 127.f);
            } else {
                #pragma unroll
                for (int ct = 0; ct < 8; ++ct)
                    if (ok) Cb[(size_t)row * HD + ct * 16 + fl] = f2bf(val[ct]);
            }
            if (ATT) {
                #pragma unroll
                for (int o = 1; o < 16; o <<= 1) {
                    sv += __shfl_xor(sv, o);
                    dv += __shfl_xor(dv, o);
                }
                if (fl == 0 && ok) { as_[row] = sv; ad_[row] = dv; }
            }
        }
    }
}

// ---------------------------------------------- fused softmax-aggregation
// One wave per node. hp is uint8 per-row-scaled, biased +128 (128 B/row);
// the unpack pattern (float)((v>>N)&0xFF) lowers to single v_cvt_f32_ubyteN.
// Bias removed exactly after reduction: acc_true = acc - 128 * sum(we).
// Row scale folded into broadcast weight (we = w * sig[src]); denominator
// uses raw w -> softmax semantics exact. Lane owns 8 features (uint2),
// 16 lanes/row, 4 wave quarters process 4 edges per load (16 in flight).
// mode 0: h += agg (no out). mode 1: mx = bf16(max(h_old, h_new)), h += agg.
// mode 2: out = max(bf2f(mx), agg + b)  (write-only out).

__device__ inline void acc8u(float wj, uint2 pv,
                             float& a0, float& a1, float& a2, float& a3,
                             float& a4, float& a5, float& a6, float& a7) {
    a0 = fmaf(wj, (float)( pv.x        & 0xFFu), a0);   // v_cvt_f32_ubyte0
    a1 = fmaf(wj, (float)((pv.x >>  8) & 0xFFu), a1);   // v_cvt_f32_ubyte1
    a2 = fmaf(wj, (float)((pv.x >> 16) & 0xFFu), a2);   // v_cvt_f32_ubyte2
    a3 = fmaf(wj, (float)( pv.x >> 24         ), a3);   // v_cvt_f32_ubyte3
    a4 = fmaf(wj, (float)( pv.y        & 0xFFu), a4);
    a5 = fmaf(wj, (float)((pv.y >>  8) & 0xFFu), a5);
    a6 = fmaf(wj, (float)((pv.y >> 16) & 0xFFu), a6);
    a7 = fmaf(wj, (float)( pv.y >> 24         ), a7);
}

__global__ __launch_bounds__(256) void k_agg(const unsigned char* __restrict__ hp8,
                                             const float* __restrict__ sig,
                                             ushort* __restrict__ hb,
                                             const float* __restrict__ as_,
                                             const float* __restrict__ ad_,
                                             const int* __restrict__ row_ptr,
                                             const unsigned int* __restrict__ cw,
                                             const float* __restrict__ bias,
                                             float* __restrict__ out,
                                             ushort* __restrict__ mx, int mode) {
    int wave = (blockIdx.x * blockDim.x + threadIdx.x) >> 6;
    int lane = threadIdx.x & 63;
    if (wave >= NN) return;
    const int d = wave;
    const int beg = row_ptr[d], end = row_ptr[d + 1];
    const float adv = ad_[d];
    const int q  = lane >> 4;          // which of 4 concurrent edges
    const int hl = lane & 15;          // feature octet: owns [hl*8, hl*8+8)

    float a0 = 0.f, a1 = 0.f, a2 = 0.f, a3 = 0.f;
    float a4 = 0.f, a5 = 0.f, a6 = 0.f, a7 = 0.f;
    float dloc = 0.f, wesum = 0.f;

    for (int base = beg; base < end; base += 64) {
        const int n = min(64, end - base);
        int s = 0; float w = 0.f, we = 0.f;
        if (lane < n) {
            unsigned int v = cw[base + lane];
            s = (int)(v & 0xFFFFu);
            float l = as_[s] + adv;
            l = (l >= 0.f) ? l : NEG_SLOPE * l;
            l = fminf(l, 80.f);                    // overflow guard (no max pass)
            w  = __expf(l) * bf2f((ushort)(v >> 16));
            we = w * sig[s];                       // fold row scale into weight
        }
        dloc += w;

        int i = 0;
        for (; i + 15 < n; i += 16) {          // 16 edges = 4 quad loads in flight
            float wv[4]; int sv[4]; uint2 pv[4];
            #pragma unroll
            for (int j = 0; j < 4; ++j) {
                const int idx = i + 4 * j + q;
                wv[j] = __shfl(we, idx);
                sv[j] = __shfl(s,  idx);
            }
            #pragma unroll
            for (int j = 0; j < 4; ++j)
                pv[j] = *reinterpret_cast<const uint2*>(hp8 + (size_t)sv[j] * HD + hl * 8);
            #pragma unroll
            for (int j = 0; j < 4; ++j) {
                acc8u(wv[j], pv[j], a0, a1, a2, a3, a4, a5, a6, a7);
                wesum += wv[j];
            }
        }
        for (; i + 3 < n; i += 4) {            // 4-edge steps
            const int idx = i + q;
            float wj = __shfl(we, idx);
            int   sj = __shfl(s,  idx);
            uint2 pv = *reinterpret_cast<const uint2*>(hp8 + (size_t)sj * HD + hl * 8);
            acc8u(wj, pv, a0, a1, a2, a3, a4, a5, a6, a7);
            wesum += wj;
        }
        if (i < n) {                           // tail < 4 edges (masked)
            const int e = i + q;
            const bool ok = e < n;
            const int idx = ok ? e : i;
            float wj = __shfl(we, idx);
            int   sj = __shfl(s,  idx);
            if (!ok) wj = 0.f;
            uint2 pv = *reinterpret_cast<const uint2*>(hp8 + (size_t)sj * HD + hl * 8);
            acc8u(wj, pv, a0, a1, a2, a3, a4, a5, a6, a7);
            wesum += wj;
        }
    }
    #pragma unroll
    for (int o = 32; o > 0; o >>= 1) dloc += __shfl_xor(dloc, o);
    #pragma unroll
    for (int o = 32; o >= 16; o >>= 1) {
        a0 += __shfl_xor(a0, o); a1 += __shfl_xor(a1, o);
        a2 += __shfl_xor(a2, o); a3 += __shfl_xor(a3, o);
        a4 += __shfl_xor(a4, o); a5 += __shfl_xor(a5, o);
        a6 += __shfl_xor(a6, o); a7 += __shfl_xor(a7, o);
        wesum += __shfl_xor(wesum, o);
    }

    if (q != 0) return;                        // lanes 0-15 do the stores
    const float c = 128.f * wesum;             // remove the +128 bias exactly
    const float inv = 1.f / (dloc + 1e-16f);
    const int f0 = hl * 8;
    float r0 = (a0 - c) * inv + bias[f0 + 0], r1 = (a1 - c) * inv + bias[f0 + 1];
    float r2 = (a2 - c) * inv + bias[f0 + 2], r3 = (a3 - c) * inv + bias[f0 + 3];
    float r4 = (a4 - c) * inv + bias[f0 + 4], r5 = (a5 - c) * inv + bias[f0 + 5];
    float r6 = (a6 - c) * inv + bias[f0 + 6], r7 = (a7 - c) * inv + bias[f0 + 7];

    if (mode == 2) {
        uint4 mv = *reinterpret_cast<const uint4*>(mx + (size_t)d * HD + f0);
        float4 o0, o1;
        o0.x = fmaxf(bf2f((ushort)mv.x),         r0);
        o0.y = fmaxf(bf2f((ushort)(mv.x >> 16)), r1);
        o0.z = fmaxf(bf2f((ushort)mv.y),         r2);
        o0.w = fmaxf(bf2f((ushort)(mv.y >> 16)), r3);
        o1.x = fmaxf(bf2f((ushort)mv.z),         r4);
        o1.y = fmaxf(bf2f((ushort)(mv.z >> 16)), r5);
        o1.z = fmaxf(bf2f((ushort)mv.w),         r6);
        o1.w = fmaxf(bf2f((ushort)(mv.w >> 16)), r7);
        float4* outp = reinterpret_cast<float4*>(out + (size_t)d * HD + f0);
        outp[0] = o0; outp[1] = o1;            // write-only full overwrite
    } else {
        uint4* hp = reinterpret_cast<uint4*>(hb + (size_t)d * HD + f0);
        uint4 hv = *hp;
        float h0 = bf2f((ushort)hv.x), h1 = bf2f((ushort)(hv.x >> 16));
        float h2 = bf2f((ushort)hv.y), h3 = bf2f((ushort)(hv.y >> 16));
        float h4 = bf2f((ushort)hv.z), h5 = bf2f((ushort)(hv.z >> 16));
        float h6 = bf2f((ushort)hv.w), h7 = bf2f((ushort)(hv.w >> 16));
        float n0 = h0 + r0, n1 = h1 + r1, n2 = h2 + r2, n3 = h3 + r3;
        float n4 = h4 + r4, n5 = h5 + r5, n6 = h6 + r6, n7 = h7 + r7;
        uint4 st;
        st.x = (uint32_t)f2bf(n0) | ((uint32_t)f2bf(n1) << 16);
        st.y = (uint32_t)f2bf(n2) | ((uint32_t)f2bf(n3) << 16);
        st.z = (uint32_t)f2bf(n4) | ((uint32_t)f2bf(n5) << 16);
        st.w = (uint32_t)f2bf(n6) | ((uint32_t)f2bf(n7) << 16);
        *hp = st;
        if (mode == 1) {                        // mx = bf16(max(h1, h2))
            uint4 sm;
            sm.x = (uint32_t)f2bf(fmaxf(h0, n0)) | ((uint32_t)f2bf(fmaxf(h1, n1)) << 16);
            sm.y = (uint32_t)f2bf(fmaxf(h2, n2)) | ((uint32_t)f2bf(fmaxf(h3, n3)) << 16);
            sm.z = (uint32_t)f2bf(fmaxf(h4, n4)) | ((uint32_t)f2bf(fmaxf(h5, n5)) << 16);
            sm.w = (uint32_t)f2bf(fmaxf(h6, n6)) | ((uint32_t)f2bf(fmaxf(h7, n7)) << 16);
            *reinterpret_cast<uint4*>(mx + (size_t)d * HD + f0) = sm;
        }
    }
}

// ---------------------------------------------------------------- launch

extern "C" void kernel_launch(void* const* d_in, const int* in_sizes, int n_in,
                              void* d_out, int out_size, void* d_ws, size_t ws_size,
                              hipStream_t stream) {
    const float* x        = (const float*)d_in[0];          // [NN][FIN]
    const int*   ei       = (const int*)d_in[1];            // [2][NE]
    const float* ew       = (const float*)d_in[2];          // [NE]
    /* d_in[3] = numNode scalar = NN */
    const float* Wlin     = (const float*)d_in[4];          // [FIN][HD]
    const float* blin     = (const float*)d_in[5];          // [HD]
    const float* Wc       = (const float*)d_in[6];          // [3][HD][HD]
    const float* att_src  = (const float*)d_in[7];          // [3][HD]
    const float* att_dst  = (const float*)d_in[8];          // [3][HD]
    const float* bias_c   = (const float*)d_in[9];          // [3][HD]
    float* out = (float*)d_out;                              // [NN][HD]

    const int* src = ei;
    const int* dst = ei + NE;

    // workspace layout (16B-aligned blocks, ~44 MB)
    char* w = (char*)d_ws;
    ushort* hb      = (ushort*)w;  w += (size_t)NN * HD * 2;   // h residual (bf16)
    unsigned char* hp8 = (unsigned char*)w; w += (size_t)NN * HD; // hp (uint8 scaled)
    float*  sig     = (float*)w;   w += (size_t)NN * 4;        // per-row scale
    ushort* mx      = (ushort*)w;  w += (size_t)NN * HD * 2;   // running max (bf16)
    float*  as_     = (float*)w;   w += (size_t)NN * 4;
    float*  ad_     = (float*)w;   w += (size_t)NN * 4;
    int*    row_ptr = (int*)w;     w += (size_t)(NN + 4) * 4;
    unsigned int* cw = (unsigned int*)w; w += (size_t)NE * 4;  // packed col|bf16(ew)
    uint2*  epk     = (uint2*)w;   w += (size_t)NE * 8;
    int*    bhist   = (int*)w;     w += (size_t)NBK * NCHP * 4;
    int*    bbeg    = (int*)w;     w += (size_t)(NBK + 4) * 4;
    ushort* WTh     = (ushort*)w;  w += (size_t)(HD * FIN + 3 * HD * HD) * 2;
    ushort* WTl     = (ushort*)w;  w += (size_t)(HD * FIN + 3 * HD * HD) * 2;
    ushort* WlinTh = WTh,            *WlinTl = WTl;
    ushort* WcTh   = WTh + HD * FIN, *WcTl   = WTl + HD * FIN;

    const int TB = 256;
    const int nblk_w = (NN * 64 + TB - 1) / TB;      // one wave per node
    const int nblk_g = (NN + 127) / 128;             // 391 (128 rows per block)
    const int nsplit = HD * FIN + 3 * HD * HD;       // all weight elements

    // ---- fused weight transpose + split (1 launch) ----
    k_split_all<<<(nsplit + TB - 1) / TB, TB, 0, stream>>>(Wlin, Wc, WTh, WTl);

    // ---- CSR build (atomic-reservation-free binning) ----
    k_bhist<<<NCH, 1024, 0, stream>>>(dst, bhist);
    k_bscan<<<1, 256, 0, stream>>>(bhist, bbeg, row_ptr);
    k_binscatter<<<NCH, 1024, 0, stream>>>(src, dst, ew, bhist, epk);
    k_build<<<NBK, 256, 0, stream>>>(epk, bbeg, row_ptr, cw);

    // ---- input projection: h = x @ Wlin + blin (bf16 out, fp32 A split) ----
    k_gemm_mfma<FIN, false, false, false><<<nblk_g, TB, 0, stream>>>(
        x, nullptr, WlinTh, WlinTl, blin, hb, nullptr, nullptr,
        nullptr, nullptr, nullptr, nullptr, NN);

    // ---- 3 GAT layers (A = h bf16 exact -> 2-MFMA path; hp emitted uint8) ----
    for (int layer = 0; layer < 3; ++layer) {
        k_gemm_mfma<HD, true, true, true><<<nblk_g, TB, 0, stream>>>(
            nullptr, hb, WcTh + (size_t)layer * HD * HD, WcTl + (size_t)layer * HD * HD,
            nullptr, nullptr, hp8, sig,
            att_src + layer * HD, att_dst + layer * HD, as_, ad_, NN);
        int mode = (layer == 0) ? 0 : (layer == 2 ? 2 : 1);
        k_agg<<<nblk_w, TB, 0, stream>>>(hp8, sig, hb, as_, ad_, row_ptr, cw,
                                         bias_c + layer * HD, out, mx, mode);
    }
}

// Round 17
// 201.778 us; speedup vs baseline: 1.0485x; 1.0485x over previous
//
#include <hip/hip_runtime.h>
#include <cstdint>
#include <cstddef>

// Problem constants (from reference)
#define NN 50000
#define NE 800000
#define FIN 256
#define HD 128
#define NEG_SLOPE 0.2f

// CSR-build binning parameters
#define NBK 196          // buckets of 256 nodes: ceil(50000/256)
#define NCH 98           // edge chunks
#define NCHP 104         // padded chunk count (mult of 4 for int4 scan)
#define CHUNK 8192       // edges per chunk (98*8192 >= 800000)

typedef short s16x8 __attribute__((ext_vector_type(8)));   // 8 bf16 (4 VGPRs)
typedef float f32x4 __attribute__((ext_vector_type(4)));   // MFMA accumulator

__device__ inline ushort f2bf(float f) {                   // fp32 -> bf16 RTN-even
    uint32_t u = __float_as_uint(f);
    u += 0x7FFFu + ((u >> 16) & 1u);
    return (ushort)(u >> 16);
}
__device__ inline float bf2f(ushort h) {
    return __uint_as_float(((uint32_t)h) << 16);
}

// ------------------------------------------------------------- CSR build
// bucket = dst >> 8. No global atomics anywhere.

__global__ __launch_bounds__(1024) void k_bhist(const int* __restrict__ dst,
                                                int* __restrict__ bhist) {
    __shared__ int hist[NBK];
    const int tid = threadIdx.x, blk = blockIdx.x;
    if (tid < NBK) hist[tid] = 0;
    __syncthreads();
    const int e0 = blk * CHUNK;
    #pragma unroll
    for (int u = 0; u < CHUNK / 1024; ++u) {
        int e = e0 + u * 1024 + tid;
        if (e < NE) atomicAdd(&hist[dst[e] >> 8], 1);
    }
    __syncthreads();
    if (tid < NBK) {
        bhist[tid * NCHP + blk] = hist[tid];
        if (blk == 0)                          // zero the scan padding once
            for (int c = NCH; c < NCHP; ++c) bhist[tid * NCHP + c] = 0;
    }
}

__global__ __launch_bounds__(256) void k_bscan(int* __restrict__ bhist,
                                               int* __restrict__ bbeg,
                                               int* __restrict__ row_ptr) {
    __shared__ int wsum[4];
    const int tid = threadIdx.x;
    int4 buf[NCHP / 4];
    int tot = 0;
    if (tid < NBK) {
        const int4* rp = reinterpret_cast<const int4*>(bhist + tid * NCHP);
        #pragma unroll
        for (int u = 0; u < NCHP / 4; ++u) buf[u] = rp[u];     // independent loads
        #pragma unroll
        for (int u = 0; u < NCHP / 4; ++u) {                   // exclusive scan in regs
            int4 v = buf[u], o;
            o.x = tot; tot += v.x;
            o.y = tot; tot += v.y;
            o.z = tot; tot += v.z;
            o.w = tot; tot += v.w;
            buf[u] = o;
        }
    }
    const int lane = tid & 63, wid = tid >> 6;
    int x = tot;
    #pragma unroll
    for (int o = 1; o < 64; o <<= 1) {
        int t = __shfl_up(x, o);
        if (lane >= o) x += t;
    }
    if (lane == 63) wsum[wid] = x;
    __syncthreads();
    int wo = 0;
    for (int k = 0; k < wid; ++k) wo += wsum[k];
    const int excl = x - tot + wo;                // bucket start offset
    if (tid < NBK) {
        bbeg[tid] = excl;
        int4* rp = reinterpret_cast<int4*>(bhist + tid * NCHP);
        #pragma unroll
        for (int u = 0; u < NCHP / 4; ++u) {
            int4 v = buf[u];
            v.x += excl; v.y += excl; v.z += excl; v.w += excl;
            rp[u] = v;
        }
    }
    if (tid == 0) { bbeg[NBK] = NE; row_ptr[NN] = NE; }
}

__global__ __launch_bounds__(1024) void k_binscatter(const int* __restrict__ src,
                                                     const int* __restrict__ dst,
                                                     const float* __restrict__ ew,
                                                     const int* __restrict__ bhist,
                                                     uint2* __restrict__ epk) {
    __shared__ int base[NBK];
    __shared__ int lcur[NBK];
    const int tid = threadIdx.x, blk = blockIdx.x;
    if (tid < NBK) { base[tid] = bhist[tid * NCHP + blk]; lcur[tid] = 0; }
    __syncthreads();
    const int e0 = blk * CHUNK;
    #pragma unroll
    for (int u = 0; u < CHUNK / 1024; ++u) {
        int e = e0 + u * 1024 + tid;
        if (e < NE) {
            int d = dst[e];
            int s = src[e];
            float w = ew[e];
            int b = d >> 8;
            int pos = base[b] + atomicAdd(&lcur[b], 1);   // LDS atomic only
            epk[pos] = make_uint2((uint32_t)s | ((uint32_t)(d & 255) << 16),
                                  __float_as_uint(w));
        }
    }
}

__global__ __launch_bounds__(256) void k_build(const uint2* __restrict__ epk,
                                               const int* __restrict__ bbeg,
                                               int* __restrict__ row_ptr,
                                               unsigned int* __restrict__ cw) {
    __shared__ int cnt[256];
    __shared__ int cur[256];
    __shared__ int wsum[4];
    const int tid = threadIdx.x, b = blockIdx.x;
    const int n0 = b << 8;
    const int ebeg = bbeg[b], eend = bbeg[b + 1];
    cnt[tid] = 0;
    __syncthreads();
    for (int e = ebeg + tid; e < eend; e += 256)
        atomicAdd(&cnt[(epk[e].x >> 16) & 255], 1);
    __syncthreads();
    const int v = cnt[tid];
    const int lane = tid & 63, wid = tid >> 6;
    int x = v;
    #pragma unroll
    for (int o = 1; o < 64; o <<= 1) {
        int t = __shfl_up(x, o);
        if (lane >= o) x += t;
    }
    if (lane == 63) wsum[wid] = x;
    __syncthreads();
    int wo = 0;
    for (int k = 0; k < wid; ++k) wo += wsum[k];
    const int excl = ebeg + x - v + wo;           // node segment start
    if (n0 + tid < NN) row_ptr[n0 + tid] = excl;
    cur[tid] = excl;
    __syncthreads();
    for (int e = ebeg + tid; e < eend; e += 256) {
        uint2 p = epk[e];
        int dl = (p.x >> 16) & 255;
        int pos = atomicAdd(&cur[dl], 1);
        // packed edge: low16 = src, high16 = bf16(edge_weight)
        cw[pos] = (p.x & 0xFFFFu) |
                  ((unsigned int)f2bf(__uint_as_float(p.y)) << 16);
    }
}

// -------------------------------------- fused weight transpose + bf16 split

__global__ void k_split_all(const float* __restrict__ Wlin,
                            const float* __restrict__ Wc,
                            ushort* __restrict__ Th, ushort* __restrict__ Tl) {
    int idx = blockIdx.x * blockDim.x + threadIdx.x;
    const int NLIN = HD * FIN;
    float f;
    if (idx < NLIN) {
        int n = idx / FIN, k = idx - n * FIN;
        f = Wlin[(size_t)k * HD + n];
    } else if (idx < NLIN + 3 * HD * HD) {
        int r = idx - NLIN;
        int l = r / (HD * HD);
        int rr = r - l * (HD * HD);
        int n = rr / HD, k = rr - n * HD;
        f = Wc[(size_t)l * HD * HD + (size_t)k * HD + n];
    } else return;
    ushort hi = f2bf(f);
    Th[idx] = hi;
    Tl[idx] = f2bf(f - bf2f(hi));
}

// ----------------------------------------------------- MFMA split-bf16 GEMM
// C[M][128] = A[M][K] @ B[K][128] (+bias), 16x16x32 bf16 MFMA.
// ABF16=false: A fp32, split hi/lo in-flight (3 MFMA). ABF16=true: A bf16
// exact (2 MFMA). OUT8=false: bf16 out. OUT8=true: uint8 per-row-scaled out
// (u = rint(val*127/rowmax) + 128) ; asig[row] = {as-dot, rowmax/127}.
// B^T hi/lo whole-BK=128 K-tile staged once into 64 KB LDS (XOR-swizzled),
// barrier-free main loop, 4 waves x 32 rows, grid 391.

template <int K, bool ATT, bool ABF16, bool OUT8>
__global__ __launch_bounds__(256) void k_gemm_mfma(
    const float*  __restrict__ Af,     // fp32 A (ABF16=false)
    const ushort* __restrict__ Ab,     // bf16 A (ABF16=true)
    const ushort* __restrict__ Bh,     // [HD][K]
    const ushort* __restrict__ Bl,     // [HD][K]
    const float*  __restrict__ bias,   // null if none
    ushort*       __restrict__ Cb,     // bf16 out (OUT8=false)
    unsigned char* __restrict__ C8,    // uint8 out (OUT8=true)
    const float*  __restrict__ att_s, const float* __restrict__ att_d,
    float2* __restrict__ asig,         // {as-dot, scale} per row (ATT)
    float*  __restrict__ ad_,          // ad-dot per row (ATT)
    int M)
{
    constexpr int BK = 128;
    constexpr int NT = K / BK;
    __shared__ ushort Bs[32768];                  // 64 KB: hi [0..16383], lo +16384

    const int tid  = threadIdx.x;
    const int lane = tid & 63;
    const int wid  = tid >> 6;
    const int fl   = lane & 15;
    const int fg   = lane >> 4;
    const int rowBase = blockIdx.x * 128 + wid * 32;

    f32x4 acc[2][8] = {};

    for (int t = 0; t < NT; ++t) {
        if (t) __syncthreads();
        #pragma unroll
        for (int u = 0; u < 8; ++u) {
            const int id  = u * 256 + tid;
            const int bcol = id >> 4, c = id & 15;
            const size_t g = (size_t)bcol * K + t * BK + c * 8;
            const int lidx = bcol * 128 + ((c ^ (bcol & 15)) << 3);
            *reinterpret_cast<uint4*>(&Bs[lidx]) =
                *reinterpret_cast<const uint4*>(Bh + g);
            *reinterpret_cast<uint4*>(&Bs[16384 + lidx]) =
                *reinterpret_cast<const uint4*>(Bl + g);
        }
        __syncthreads();

        #pragma unroll
        for (int kt = 0; kt < BK / 32; ++kt) {
            s16x8 a_h[2], a_l[2];
            #pragma unroll
            for (int rt = 0; rt < 2; ++rt) {
                int r = rowBase + rt * 16 + fl;
                if (r >= M) r = M - 1;            // harmless clamp (stores guarded)
                if (ABF16) {
                    a_h[rt] = *reinterpret_cast<const s16x8*>(
                        Ab + (size_t)r * K + t * BK + kt * 32 + fg * 8);
                } else {
                    const float* ap = Af + (size_t)r * K + t * BK + kt * 32 + fg * 8;
                    float4 t0 = *reinterpret_cast<const float4*>(ap);
                    float4 t1 = *reinterpret_cast<const float4*>(ap + 4);
                    float v[8] = {t0.x, t0.y, t0.z, t0.w, t1.x, t1.y, t1.z, t1.w};
                    #pragma unroll
                    for (int u = 0; u < 8; ++u) {
                        ushort h0 = f2bf(v[u]);
                        a_h[rt][u] = (short)h0;
                        a_l[rt][u] = (short)f2bf(v[u] - bf2f(h0));
                    }
                }
            }
            #pragma unroll
            for (int ct = 0; ct < 8; ++ct) {
                const int lidx = (ct * 16 + fl) * 128 + (((kt * 4 + fg) ^ fl) << 3);
                s16x8 b_h = *reinterpret_cast<const s16x8*>(&Bs[lidx]);
                s16x8 b_l = *reinterpret_cast<const s16x8*>(&Bs[16384 + lidx]);
                #pragma unroll
                for (int rt = 0; rt < 2; ++rt) {
                    acc[rt][ct] = __builtin_amdgcn_mfma_f32_16x16x32_bf16(a_h[rt], b_h, acc[rt][ct], 0, 0, 0);
                    acc[rt][ct] = __builtin_amdgcn_mfma_f32_16x16x32_bf16(a_h[rt], b_l, acc[rt][ct], 0, 0, 0);
                    if (!ABF16)
                        acc[rt][ct] = __builtin_amdgcn_mfma_f32_16x16x32_bf16(a_l[rt], b_h, acc[rt][ct], 0, 0, 0);
                }
            }
        }
    }

    // ---- epilogue: C/D layout col = ct*16 + fl, row = base + fg*4 + reg ----
    float bval[8];
    #pragma unroll
    for (int ct = 0; ct < 8; ++ct) bval[ct] = bias ? bias[ct * 16 + fl] : 0.f;
    float asv[8], adv[8];
    if (ATT) {
        #pragma unroll
        for (int ct = 0; ct < 8; ++ct) {
            asv[ct] = att_s[ct * 16 + fl];
            adv[ct] = att_d[ct * 16 + fl];
        }
    }

    #pragma unroll
    for (int rt = 0; rt < 2; ++rt) {
        const int rbase = rowBase + rt * 16 + fg * 4;
        #pragma unroll
        for (int r = 0; r < 4; ++r) {
            const int row = rbase + r;
            const bool ok = row < M;
            float sv = 0.f, dv = 0.f, m = 0.f;
            float val[8];
            #pragma unroll
            for (int ct = 0; ct < 8; ++ct) {
                val[ct] = acc[rt][ct][r] + bval[ct];
                if (ATT) { sv = fmaf(val[ct], asv[ct], sv); dv = fmaf(val[ct], adv[ct], dv); }
                if (OUT8) m = fmaxf(m, fabsf(val[ct]));
            }
            if (OUT8) {
                #pragma unroll
                for (int o = 1; o < 16; o <<= 1) m = fmaxf(m, __shfl_xor(m, o));
                const float qs = 127.f / fmaxf(m, 1e-30f);
                #pragma unroll
                for (int ct = 0; ct < 8; ++ct) {
                    int qv = (int)rintf(val[ct] * qs);
                    qv = qv < -127 ? -127 : (qv > 127 ? 127 : qv);
                    if (ok) C8[(size_t)row * HD + ct * 16 + fl] =
                        (unsigned char)(qv + 128);           // biased uint8
                }
            } else {
                #pragma unroll
                for (int ct = 0; ct < 8; ++ct)
                    if (ok) Cb[(size_t)row * HD + ct * 16 + fl] = f2bf(val[ct]);
            }
            if (ATT) {
                #pragma unroll
                for (int o = 1; o < 16; o <<= 1) {
                    sv += __shfl_xor(sv, o);
                    dv += __shfl_xor(dv, o);
                }
                if (fl == 0 && ok) {
                    asig[row] = make_float2(sv, OUT8 ? m * (1.f / 127.f) : 0.f);
                    ad_[row]  = dv;
                }
            }
        }
    }
}

// ---------------------------------------------- fused softmax-aggregation
// One wave per node. hp uint8 per-row-scaled biased +128 (bias removed
// exactly via 128*sum(we)). Weight chain does ONE 8B gather (asig = packed
// {as, sig}). Broadcasts go through a wave-private LDS buffer (1 ds_read_b64
// per 4 edges) instead of ds_bpermute; s pre-shifted so payload address is
// one v_add. Lane owns 8 features (uint2), 16 lanes/row, 4 wave quarters
// process 4 edges per load (16 in flight).
// mode 0: h += agg (no out). mode 1: mx = bf16(max(h_old, h_new)), h += agg.
// mode 2: out = max(bf2f(mx), agg + b)  (write-only out).

__device__ inline void acc8u(float wj, uint2 pv,
                             float& a0, float& a1, float& a2, float& a3,
                             float& a4, float& a5, float& a6, float& a7) {
    a0 = fmaf(wj, (float)( pv.x        & 0xFFu), a0);   // v_cvt_f32_ubyte0
    a1 = fmaf(wj, (float)((pv.x >>  8) & 0xFFu), a1);
    a2 = fmaf(wj, (float)((pv.x >> 16) & 0xFFu), a2);
    a3 = fmaf(wj, (float)( pv.x >> 24         ), a3);
    a4 = fmaf(wj, (float)( pv.y        & 0xFFu), a4);
    a5 = fmaf(wj, (float)((pv.y >>  8) & 0xFFu), a5);
    a6 = fmaf(wj, (float)((pv.y >> 16) & 0xFFu), a6);
    a7 = fmaf(wj, (float)( pv.y >> 24         ), a7);
}

__global__ __launch_bounds__(256) void k_agg(const unsigned char* __restrict__ hp8,
                                             const float2* __restrict__ asig,
                                             ushort* __restrict__ hb,
                                             const float* __restrict__ ad_,
                                             const int* __restrict__ row_ptr,
                                             const unsigned int* __restrict__ cw,
                                             const float* __restrict__ bias,
                                             float* __restrict__ out,
                                             ushort* __restrict__ mx, int mode) {
    __shared__ uint2 swb[4][64];       // per-wave (s<<7, we) staging, no barriers
    const int wid  = threadIdx.x >> 6;
    const int lane = threadIdx.x & 63;
    int wave = blockIdx.x * 4 + wid;
    if (wave >= NN) return;
    const int d = wave;
    const int beg = row_ptr[d], end = row_ptr[d + 1];
    const float adv = ad_[d];
    const int q   = lane >> 4;         // which of 4 concurrent edges
    const int hl  = lane & 15;         // feature octet: owns [hl*8, hl*8+8)
    const int hlo = hl << 3;           // loop-invariant byte offset

    float a0 = 0.f, a1 = 0.f, a2 = 0.f, a3 = 0.f;
    float a4 = 0.f, a5 = 0.f, a6 = 0.f, a7 = 0.f;
    float dloc = 0.f, wesum = 0.f;

    for (int base = beg; base < end; base += 64) {
        const int n = min(64, end - base);
        // ---- lane-parallel weight phase: 1 coalesced + 1 packed 8B gather ----
        unsigned soff = 0; float w = 0.f, we = 0.f;
        if (lane < n) {
            unsigned int v = cw[base + lane];
            unsigned s = v & 0xFFFFu;
            float2 ag = asig[s];                   // {as-dot, row scale}
            float l = ag.x + adv;
            l = (l >= 0.f) ? l : NEG_SLOPE * l;
            l = fminf(l, 80.f);                    // overflow guard (no max pass)
            w  = __expf(l) * bf2f((ushort)(v >> 16));
            we = w * ag.y;                         // fold row scale into weight
            soff = s << 7;                         // byte offset of row
        }
        dloc += w;
        swb[wid][lane] = make_uint2(soff, __float_as_uint(we));

        int i = 0;
        for (; i + 15 < n; i += 16) {          // 16 edges = 4 quad loads in flight
            uint2 sw[4]; uint2 pv[4];
            #pragma unroll
            for (int j = 0; j < 4; ++j)
                sw[j] = swb[wid][i + 4 * j + q];   // 16-lane broadcast read
            #pragma unroll
            for (int j = 0; j < 4; ++j)
                pv[j] = *reinterpret_cast<const uint2*>(hp8 + sw[j].x + hlo);
            #pragma unroll
            for (int j = 0; j < 4; ++j) {
                const float wj = __uint_as_float(sw[j].y);
                acc8u(wj, pv[j], a0, a1, a2, a3, a4, a5, a6, a7);
                wesum += wj;
            }
        }
        for (; i + 3 < n; i += 4) {            // 4-edge steps
            uint2 sw = swb[wid][i + q];
            uint2 pv = *reinterpret_cast<const uint2*>(hp8 + sw.x + hlo);
            const float wj = __uint_as_float(sw.y);
            acc8u(wj, pv, a0, a1, a2, a3, a4, a5, a6, a7);
            wesum += wj;
        }
        if (i < n) {                           // tail < 4 edges (masked)
            const int e = i + q;
            const bool ok = e < n;
            uint2 sw = swb[wid][ok ? e : i];
            float wj = ok ? __uint_as_float(sw.y) : 0.f;
            uint2 pv = *reinterpret_cast<const uint2*>(hp8 + sw.x + hlo);
            acc8u(wj, pv, a0, a1, a2, a3, a4, a5, a6, a7);
            wesum += wj;
        }
    }
    #pragma unroll
    for (int o = 32; o > 0; o >>= 1) dloc += __shfl_xor(dloc, o);
    #pragma unroll
    for (int o = 32; o >= 16; o >>= 1) {
        a0 += __shfl_xor(a0, o); a1 += __shfl_xor(a1, o);
        a2 += __shfl_xor(a2, o); a3 += __shfl_xor(a3, o);
        a4 += __shfl_xor(a4, o); a5 += __shfl_xor(a5, o);
        a6 += __shfl_xor(a6, o); a7 += __shfl_xor(a7, o);
        wesum += __shfl_xor(wesum, o);
    }

    if (q != 0) return;                        // lanes 0-15 do the stores
    const float c = 128.f * wesum;             // remove the +128 bias exactly
    const float inv = 1.f / (dloc + 1e-16f);
    const int f0 = hl * 8;
    float r0 = (a0 - c) * inv + bias[f0 + 0], r1 = (a1 - c) * inv + bias[f0 + 1];
    float r2 = (a2 - c) * inv + bias[f0 + 2], r3 = (a3 - c) * inv + bias[f0 + 3];
    float r4 = (a4 - c) * inv + bias[f0 + 4], r5 = (a5 - c) * inv + bias[f0 + 5];
    float r6 = (a6 - c) * inv + bias[f0 + 6], r7 = (a7 - c) * inv + bias[f0 + 7];

    if (mode == 2) {
        uint4 mv = *reinterpret_cast<const uint4*>(mx + (size_t)d * HD + f0);
        float4 o0, o1;
        o0.x = fmaxf(bf2f((ushort)mv.x),         r0);
        o0.y = fmaxf(bf2f((ushort)(mv.x >> 16)), r1);
        o0.z = fmaxf(bf2f((ushort)mv.y),         r2);
        o0.w = fmaxf(bf2f((ushort)(mv.y >> 16)), r3);
        o1.x = fmaxf(bf2f((ushort)mv.z),         r4);
        o1.y = fmaxf(bf2f((ushort)(mv.z >> 16)), r5);
        o1.z = fmaxf(bf2f((ushort)mv.w),         r6);
        o1.w = fmaxf(bf2f((ushort)(mv.w >> 16)), r7);
        float4* outp = reinterpret_cast<float4*>(out + (size_t)d * HD + f0);
        outp[0] = o0; outp[1] = o1;            // write-only full overwrite
    } else {
        uint4* hp = reinterpret_cast<uint4*>(hb + (size_t)d * HD + f0);
        uint4 hv = *hp;
        float h0 = bf2f((ushort)hv.x), h1 = bf2f((ushort)(hv.x >> 16));
        float h2 = bf2f((ushort)hv.y), h3 = bf2f((ushort)(hv.y >> 16));
        float h4 = bf2f((ushort)hv.z), h5 = bf2f((ushort)(hv.z >> 16));
        float h6 = bf2f((ushort)hv.w), h7 = bf2f((ushort)(hv.w >> 16));
        float n0 = h0 + r0, n1 = h1 + r1, n2 = h2 + r2, n3 = h3 + r3;
        float n4 = h4 + r4, n5 = h5 + r5, n6 = h6 + r6, n7 = h7 + r7;
        uint4 st;
        st.x = (uint32_t)f2bf(n0) | ((uint32_t)f2bf(n1) << 16);
        st.y = (uint32_t)f2bf(n2) | ((uint32_t)f2bf(n3) << 16);
        st.z = (uint32_t)f2bf(n4) | ((uint32_t)f2bf(n5) << 16);
        st.w = (uint32_t)f2bf(n6) | ((uint32_t)f2bf(n7) << 16);
        *hp = st;
        if (mode == 1) {                        // mx = bf16(max(h1, h2))
            uint4 sm;
            sm.x = (uint32_t)f2bf(fmaxf(h0, n0)) | ((uint32_t)f2bf(fmaxf(h1, n1)) << 16);
            sm.y = (uint32_t)f2bf(fmaxf(h2, n2)) | ((uint32_t)f2bf(fmaxf(h3, n3)) << 16);
            sm.z = (uint32_t)f2bf(fmaxf(h4, n4)) | ((uint32_t)f2bf(fmaxf(h5, n5)) << 16);
            sm.w = (uint32_t)f2bf(fmaxf(h6, n6)) | ((uint32_t)f2bf(fmaxf(h7, n7)) << 16);
            *reinterpret_cast<uint4*>(mx + (size_t)d * HD + f0) = sm;
        }
    }
}

// ---------------------------------------------------------------- launch

extern "C" void kernel_launch(void* const* d_in, const int* in_sizes, int n_in,
                              void* d_out, int out_size, void* d_ws, size_t ws_size,
                              hipStream_t stream) {
    const float* x        = (const float*)d_in[0];          // [NN][FIN]
    const int*   ei       = (const int*)d_in[1];            // [2][NE]
    const float* ew       = (const float*)d_in[2];          // [NE]
    /* d_in[3] = numNode scalar = NN */
    const float* Wlin     = (const float*)d_in[4];          // [FIN][HD]
    const float* blin     = (const float*)d_in[5];          // [HD]
    const float* Wc       = (const float*)d_in[6];          // [3][HD][HD]
    const float* att_src  = (const float*)d_in[7];          // [3][HD]
    const float* att_dst  = (const float*)d_in[8];          // [3][HD]
    const float* bias_c   = (const float*)d_in[9];          // [3][HD]
    float* out = (float*)d_out;                              // [NN][HD]

    const int* src = ei;
    const int* dst = ei + NE;

    // workspace layout (16B-aligned blocks, ~44 MB)
    char* w = (char*)d_ws;
    ushort* hb      = (ushort*)w;  w += (size_t)NN * HD * 2;   // h residual (bf16)
    unsigned char* hp8 = (unsigned char*)w; w += (size_t)NN * HD; // hp (uint8 scaled)
    float2* asig    = (float2*)w;  w += (size_t)NN * 8;        // {as-dot, scale}
    ushort* mx      = (ushort*)w;  w += (size_t)NN * HD * 2;   // running max (bf16)
    float*  ad_     = (float*)w;   w += (size_t)NN * 4;
    int*    row_ptr = (int*)w;     w += (size_t)(NN + 4) * 4;
    unsigned int* cw = (unsigned int*)w; w += (size_t)NE * 4;  // packed col|bf16(ew)
    uint2*  epk     = (uint2*)w;   w += (size_t)NE * 8;
    int*    bhist   = (int*)w;     w += (size_t)NBK * NCHP * 4;
    int*    bbeg    = (int*)w;     w += (size_t)(NBK + 4) * 4;
    ushort* WTh     = (ushort*)w;  w += (size_t)(HD * FIN + 3 * HD * HD) * 2;
    ushort* WTl     = (ushort*)w;  w += (size_t)(HD * FIN + 3 * HD * HD) * 2;
    ushort* WlinTh = WTh,            *WlinTl = WTl;
    ushort* WcTh   = WTh + HD * FIN, *WcTl   = WTl + HD * FIN;

    const int TB = 256;
    const int nblk_w = (NN + 3) / 4;                 // 4 node-waves per block
    const int nblk_g = (NN + 127) / 128;             // 391 (128 rows per block)
    const int nsplit = HD * FIN + 3 * HD * HD;       // all weight elements

    // ---- fused weight transpose + split (1 launch) ----
    k_split_all<<<(nsplit + TB - 1) / TB, TB, 0, stream>>>(Wlin, Wc, WTh, WTl);

    // ---- CSR build (atomic-reservation-free binning) ----
    k_bhist<<<NCH, 1024, 0, stream>>>(dst, bhist);
    k_bscan<<<1, 256, 0, stream>>>(bhist, bbeg, row_ptr);
    k_binscatter<<<NCH, 1024, 0, stream>>>(src, dst, ew, bhist, epk);
    k_build<<<NBK, 256, 0, stream>>>(epk, bbeg, row_ptr, cw);

    // ---- input projection: h = x @ Wlin + blin (bf16 out, fp32 A split) ----
    k_gemm_mfma<FIN, false, false, false><<<nblk_g, TB, 0, stream>>>(
        x, nullptr, WlinTh, WlinTl, blin, hb, nullptr,
        nullptr, nullptr, nullptr, nullptr, NN);

    // ---- 3 GAT layers (A = h bf16 exact -> 2-MFMA path; hp emitted uint8) ----
    for (int layer = 0; layer < 3; ++layer) {
        k_gemm_mfma<HD, true, true, true><<<nblk_g, TB, 0, stream>>>(
            nullptr, hb, WcTh + (size_t)layer * HD * HD, WcTl + (size_t)layer * HD * HD,
            nullptr, nullptr, hp8,
            att_src + layer * HD, att_dst + layer * HD, asig, ad_, NN);
        int mode = (layer == 0) ? 0 : (layer == 2 ? 2 : 1);
        k_agg<<<nblk_w, TB, 0, stream>>>(hp8, asig, hb, ad_, row_ptr, cw,
                                         bias_c + layer * HD, out, mx, mode);
    }
}

// Round 18
// 171.326 us; speedup vs baseline: 1.2348x; 1.1777x over previous
//
#include <hip/hip_runtime.h>
#include <cstdint>
#include <cstddef>

// Problem constants (from reference)
#define NN 50000
#define NE 800000
#define FIN 256
#define HD 128
#define NEG_SLOPE 0.2f

// CSR-build binning parameters
#define NBK 196          // buckets of 256 nodes: ceil(50000/256)
#define NCH 98           // edge chunks
#define NCHP 104         // padded chunk count (mult of 4 for int4 scan)
#define CHUNK 8192       // edges per chunk (98*8192 >= 800000)

typedef short s16x8 __attribute__((ext_vector_type(8)));   // 8 bf16 (4 VGPRs)
typedef float f32x4 __attribute__((ext_vector_type(4)));   // MFMA accumulator

__device__ inline ushort f2bf(float f) {                   // fp32 -> bf16 RTN-even
    uint32_t u = __float_as_uint(f);
    u += 0x7FFFu + ((u >> 16) & 1u);
    return (ushort)(u >> 16);
}
__device__ inline float bf2f(ushort h) {
    return __uint_as_float(((uint32_t)h) << 16);
}

// ------------------------------------------------------------- CSR build
// bucket = dst >> 8. No global atomics anywhere.

__global__ __launch_bounds__(1024) void k_bhist(const int* __restrict__ dst,
                                                int* __restrict__ bhist) {
    __shared__ int hist[NBK];
    const int tid = threadIdx.x, blk = blockIdx.x;
    if (tid < NBK) hist[tid] = 0;
    __syncthreads();
    const int e0 = blk * CHUNK;
    #pragma unroll
    for (int u = 0; u < CHUNK / 1024; ++u) {
        int e = e0 + u * 1024 + tid;
        if (e < NE) atomicAdd(&hist[dst[e] >> 8], 1);
    }
    __syncthreads();
    if (tid < NBK) {
        bhist[tid * NCHP + blk] = hist[tid];
        if (blk == 0)                          // zero the scan padding once
            for (int c = NCH; c < NCHP; ++c) bhist[tid * NCHP + c] = 0;
    }
}

__global__ __launch_bounds__(256) void k_bscan(int* __restrict__ bhist,
                                               int* __restrict__ bbeg,
                                               int* __restrict__ row_ptr) {
    __shared__ int wsum[4];
    const int tid = threadIdx.x;
    int4 buf[NCHP / 4];
    int tot = 0;
    if (tid < NBK) {
        const int4* rp = reinterpret_cast<const int4*>(bhist + tid * NCHP);
        #pragma unroll
        for (int u = 0; u < NCHP / 4; ++u) buf[u] = rp[u];     // independent loads
        #pragma unroll
        for (int u = 0; u < NCHP / 4; ++u) {                   // exclusive scan in regs
            int4 v = buf[u], o;
            o.x = tot; tot += v.x;
            o.y = tot; tot += v.y;
            o.z = tot; tot += v.z;
            o.w = tot; tot += v.w;
            buf[u] = o;
        }
    }
    const int lane = tid & 63, wid = tid >> 6;
    int x = tot;
    #pragma unroll
    for (int o = 1; o < 64; o <<= 1) {
        int t = __shfl_up(x, o);
        if (lane >= o) x += t;
    }
    if (lane == 63) wsum[wid] = x;
    __syncthreads();
    int wo = 0;
    for (int k = 0; k < wid; ++k) wo += wsum[k];
    const int excl = x - tot + wo;                // bucket start offset
    if (tid < NBK) {
        bbeg[tid] = excl;
        int4* rp = reinterpret_cast<int4*>(bhist + tid * NCHP);
        #pragma unroll
        for (int u = 0; u < NCHP / 4; ++u) {
            int4 v = buf[u];
            v.x += excl; v.y += excl; v.z += excl; v.w += excl;
            rp[u] = v;
        }
    }
    if (tid == 0) { bbeg[NBK] = NE; row_ptr[NN] = NE; }
}

__global__ __launch_bounds__(1024) void k_binscatter(const int* __restrict__ src,
                                                     const int* __restrict__ dst,
                                                     const float* __restrict__ ew,
                                                     const int* __restrict__ bhist,
                                                     uint2* __restrict__ epk) {
    __shared__ int base[NBK];
    __shared__ int lcur[NBK];
    const int tid = threadIdx.x, blk = blockIdx.x;
    if (tid < NBK) { base[tid] = bhist[tid * NCHP + blk]; lcur[tid] = 0; }
    __syncthreads();
    const int e0 = blk * CHUNK;
    #pragma unroll
    for (int u = 0; u < CHUNK / 1024; ++u) {
        int e = e0 + u * 1024 + tid;
        if (e < NE) {
            int d = dst[e];
            int s = src[e];
            float w = ew[e];
            int b = d >> 8;
            int pos = base[b] + atomicAdd(&lcur[b], 1);   // LDS atomic only
            epk[pos] = make_uint2((uint32_t)s | ((uint32_t)(d & 255) << 16),
                                  __float_as_uint(w));
        }
    }
}

__global__ __launch_bounds__(256) void k_build(const uint2* __restrict__ epk,
                                               const int* __restrict__ bbeg,
                                               int* __restrict__ row_ptr,
                                               unsigned int* __restrict__ cw) {
    __shared__ int cnt[256];
    __shared__ int cur[256];
    __shared__ int wsum[4];
    const int tid = threadIdx.x, b = blockIdx.x;
    const int n0 = b << 8;
    const int ebeg = bbeg[b], eend = bbeg[b + 1];
    cnt[tid] = 0;
    __syncthreads();
    for (int e = ebeg + tid; e < eend; e += 256)
        atomicAdd(&cnt[(epk[e].x >> 16) & 255], 1);
    __syncthreads();
    const int v = cnt[tid];
    const int lane = tid & 63, wid = tid >> 6;
    int x = v;
    #pragma unroll
    for (int o = 1; o < 64; o <<= 1) {
        int t = __shfl_up(x, o);
        if (lane >= o) x += t;
    }
    if (lane == 63) wsum[wid] = x;
    __syncthreads();
    int wo = 0;
    for (int k = 0; k < wid; ++k) wo += wsum[k];
    const int excl = ebeg + x - v + wo;           // node segment start
    if (n0 + tid < NN) row_ptr[n0 + tid] = excl;
    cur[tid] = excl;
    __syncthreads();
    for (int e = ebeg + tid; e < eend; e += 256) {
        uint2 p = epk[e];
        int dl = (p.x >> 16) & 255;
        int pos = atomicAdd(&cur[dl], 1);
        // packed edge: low16 = src, high16 = bf16(edge_weight)
        cw[pos] = (p.x & 0xFFFFu) |
                  ((unsigned int)f2bf(__uint_as_float(p.y)) << 16);
    }
}

// -------------------------------------- fused weight transpose + bf16 split

__global__ void k_split_all(const float* __restrict__ Wlin,
                            const float* __restrict__ Wc,
                            ushort* __restrict__ Th, ushort* __restrict__ Tl) {
    int idx = blockIdx.x * blockDim.x + threadIdx.x;
    const int NLIN = HD * FIN;
    float f;
    if (idx < NLIN) {
        int n = idx / FIN, k = idx - n * FIN;
        f = Wlin[(size_t)k * HD + n];
    } else if (idx < NLIN + 3 * HD * HD) {
        int r = idx - NLIN;
        int l = r / (HD * HD);
        int rr = r - l * (HD * HD);
        int n = rr / HD, k = rr - n * HD;
        f = Wc[(size_t)l * HD * HD + (size_t)k * HD + n];
    } else return;
    ushort hi = f2bf(f);
    Th[idx] = hi;
    Tl[idx] = f2bf(f - bf2f(hi));
}

// ----------------------------------------------------- MFMA split-bf16 GEMM
// C[M][128] = A[M][K] @ B[K][128] (+bias), 16x16x32 bf16 MFMA.
// ABF16=false: A fp32, split hi/lo in-flight (3 MFMA). ABF16=true: A bf16
// exact (2 MFMA). OUT8=false: bf16 out. OUT8=true: uint8 per-row-scaled out
// (u = rint(val*127/rowmax) + 128) ; asig[row] = {as-dot, rowmax/127}.
// B^T hi/lo whole-BK=128 K-tile staged once into 64 KB LDS (XOR-swizzled),
// barrier-free main loop, 4 waves x 32 rows, grid 391.

template <int K, bool ATT, bool ABF16, bool OUT8>
__global__ __launch_bounds__(256) void k_gemm_mfma(
    const float*  __restrict__ Af,     // fp32 A (ABF16=false)
    const ushort* __restrict__ Ab,     // bf16 A (ABF16=true)
    const ushort* __restrict__ Bh,     // [HD][K]
    const ushort* __restrict__ Bl,     // [HD][K]
    const float*  __restrict__ bias,   // null if none
    ushort*       __restrict__ Cb,     // bf16 out (OUT8=false)
    unsigned char* __restrict__ C8,    // uint8 out (OUT8=true)
    const float*  __restrict__ att_s, const float* __restrict__ att_d,
    float2* __restrict__ asig,         // {as-dot, scale} per row (ATT)
    float*  __restrict__ ad_,          // ad-dot per row (ATT)
    int M)
{
    constexpr int BK = 128;
    constexpr int NT = K / BK;
    __shared__ ushort Bs[32768];                  // 64 KB: hi [0..16383], lo +16384

    const int tid  = threadIdx.x;
    const int lane = tid & 63;
    const int wid  = tid >> 6;
    const int fl   = lane & 15;
    const int fg   = lane >> 4;
    const int rowBase = blockIdx.x * 128 + wid * 32;

    f32x4 acc[2][8] = {};

    for (int t = 0; t < NT; ++t) {
        if (t) __syncthreads();
        #pragma unroll
        for (int u = 0; u < 8; ++u) {
            const int id  = u * 256 + tid;
            const int bcol = id >> 4, c = id & 15;
            const size_t g = (size_t)bcol * K + t * BK + c * 8;
            const int lidx = bcol * 128 + ((c ^ (bcol & 15)) << 3);
            *reinterpret_cast<uint4*>(&Bs[lidx]) =
                *reinterpret_cast<const uint4*>(Bh + g);
            *reinterpret_cast<uint4*>(&Bs[16384 + lidx]) =
                *reinterpret_cast<const uint4*>(Bl + g);
        }
        __syncthreads();

        #pragma unroll
        for (int kt = 0; kt < BK / 32; ++kt) {
            s16x8 a_h[2], a_l[2];
            #pragma unroll
            for (int rt = 0; rt < 2; ++rt) {
                int r = rowBase + rt * 16 + fl;
                if (r >= M) r = M - 1;            // harmless clamp (stores guarded)
                if (ABF16) {
                    a_h[rt] = *reinterpret_cast<const s16x8*>(
                        Ab + (size_t)r * K + t * BK + kt * 32 + fg * 8);
                } else {
                    const float* ap = Af + (size_t)r * K + t * BK + kt * 32 + fg * 8;
                    float4 t0 = *reinterpret_cast<const float4*>(ap);
                    float4 t1 = *reinterpret_cast<const float4*>(ap + 4);
                    float v[8] = {t0.x, t0.y, t0.z, t0.w, t1.x, t1.y, t1.z, t1.w};
                    #pragma unroll
                    for (int u = 0; u < 8; ++u) {
                        ushort h0 = f2bf(v[u]);
                        a_h[rt][u] = (short)h0;
                        a_l[rt][u] = (short)f2bf(v[u] - bf2f(h0));
                    }
                }
            }
            #pragma unroll
            for (int ct = 0; ct < 8; ++ct) {
                const int lidx = (ct * 16 + fl) * 128 + (((kt * 4 + fg) ^ fl) << 3);
                s16x8 b_h = *reinterpret_cast<const s16x8*>(&Bs[lidx]);
                s16x8 b_l = *reinterpret_cast<const s16x8*>(&Bs[16384 + lidx]);
                #pragma unroll
                for (int rt = 0; rt < 2; ++rt) {
                    acc[rt][ct] = __builtin_amdgcn_mfma_f32_16x16x32_bf16(a_h[rt], b_h, acc[rt][ct], 0, 0, 0);
                    acc[rt][ct] = __builtin_amdgcn_mfma_f32_16x16x32_bf16(a_h[rt], b_l, acc[rt][ct], 0, 0, 0);
                    if (!ABF16)
                        acc[rt][ct] = __builtin_amdgcn_mfma_f32_16x16x32_bf16(a_l[rt], b_h, acc[rt][ct], 0, 0, 0);
                }
            }
        }
    }

    // ---- epilogue: C/D layout col = ct*16 + fl, row = base + fg*4 + reg ----
    float bval[8];
    #pragma unroll
    for (int ct = 0; ct < 8; ++ct) bval[ct] = bias ? bias[ct * 16 + fl] : 0.f;
    float asv[8], adv[8];
    if (ATT) {
        #pragma unroll
        for (int ct = 0; ct < 8; ++ct) {
            asv[ct] = att_s[ct * 16 + fl];
            adv[ct] = att_d[ct * 16 + fl];
        }
    }

    #pragma unroll
    for (int rt = 0; rt < 2; ++rt) {
        const int rbase = rowBase + rt * 16 + fg * 4;
        #pragma unroll
        for (int r = 0; r < 4; ++r) {
            const int row = rbase + r;
            const bool ok = row < M;
            float sv = 0.f, dv = 0.f, m = 0.f;
            float val[8];
            #pragma unroll
            for (int ct = 0; ct < 8; ++ct) {
                val[ct] = acc[rt][ct][r] + bval[ct];
                if (ATT) { sv = fmaf(val[ct], asv[ct], sv); dv = fmaf(val[ct], adv[ct], dv); }
                if (OUT8) m = fmaxf(m, fabsf(val[ct]));
            }
            if (OUT8) {
                #pragma unroll
                for (int o = 1; o < 16; o <<= 1) m = fmaxf(m, __shfl_xor(m, o));
                const float qs = 127.f / fmaxf(m, 1e-30f);
                #pragma unroll
                for (int ct = 0; ct < 8; ++ct) {
                    int qv = (int)rintf(val[ct] * qs);
                    qv = qv < -127 ? -127 : (qv > 127 ? 127 : qv);
                    if (ok) C8[(size_t)row * HD + ct * 16 + fl] =
                        (unsigned char)(qv + 128);           // biased uint8
                }
            } else {
                #pragma unroll
                for (int ct = 0; ct < 8; ++ct)
                    if (ok) Cb[(size_t)row * HD + ct * 16 + fl] = f2bf(val[ct]);
            }
            if (ATT) {
                #pragma unroll
                for (int o = 1; o < 16; o <<= 1) {
                    sv += __shfl_xor(sv, o);
                    dv += __shfl_xor(dv, o);
                }
                if (fl == 0 && ok) {
                    asig[row] = make_float2(sv, OUT8 ? m * (1.f / 127.f) : 0.f);
                    ad_[row]  = dv;
                }
            }
        }
    }
}

// ---------------------------------------------- fused softmax-aggregation
// Round-18 layout: one node per 16-LANE GROUP (4 nodes/wave, 16/block).
// All 16 lanes of a group process EVERY edge of their node (lane = feature
// octet), so feature accumulators need NO cross-lane folds; only dloc folds
// (4 shfls within the group) and wesum is broadcast-identical. Weight phase
// is lane-parallel over 16-edge passes (avg degree 16 -> one full pass,
// 100% lane utilization); (s<<7, we) staged in wave-private LDS, inner loop
// broadcasts via ds_read_b64 (zero-filled slots make tail masking free).
// hp uint8 per-row-scaled biased +128 (bias removed via 128*sum(we)).
// mode 0: h += agg (no out). mode 1: mx = bf16(max(h_old, h_new)), h += agg.
// mode 2: out = max(bf2f(mx), agg + b)  (write-only out).

__device__ inline void acc8u(float wj, uint2 pv,
                             float& a0, float& a1, float& a2, float& a3,
                             float& a4, float& a5, float& a6, float& a7) {
    a0 = fmaf(wj, (float)( pv.x        & 0xFFu), a0);   // v_cvt_f32_ubyte0
    a1 = fmaf(wj, (float)((pv.x >>  8) & 0xFFu), a1);
    a2 = fmaf(wj, (float)((pv.x >> 16) & 0xFFu), a2);
    a3 = fmaf(wj, (float)( pv.x >> 24         ), a3);
    a4 = fmaf(wj, (float)( pv.y        & 0xFFu), a4);
    a5 = fmaf(wj, (float)((pv.y >>  8) & 0xFFu), a5);
    a6 = fmaf(wj, (float)((pv.y >> 16) & 0xFFu), a6);
    a7 = fmaf(wj, (float)( pv.y >> 24         ), a7);
}

__global__ __launch_bounds__(256) void k_agg(const unsigned char* __restrict__ hp8,
                                             const float2* __restrict__ asig,
                                             ushort* __restrict__ hb,
                                             const float* __restrict__ ad_,
                                             const int* __restrict__ row_ptr,
                                             const unsigned int* __restrict__ cw,
                                             const float* __restrict__ bias,
                                             float* __restrict__ out,
                                             ushort* __restrict__ mx, int mode) {
    __shared__ uint2 swb[4][64];       // per-wave staging: [wave][group*16+slot]
    const int wid  = threadIdx.x >> 6;
    const int lane = threadIdx.x & 63;
    const int g    = lane >> 4;        // group = node slot within wave
    const int hl   = lane & 15;        // feature octet within node row
    const int d    = blockIdx.x * 16 + wid * 4 + g;   // grid 3125 * 16 = NN exact
    const int beg = row_ptr[d], end = row_ptr[d + 1];
    const float adv = ad_[d];
    const int hlo = hl << 3;           // loop-invariant byte offset
    const int sb  = g << 4;            // group staging base

    float a0 = 0.f, a1 = 0.f, a2 = 0.f, a3 = 0.f;
    float a4 = 0.f, a5 = 0.f, a6 = 0.f, a7 = 0.f;
    float dloc = 0.f, wesum = 0.f;

    for (int base = beg; base < end; base += 16) {
        const int n = min(16, end - base);
        // ---- lane-parallel weight phase (one edge per lane) ----
        unsigned soff = 0; float w = 0.f, we = 0.f;
        if (hl < n) {
            unsigned int v = cw[base + hl];
            unsigned s = v & 0xFFFFu;
            float2 ag = asig[s];                   // {as-dot, row scale}
            float l = ag.x + adv;
            l = (l >= 0.f) ? l : NEG_SLOPE * l;
            l = fminf(l, 80.f);                    // overflow guard (no max pass)
            w  = __expf(l) * bf2f((ushort)(v >> 16));
            we = w * ag.y;                         // fold row scale into weight
            soff = s << 7;                         // byte offset of row
        }
        dloc += w;
        swb[wid][sb + hl] = make_uint2(soff, __float_as_uint(we));
        // zero-filled slots (hl >= n) make tail edges contribute 0 safely

        for (int i = 0; i < n; i += 4) {       // 4 edges of this node in flight
            uint2 sw[4]; uint2 pv[4];
            #pragma unroll
            for (int j = 0; j < 4; ++j)
                sw[j] = swb[wid][sb + i + j];      // 16-lane broadcast read
            #pragma unroll
            for (int j = 0; j < 4; ++j)
                pv[j] = *reinterpret_cast<const uint2*>(hp8 + sw[j].x + hlo);
            #pragma unroll
            for (int j = 0; j < 4; ++j) {
                const float wj = __uint_as_float(sw[j].y);
                acc8u(wj, pv[j], a0, a1, a2, a3, a4, a5, a6, a7);
                wesum += wj;
            }
        }
    }
    // dloc: fold within the 16-lane group (weight phase was lane-parallel)
    #pragma unroll
    for (int o = 1; o < 16; o <<= 1) dloc += __shfl_xor(dloc, o);
    // a0..a7 and wesum are already complete per lane (broadcast accumulation)

    const float c = 128.f * wesum;             // remove the +128 bias exactly
    const float inv = 1.f / (dloc + 1e-16f);
    const int f0 = hl * 8;
    float r0 = (a0 - c) * inv + bias[f0 + 0], r1 = (a1 - c) * inv + bias[f0 + 1];
    float r2 = (a2 - c) * inv + bias[f0 + 2], r3 = (a3 - c) * inv + bias[f0 + 3];
    float r4 = (a4 - c) * inv + bias[f0 + 4], r5 = (a5 - c) * inv + bias[f0 + 5];
    float r6 = (a6 - c) * inv + bias[f0 + 6], r7 = (a7 - c) * inv + bias[f0 + 7];

    if (mode == 2) {
        uint4 mv = *reinterpret_cast<const uint4*>(mx + (size_t)d * HD + f0);
        float4 o0, o1;
        o0.x = fmaxf(bf2f((ushort)mv.x),         r0);
        o0.y = fmaxf(bf2f((ushort)(mv.x >> 16)), r1);
        o0.z = fmaxf(bf2f((ushort)mv.y),         r2);
        o0.w = fmaxf(bf2f((ushort)(mv.y >> 16)), r3);
        o1.x = fmaxf(bf2f((ushort)mv.z),         r4);
        o1.y = fmaxf(bf2f((ushort)(mv.z >> 16)), r5);
        o1.z = fmaxf(bf2f((ushort)mv.w),         r6);
        o1.w = fmaxf(bf2f((ushort)(mv.w >> 16)), r7);
        float4* outp = reinterpret_cast<float4*>(out + (size_t)d * HD + f0);
        outp[0] = o0; outp[1] = o1;            // write-only full overwrite
    } else {
        uint4* hp = reinterpret_cast<uint4*>(hb + (size_t)d * HD + f0);
        uint4 hv = *hp;
        float h0 = bf2f((ushort)hv.x), h1 = bf2f((ushort)(hv.x >> 16));
        float h2 = bf2f((ushort)hv.y), h3 = bf2f((ushort)(hv.y >> 16));
        float h4 = bf2f((ushort)hv.z), h5 = bf2f((ushort)(hv.z >> 16));
        float h6 = bf2f((ushort)hv.w), h7 = bf2f((ushort)(hv.w >> 16));
        float n0 = h0 + r0, n1 = h1 + r1, n2 = h2 + r2, n3 = h3 + r3;
        float n4 = h4 + r4, n5 = h5 + r5, n6 = h6 + r6, n7 = h7 + r7;
        uint4 st;
        st.x = (uint32_t)f2bf(n0) | ((uint32_t)f2bf(n1) << 16);
        st.y = (uint32_t)f2bf(n2) | ((uint32_t)f2bf(n3) << 16);
        st.z = (uint32_t)f2bf(n4) | ((uint32_t)f2bf(n5) << 16);
        st.w = (uint32_t)f2bf(n6) | ((uint32_t)f2bf(n7) << 16);
        *hp = st;
        if (mode == 1) {                        // mx = bf16(max(h1, h2))
            uint4 sm;
            sm.x = (uint32_t)f2bf(fmaxf(h0, n0)) | ((uint32_t)f2bf(fmaxf(h1, n1)) << 16);
            sm.y = (uint32_t)f2bf(fmaxf(h2, n2)) | ((uint32_t)f2bf(fmaxf(h3, n3)) << 16);
            sm.z = (uint32_t)f2bf(fmaxf(h4, n4)) | ((uint32_t)f2bf(fmaxf(h5, n5)) << 16);
            sm.w = (uint32_t)f2bf(fmaxf(h6, n6)) | ((uint32_t)f2bf(fmaxf(h7, n7)) << 16);
            *reinterpret_cast<uint4*>(mx + (size_t)d * HD + f0) = sm;
        }
    }
}

// ---------------------------------------------------------------- launch

extern "C" void kernel_launch(void* const* d_in, const int* in_sizes, int n_in,
                              void* d_out, int out_size, void* d_ws, size_t ws_size,
                              hipStream_t stream) {
    const float* x        = (const float*)d_in[0];          // [NN][FIN]
    const int*   ei       = (const int*)d_in[1];            // [2][NE]
    const float* ew       = (const float*)d_in[2];          // [NE]
    /* d_in[3] = numNode scalar = NN */
    const float* Wlin     = (const float*)d_in[4];          // [FIN][HD]
    const float* blin     = (const float*)d_in[5];          // [HD]
    const float* Wc       = (const float*)d_in[6];          // [3][HD][HD]
    const float* att_src  = (const float*)d_in[7];          // [3][HD]
    const float* att_dst  = (const float*)d_in[8];          // [3][HD]
    const float* bias_c   = (const float*)d_in[9];          // [3][HD]
    float* out = (float*)d_out;                              // [NN][HD]

    const int* src = ei;
    const int* dst = ei + NE;

    // workspace layout (16B-aligned blocks, ~44 MB)
    char* w = (char*)d_ws;
    ushort* hb      = (ushort*)w;  w += (size_t)NN * HD * 2;   // h residual (bf16)
    unsigned char* hp8 = (unsigned char*)w; w += (size_t)NN * HD; // hp (uint8 scaled)
    float2* asig    = (float2*)w;  w += (size_t)NN * 8;        // {as-dot, scale}
    ushort* mx      = (ushort*)w;  w += (size_t)NN * HD * 2;   // running max (bf16)
    float*  ad_     = (float*)w;   w += (size_t)NN * 4;
    int*    row_ptr = (int*)w;     w += (size_t)(NN + 4) * 4;
    unsigned int* cw = (unsigned int*)w; w += (size_t)NE * 4;  // packed col|bf16(ew)
    uint2*  epk     = (uint2*)w;   w += (size_t)NE * 8;
    int*    bhist   = (int*)w;     w += (size_t)NBK * NCHP * 4;
    int*    bbeg    = (int*)w;     w += (size_t)(NBK + 4) * 4;
    ushort* WTh     = (ushort*)w;  w += (size_t)(HD * FIN + 3 * HD * HD) * 2;
    ushort* WTl     = (ushort*)w;  w += (size_t)(HD * FIN + 3 * HD * HD) * 2;
    ushort* WlinTh = WTh,            *WlinTl = WTl;
    ushort* WcTh   = WTh + HD * FIN, *WcTl   = WTl + HD * FIN;

    const int TB = 256;
    const int nblk_w = NN / 16;                      // 3125 (16 nodes per block)
    const int nblk_g = (NN + 127) / 128;             // 391 (128 rows per block)
    const int nsplit = HD * FIN + 3 * HD * HD;       // all weight elements

    // ---- fused weight transpose + split (1 launch) ----
    k_split_all<<<(nsplit + TB - 1) / TB, TB, 0, stream>>>(Wlin, Wc, WTh, WTl);

    // ---- CSR build (atomic-reservation-free binning) ----
    k_bhist<<<NCH, 1024, 0, stream>>>(dst, bhist);
    k_bscan<<<1, 256, 0, stream>>>(bhist, bbeg, row_ptr);
    k_binscatter<<<NCH, 1024, 0, stream>>>(src, dst, ew, bhist, epk);
    k_build<<<NBK, 256, 0, stream>>>(epk, bbeg, row_ptr, cw);

    // ---- input projection: h = x @ Wlin + blin (bf16 out, fp32 A split) ----
    k_gemm_mfma<FIN, false, false, false><<<nblk_g, TB, 0, stream>>>(
        x, nullptr, WlinTh, WlinTl, blin, hb, nullptr,
        nullptr, nullptr, nullptr, nullptr, NN);

    // ---- 3 GAT layers (A = h bf16 exact -> 2-MFMA path; hp emitted uint8) ----
    for (int layer = 0; layer < 3; ++layer) {
        k_gemm_mfma<HD, true, true, true><<<nblk_g, TB, 0, stream>>>(
            nullptr, hb, WcTh + (size_t)layer * HD * HD, WcTl + (size_t)layer * HD * HD,
            nullptr, nullptr, hp8,
            att_src + layer * HD, att_dst + layer * HD, asig, ad_, NN);
        int mode = (layer == 0) ? 0 : (layer == 2 ? 2 : 1);
        k_agg<<<nblk_w, TB, 0, stream>>>(hp8, asig, hb, ad_, row_ptr, cw,
                                         bias_c + layer * HD, out, mx, mode);
    }
}

// Round 19
// 170.490 us; speedup vs baseline: 1.2409x; 1.0049x over previous
//
#include <hip/hip_runtime.h>
#include <cstdint>
#include <cstddef>

// Problem constants (from reference)
#define NN 50000
#define NE 800000
#define FIN 256
#define HD 128
#define NEG_SLOPE 0.2f

// CSR-build binning parameters
#define NBK 196          // buckets of 256 nodes: ceil(50000/256)
#define NCH 98           // edge chunks
#define NCHP 104         // padded chunk count (mult of 4 for int4 scan)
#define CHUNK 8192       // edges per chunk (98*8192 >= 800000)

typedef short s16x8 __attribute__((ext_vector_type(8)));   // 8 bf16 (4 VGPRs)
typedef float f32x4 __attribute__((ext_vector_type(4)));   // MFMA accumulator

__device__ inline ushort f2bf(float f) {                   // fp32 -> bf16 RTN-even
    uint32_t u = __float_as_uint(f);
    u += 0x7FFFu + ((u >> 16) & 1u);
    return (ushort)(u >> 16);
}
__device__ inline float bf2f(ushort h) {
    return __uint_as_float(((uint32_t)h) << 16);
}

// ------------------------------------------------------------- CSR build
// bucket = dst >> 8. No global atomics anywhere.

__global__ __launch_bounds__(1024) void k_bhist(const int* __restrict__ dst,
                                                int* __restrict__ bhist) {
    __shared__ int hist[NBK];
    const int tid = threadIdx.x, blk = blockIdx.x;
    if (tid < NBK) hist[tid] = 0;
    __syncthreads();
    const int e0 = blk * CHUNK;
    #pragma unroll
    for (int u = 0; u < CHUNK / 1024; ++u) {
        int e = e0 + u * 1024 + tid;
        if (e < NE) atomicAdd(&hist[dst[e] >> 8], 1);
    }
    __syncthreads();
    if (tid < NBK) {
        bhist[tid * NCHP + blk] = hist[tid];
        if (blk == 0)                          // zero the scan padding once
            for (int c = NCH; c < NCHP; ++c) bhist[tid * NCHP + c] = 0;
    }
}

__global__ __launch_bounds__(256) void k_bscan(int* __restrict__ bhist,
                                               int* __restrict__ bbeg,
                                               int* __restrict__ row_ptr) {
    __shared__ int wsum[4];
    const int tid = threadIdx.x;
    int4 buf[NCHP / 4];
    int tot = 0;
    if (tid < NBK) {
        const int4* rp = reinterpret_cast<const int4*>(bhist + tid * NCHP);
        #pragma unroll
        for (int u = 0; u < NCHP / 4; ++u) buf[u] = rp[u];     // independent loads
        #pragma unroll
        for (int u = 0; u < NCHP / 4; ++u) {                   // exclusive scan in regs
            int4 v = buf[u], o;
            o.x = tot; tot += v.x;
            o.y = tot; tot += v.y;
            o.z = tot; tot += v.z;
            o.w = tot; tot += v.w;
            buf[u] = o;
        }
    }
    const int lane = tid & 63, wid = tid >> 6;
    int x = tot;
    #pragma unroll
    for (int o = 1; o < 64; o <<= 1) {
        int t = __shfl_up(x, o);
        if (lane >= o) x += t;
    }
    if (lane == 63) wsum[wid] = x;
    __syncthreads();
    int wo = 0;
    for (int k = 0; k < wid; ++k) wo += wsum[k];
    const int excl = x - tot + wo;                // bucket start offset
    if (tid < NBK) {
        bbeg[tid] = excl;
        int4* rp = reinterpret_cast<int4*>(bhist + tid * NCHP);
        #pragma unroll
        for (int u = 0; u < NCHP / 4; ++u) {
            int4 v = buf[u];
            v.x += excl; v.y += excl; v.z += excl; v.w += excl;
            rp[u] = v;
        }
    }
    if (tid == 0) { bbeg[NBK] = NE; row_ptr[NN] = NE; }
}

__global__ __launch_bounds__(1024) void k_binscatter(const int* __restrict__ src,
                                                     const int* __restrict__ dst,
                                                     const float* __restrict__ ew,
                                                     const int* __restrict__ bhist,
                                                     uint2* __restrict__ epk) {
    __shared__ int base[NBK];
    __shared__ int lcur[NBK];
    const int tid = threadIdx.x, blk = blockIdx.x;
    if (tid < NBK) { base[tid] = bhist[tid * NCHP + blk]; lcur[tid] = 0; }
    __syncthreads();
    const int e0 = blk * CHUNK;
    #pragma unroll
    for (int u = 0; u < CHUNK / 1024; ++u) {
        int e = e0 + u * 1024 + tid;
        if (e < NE) {
            int d = dst[e];
            int s = src[e];
            float w = ew[e];
            int b = d >> 8;
            int pos = base[b] + atomicAdd(&lcur[b], 1);   // LDS atomic only
            epk[pos] = make_uint2((uint32_t)s | ((uint32_t)(d & 255) << 16),
                                  __float_as_uint(w));
        }
    }
}

__global__ __launch_bounds__(256) void k_build(const uint2* __restrict__ epk,
                                               const int* __restrict__ bbeg,
                                               int* __restrict__ row_ptr,
                                               unsigned int* __restrict__ cw) {
    __shared__ int cnt[256];
    __shared__ int cur[256];
    __shared__ int wsum[4];
    const int tid = threadIdx.x, b = blockIdx.x;
    const int n0 = b << 8;
    const int ebeg = bbeg[b], eend = bbeg[b + 1];
    cnt[tid] = 0;
    __syncthreads();
    for (int e = ebeg + tid; e < eend; e += 256)
        atomicAdd(&cnt[(epk[e].x >> 16) & 255], 1);
    __syncthreads();
    const int v = cnt[tid];
    const int lane = tid & 63, wid = tid >> 6;
    int x = v;
    #pragma unroll
    for (int o = 1; o < 64; o <<= 1) {
        int t = __shfl_up(x, o);
        if (lane >= o) x += t;
    }
    if (lane == 63) wsum[wid] = x;
    __syncthreads();
    int wo = 0;
    for (int k = 0; k < wid; ++k) wo += wsum[k];
    const int excl = ebeg + x - v + wo;           // node segment start
    if (n0 + tid < NN) row_ptr[n0 + tid] = excl;
    cur[tid] = excl;
    __syncthreads();
    for (int e = ebeg + tid; e < eend; e += 256) {
        uint2 p = epk[e];
        int dl = (p.x >> 16) & 255;
        int pos = atomicAdd(&cur[dl], 1);
        // packed edge: low16 = src, high16 = bf16(edge_weight)
        cw[pos] = (p.x & 0xFFFFu) |
                  ((unsigned int)f2bf(__uint_as_float(p.y)) << 16);
    }
}

// -------------------------------------- fused weight transpose + bf16 split

__global__ void k_split_all(const float* __restrict__ Wlin,
                            const float* __restrict__ Wc,
                            ushort* __restrict__ Th, ushort* __restrict__ Tl) {
    int idx = blockIdx.x * blockDim.x + threadIdx.x;
    const int NLIN = HD * FIN;
    float f;
    if (idx < NLIN) {
        int n = idx / FIN, k = idx - n * FIN;
        f = Wlin[(size_t)k * HD + n];
    } else if (idx < NLIN + 3 * HD * HD) {
        int r = idx - NLIN;
        int l = r / (HD * HD);
        int rr = r - l * (HD * HD);
        int n = rr / HD, k = rr - n * HD;
        f = Wc[(size_t)l * HD * HD + (size_t)k * HD + n];
    } else return;
    ushort hi = f2bf(f);
    Th[idx] = hi;
    Tl[idx] = f2bf(f - bf2f(hi));
}

// ----------------------------------------------------- MFMA split-bf16 GEMM
// C[M][128] = A[M][K] @ B[K][128] (+bias), 16x16x32 bf16 MFMA.
// ABF16=false: A fp32, split hi/lo in-flight (3 MFMA). ABF16=true: A bf16
// exact (2 MFMA). OUT8=false: bf16 out. OUT8=true: uint8 per-row-scaled out
// (u = rint(val*127/rowmax) + 128) ; asig[row] = {as-dot, rowmax/127}.
// B^T hi/lo whole-BK=128 K-tile staged once into 64 KB LDS (XOR-swizzled),
// barrier-free main loop, 4 waves x 32 rows, grid 391.

template <int K, bool ATT, bool ABF16, bool OUT8>
__global__ __launch_bounds__(256) void k_gemm_mfma(
    const float*  __restrict__ Af,     // fp32 A (ABF16=false)
    const ushort* __restrict__ Ab,     // bf16 A (ABF16=true)
    const ushort* __restrict__ Bh,     // [HD][K]
    const ushort* __restrict__ Bl,     // [HD][K]
    const float*  __restrict__ bias,   // null if none
    ushort*       __restrict__ Cb,     // bf16 out (OUT8=false)
    unsigned char* __restrict__ C8,    // uint8 out (OUT8=true)
    const float*  __restrict__ att_s, const float* __restrict__ att_d,
    float2* __restrict__ asig,         // {as-dot, scale} per row (ATT)
    float*  __restrict__ ad_,          // ad-dot per row (ATT)
    int M)
{
    constexpr int BK = 128;
    constexpr int NT = K / BK;
    __shared__ ushort Bs[32768];                  // 64 KB: hi [0..16383], lo +16384

    const int tid  = threadIdx.x;
    const int lane = tid & 63;
    const int wid  = tid >> 6;
    const int fl   = lane & 15;
    const int fg   = lane >> 4;
    const int rowBase = blockIdx.x * 128 + wid * 32;

    f32x4 acc[2][8] = {};

    for (int t = 0; t < NT; ++t) {
        if (t) __syncthreads();
        #pragma unroll
        for (int u = 0; u < 8; ++u) {
            const int id  = u * 256 + tid;
            const int bcol = id >> 4, c = id & 15;
            const size_t g = (size_t)bcol * K + t * BK + c * 8;
            const int lidx = bcol * 128 + ((c ^ (bcol & 15)) << 3);
            *reinterpret_cast<uint4*>(&Bs[lidx]) =
                *reinterpret_cast<const uint4*>(Bh + g);
            *reinterpret_cast<uint4*>(&Bs[16384 + lidx]) =
                *reinterpret_cast<const uint4*>(Bl + g);
        }
        __syncthreads();

        #pragma unroll
        for (int kt = 0; kt < BK / 32; ++kt) {
            s16x8 a_h[2], a_l[2];
            #pragma unroll
            for (int rt = 0; rt < 2; ++rt) {
                int r = rowBase + rt * 16 + fl;
                if (r >= M) r = M - 1;            // harmless clamp (stores guarded)
                if (ABF16) {
                    a_h[rt] = *reinterpret_cast<const s16x8*>(
                        Ab + (size_t)r * K + t * BK + kt * 32 + fg * 8);
                } else {
                    const float* ap = Af + (size_t)r * K + t * BK + kt * 32 + fg * 8;
                    float4 t0 = *reinterpret_cast<const float4*>(ap);
                    float4 t1 = *reinterpret_cast<const float4*>(ap + 4);
                    float v[8] = {t0.x, t0.y, t0.z, t0.w, t1.x, t1.y, t1.z, t1.w};
                    #pragma unroll
                    for (int u = 0; u < 8; ++u) {
                        ushort h0 = f2bf(v[u]);
                        a_h[rt][u] = (short)h0;
                        a_l[rt][u] = (short)f2bf(v[u] - bf2f(h0));
                    }
                }
            }
            #pragma unroll
            for (int ct = 0; ct < 8; ++ct) {
                const int lidx = (ct * 16 + fl) * 128 + (((kt * 4 + fg) ^ fl) << 3);
                s16x8 b_h = *reinterpret_cast<const s16x8*>(&Bs[lidx]);
                s16x8 b_l = *reinterpret_cast<const s16x8*>(&Bs[16384 + lidx]);
                #pragma unroll
                for (int rt = 0; rt < 2; ++rt) {
                    acc[rt][ct] = __builtin_amdgcn_mfma_f32_16x16x32_bf16(a_h[rt], b_h, acc[rt][ct], 0, 0, 0);
                    acc[rt][ct] = __builtin_amdgcn_mfma_f32_16x16x32_bf16(a_h[rt], b_l, acc[rt][ct], 0, 0, 0);
                    if (!ABF16)
                        acc[rt][ct] = __builtin_amdgcn_mfma_f32_16x16x32_bf16(a_l[rt], b_h, acc[rt][ct], 0, 0, 0);
                }
            }
        }
    }

    // ---- epilogue: C/D layout col = ct*16 + fl, row = base + fg*4 + reg ----
    float bval[8];
    #pragma unroll
    for (int ct = 0; ct < 8; ++ct) bval[ct] = bias ? bias[ct * 16 + fl] : 0.f;
    float asv[8], adv[8];
    if (ATT) {
        #pragma unroll
        for (int ct = 0; ct < 8; ++ct) {
            asv[ct] = att_s[ct * 16 + fl];
            adv[ct] = att_d[ct * 16 + fl];
        }
    }

    #pragma unroll
    for (int rt = 0; rt < 2; ++rt) {
        const int rbase = rowBase + rt * 16 + fg * 4;
        #pragma unroll
        for (int r = 0; r < 4; ++r) {
            const int row = rbase + r;
            const bool ok = row < M;
            float sv = 0.f, dv = 0.f, m = 0.f;
            float val[8];
            #pragma unroll
            for (int ct = 0; ct < 8; ++ct) {
                val[ct] = acc[rt][ct][r] + bval[ct];
                if (ATT) { sv = fmaf(val[ct], asv[ct], sv); dv = fmaf(val[ct], adv[ct], dv); }
                if (OUT8) m = fmaxf(m, fabsf(val[ct]));
            }
            if (OUT8) {
                #pragma unroll
                for (int o = 1; o < 16; o <<= 1) m = fmaxf(m, __shfl_xor(m, o));
                const float qs = 127.f / fmaxf(m, 1e-30f);
                #pragma unroll
                for (int ct = 0; ct < 8; ++ct) {
                    int qv = (int)rintf(val[ct] * qs);
                    qv = qv < -127 ? -127 : (qv > 127 ? 127 : qv);
                    if (ok) C8[(size_t)row * HD + ct * 16 + fl] =
                        (unsigned char)(qv + 128);           // biased uint8
                }
            } else {
                #pragma unroll
                for (int ct = 0; ct < 8; ++ct)
                    if (ok) Cb[(size_t)row * HD + ct * 16 + fl] = f2bf(val[ct]);
            }
            if (ATT) {
                #pragma unroll
                for (int o = 1; o < 16; o <<= 1) {
                    sv += __shfl_xor(sv, o);
                    dv += __shfl_xor(dv, o);
                }
                if (fl == 0 && ok) {
                    asig[row] = make_float2(sv, OUT8 ? m * (1.f / 127.f) : 0.f);
                    ad_[row]  = dv;
                }
            }
        }
    }
}

// ---------------------------------------------- fused softmax-aggregation
// One node per 16-LANE GROUP (4 nodes/wave). All 16 lanes of a group process
// every edge of their node (lane = feature octet) -> feature accumulators
// need no cross-lane folds; only dloc folds (4 shfls). Weight phase is
// lane-parallel over 16-edge passes; (s<<7, we) staged in wave-private LDS.
// Round-19: 8 edges per batch (8 ds_read_b64 + 8 independent gathers in
// flight) and edge count rounded UP to a multiple of 8 -- zero-filled
// staging slots (we=0, soff=0) contribute exactly 0 via a cheap hp8[0]
// broadcast load, so there is NO tail branching at all.
// hp uint8 per-row-scaled biased +128 (bias removed via 128*sum(we)).
// mode 0: h += agg (no out). mode 1: mx = bf16(max(h_old, h_new)), h += agg.
// mode 2: out = max(bf2f(mx), agg + b)  (write-only out).

__device__ inline void acc8u(float wj, uint2 pv,
                             float& a0, float& a1, float& a2, float& a3,
                             float& a4, float& a5, float& a6, float& a7) {
    a0 = fmaf(wj, (float)( pv.x        & 0xFFu), a0);   // v_cvt_f32_ubyte0
    a1 = fmaf(wj, (float)((pv.x >>  8) & 0xFFu), a1);
    a2 = fmaf(wj, (float)((pv.x >> 16) & 0xFFu), a2);
    a3 = fmaf(wj, (float)( pv.x >> 24         ), a3);
    a4 = fmaf(wj, (float)( pv.y        & 0xFFu), a4);
    a5 = fmaf(wj, (float)((pv.y >>  8) & 0xFFu), a5);
    a6 = fmaf(wj, (float)((pv.y >> 16) & 0xFFu), a6);
    a7 = fmaf(wj, (float)( pv.y >> 24         ), a7);
}

__global__ __launch_bounds__(256) void k_agg(const unsigned char* __restrict__ hp8,
                                             const float2* __restrict__ asig,
                                             ushort* __restrict__ hb,
                                             const float* __restrict__ ad_,
                                             const int* __restrict__ row_ptr,
                                             const unsigned int* __restrict__ cw,
                                             const float* __restrict__ bias,
                                             float* __restrict__ out,
                                             ushort* __restrict__ mx, int mode) {
    __shared__ uint2 swb[4][64];       // per-wave staging: [wave][group*16+slot]
    const int wid  = threadIdx.x >> 6;
    const int lane = threadIdx.x & 63;
    const int g    = lane >> 4;        // group = node slot within wave
    const int hl   = lane & 15;        // feature octet within node row
    const int d    = blockIdx.x * 16 + wid * 4 + g;   // grid 3125 * 16 = NN exact
    const int beg = row_ptr[d], end = row_ptr[d + 1];
    const float adv = ad_[d];
    const int hlo = hl << 3;           // loop-invariant byte offset
    const int sb  = g << 4;            // group staging base

    float a0 = 0.f, a1 = 0.f, a2 = 0.f, a3 = 0.f;
    float a4 = 0.f, a5 = 0.f, a6 = 0.f, a7 = 0.f;
    float dloc = 0.f, wesum = 0.f;

    for (int base = beg; base < end; base += 16) {
        const int n = min(16, end - base);
        // ---- lane-parallel weight phase (one edge per lane) ----
        unsigned soff = 0; float w = 0.f, we = 0.f;
        if (hl < n) {
            unsigned int v = cw[base + hl];
            unsigned s = v & 0xFFFFu;
            float2 ag = asig[s];                   // {as-dot, row scale}
            float l = ag.x + adv;
            l = (l >= 0.f) ? l : NEG_SLOPE * l;
            l = fminf(l, 80.f);                    // overflow guard (no max pass)
            w  = __expf(l) * bf2f((ushort)(v >> 16));
            we = w * ag.y;                         // fold row scale into weight
            soff = s << 7;                         // byte offset of row
        }
        dloc += w;
        swb[wid][sb + hl] = make_uint2(soff, __float_as_uint(we));
        // zero-filled slots (hl >= n) contribute exactly 0 below

        const int nr = (n > 8) ? 16 : 8;           // round up: no tail branches
        for (int i = 0; i < nr; i += 8) {          // 8 edges in flight
            uint2 sw[8]; uint2 pv[8];
            #pragma unroll
            for (int j = 0; j < 8; ++j)
                sw[j] = swb[wid][sb + i + j];      // 16-lane broadcast read
            #pragma unroll
            for (int j = 0; j < 8; ++j)
                pv[j] = *reinterpret_cast<const uint2*>(hp8 + sw[j].x + hlo);
            #pragma unroll
            for (int j = 0; j < 8; ++j) {
                const float wj = __uint_as_float(sw[j].y);
                acc8u(wj, pv[j], a0, a1, a2, a3, a4, a5, a6, a7);
                wesum += wj;
            }
        }
    }
    // dloc: fold within the 16-lane group (weight phase was lane-parallel)
    #pragma unroll
    for (int o = 1; o < 16; o <<= 1) dloc += __shfl_xor(dloc, o);
    // a0..a7 and wesum are already complete per lane (broadcast accumulation)

    const float c = 128.f * wesum;             // remove the +128 bias exactly
    const float inv = 1.f / (dloc + 1e-16f);
    const int f0 = hl * 8;
    float r0 = (a0 - c) * inv + bias[f0 + 0], r1 = (a1 - c) * inv + bias[f0 + 1];
    float r2 = (a2 - c) * inv + bias[f0 + 2], r3 = (a3 - c) * inv + bias[f0 + 3];
    float r4 = (a4 - c) * inv + bias[f0 + 4], r5 = (a5 - c) * inv + bias[f0 + 5];
    float r6 = (a6 - c) * inv + bias[f0 + 6], r7 = (a7 - c) * inv + bias[f0 + 7];

    if (mode == 2) {
        uint4 mv = *reinterpret_cast<const uint4*>(mx + (size_t)d * HD + f0);
        float4 o0, o1;
        o0.x = fmaxf(bf2f((ushort)mv.x),         r0);
        o0.y = fmaxf(bf2f((ushort)(mv.x >> 16)), r1);
        o0.z = fmaxf(bf2f((ushort)mv.y),         r2);
        o0.w = fmaxf(bf2f((ushort)(mv.y >> 16)), r3);
        o1.x = fmaxf(bf2f((ushort)mv.z),         r4);
        o1.y = fmaxf(bf2f((ushort)(mv.z >> 16)), r5);
        o1.z = fmaxf(bf2f((ushort)mv.w),         r6);
        o1.w = fmaxf(bf2f((ushort)(mv.w >> 16)), r7);
        float4* outp = reinterpret_cast<float4*>(out + (size_t)d * HD + f0);
        outp[0] = o0; outp[1] = o1;            // write-only full overwrite
    } else {
        uint4* hp = reinterpret_cast<uint4*>(hb + (size_t)d * HD + f0);
        uint4 hv = *hp;
        float h0 = bf2f((ushort)hv.x), h1 = bf2f((ushort)(hv.x >> 16));
        float h2 = bf2f((ushort)hv.y), h3 = bf2f((ushort)(hv.y >> 16));
        float h4 = bf2f((ushort)hv.z), h5 = bf2f((ushort)(hv.z >> 16));
        float h6 = bf2f((ushort)hv.w), h7 = bf2f((ushort)(hv.w >> 16));
        float n0 = h0 + r0, n1 = h1 + r1, n2 = h2 + r2, n3 = h3 + r3;
        float n4 = h4 + r4, n5 = h5 + r5, n6 = h6 + r6, n7 = h7 + r7;
        uint4 st;
        st.x = (uint32_t)f2bf(n0) | ((uint32_t)f2bf(n1) << 16);
        st.y = (uint32_t)f2bf(n2) | ((uint32_t)f2bf(n3) << 16);
        st.z = (uint32_t)f2bf(n4) | ((uint32_t)f2bf(n5) << 16);
        st.w = (uint32_t)f2bf(n6) | ((uint32_t)f2bf(n7) << 16);
        *hp = st;
        if (mode == 1) {                        // mx = bf16(max(h1, h2))
            uint4 sm;
            sm.x = (uint32_t)f2bf(fmaxf(h0, n0)) | ((uint32_t)f2bf(fmaxf(h1, n1)) << 16);
            sm.y = (uint32_t)f2bf(fmaxf(h2, n2)) | ((uint32_t)f2bf(fmaxf(h3, n3)) << 16);
            sm.z = (uint32_t)f2bf(fmaxf(h4, n4)) | ((uint32_t)f2bf(fmaxf(h5, n5)) << 16);
            sm.w = (uint32_t)f2bf(fmaxf(h6, n6)) | ((uint32_t)f2bf(fmaxf(h7, n7)) << 16);
            *reinterpret_cast<uint4*>(mx + (size_t)d * HD + f0) = sm;
        }
    }
}

// ---------------------------------------------------------------- launch

extern "C" void kernel_launch(void* const* d_in, const int* in_sizes, int n_in,
                              void* d_out, int out_size, void* d_ws, size_t ws_size,
                              hipStream_t stream) {
    const float* x        = (const float*)d_in[0];          // [NN][FIN]
    const int*   ei       = (const int*)d_in[1];            // [2][NE]
    const float* ew       = (const float*)d_in[2];          // [NE]
    /* d_in[3] = numNode scalar = NN */
    const float* Wlin     = (const float*)d_in[4];          // [FIN][HD]
    const float* blin     = (const float*)d_in[5];          // [HD]
    const float* Wc       = (const float*)d_in[6];          // [3][HD][HD]
    const float* att_src  = (const float*)d_in[7];          // [3][HD]
    const float* att_dst  = (const float*)d_in[8];          // [3][HD]
    const float* bias_c   = (const float*)d_in[9];          // [3][HD]
    float* out = (float*)d_out;                              // [NN][HD]

    const int* src = ei;
    const int* dst = ei + NE;

    // workspace layout (16B-aligned blocks, ~44 MB)
    char* w = (char*)d_ws;
    ushort* hb      = (ushort*)w;  w += (size_t)NN * HD * 2;   // h residual (bf16)
    unsigned char* hp8 = (unsigned char*)w; w += (size_t)NN * HD; // hp (uint8 scaled)
    float2* asig    = (float2*)w;  w += (size_t)NN * 8;        // {as-dot, scale}
    ushort* mx      = (ushort*)w;  w += (size_t)NN * HD * 2;   // running max (bf16)
    float*  ad_     = (float*)w;   w += (size_t)NN * 4;
    int*    row_ptr = (int*)w;     w += (size_t)(NN + 4) * 4;
    unsigned int* cw = (unsigned int*)w; w += (size_t)NE * 4;  // packed col|bf16(ew)
    uint2*  epk     = (uint2*)w;   w += (size_t)NE * 8;
    int*    bhist   = (int*)w;     w += (size_t)NBK * NCHP * 4;
    int*    bbeg    = (int*)w;     w += (size_t)(NBK + 4) * 4;
    ushort* WTh     = (ushort*)w;  w += (size_t)(HD * FIN + 3 * HD * HD) * 2;
    ushort* WTl     = (ushort*)w;  w += (size_t)(HD * FIN + 3 * HD * HD) * 2;
    ushort* WlinTh = WTh,            *WlinTl = WTl;
    ushort* WcTh   = WTh + HD * FIN, *WcTl   = WTl + HD * FIN;

    const int TB = 256;
    const int nblk_w = NN / 16;                      // 3125 (16 nodes per block)
    const int nblk_g = (NN + 127) / 128;             // 391 (128 rows per block)
    const int nsplit = HD * FIN + 3 * HD * HD;       // all weight elements

    // ---- fused weight transpose + split (1 launch) ----
    k_split_all<<<(nsplit + TB - 1) / TB, TB, 0, stream>>>(Wlin, Wc, WTh, WTl);

    // ---- CSR build (atomic-reservation-free binning) ----
    k_bhist<<<NCH, 1024, 0, stream>>>(dst, bhist);
    k_bscan<<<1, 256, 0, stream>>>(bhist, bbeg, row_ptr);
    k_binscatter<<<NCH, 1024, 0, stream>>>(src, dst, ew, bhist, epk);
    k_build<<<NBK, 256, 0, stream>>>(epk, bbeg, row_ptr, cw);

    // ---- input projection: h = x @ Wlin + blin (bf16 out, fp32 A split) ----
    k_gemm_mfma<FIN, false, false, false><<<nblk_g, TB, 0, stream>>>(
        x, nullptr, WlinTh, WlinTl, blin, hb, nullptr,
        nullptr, nullptr, nullptr, nullptr, NN);

    // ---- 3 GAT layers (A = h bf16 exact -> 2-MFMA path; hp emitted uint8) ----
    for (int layer = 0; layer < 3; ++layer) {
        k_gemm_mfma<HD, true, true, true><<<nblk_g, TB, 0, stream>>>(
            nullptr, hb, WcTh + (size_t)layer * HD * HD, WcTl + (size_t)layer * HD * HD,
            nullptr, nullptr, hp8,
            att_src + layer * HD, att_dst + layer * HD, asig, ad_, NN);
        int mode = (layer == 0) ? 0 : (layer == 2 ? 2 : 1);
        k_agg<<<nblk_w, TB, 0, stream>>>(hp8, asig, hb, ad_, row_ptr, cw,
                                         bias_c + layer * HD, out, mx, mode);
    }
}

// Round 21
// 170.268 us; speedup vs baseline: 1.2425x; 1.0013x over previous
//
#include <hip/hip_runtime.h>
#include <cstdint>
#include <cstddef>

// Problem constants (from reference)
#define NN 50000
#define NE 800000
#define FIN 256
#define HD 128
#define NEG_SLOPE 0.2f

// CSR-build binning parameters
#define NBK 196          // buckets of 256 nodes: ceil(50000/256)
#define NCH 98           // edge chunks
#define NCHP 104         // padded chunk count (mult of 4 for int4 scan)
#define CHUNK 8192       // edges per chunk (98*8192 >= 800000)

typedef short s16x8 __attribute__((ext_vector_type(8)));   // 8 bf16 (4 VGPRs)
typedef float f32x4 __attribute__((ext_vector_type(4)));   // MFMA acc / nt stores

__device__ inline ushort f2bf(float f) {                   // fp32 -> bf16 RTN-even
    uint32_t u = __float_as_uint(f);
    u += 0x7FFFu + ((u >> 16) & 1u);
    return (ushort)(u >> 16);
}
__device__ inline float bf2f(ushort h) {
    return __uint_as_float(((uint32_t)h) << 16);
}

// ------------------------------------------------------------- CSR build
// bucket = dst >> 8. No global atomics anywhere.

__global__ __launch_bounds__(1024) void k_bhist(const int* __restrict__ dst,
                                                int* __restrict__ bhist) {
    __shared__ int hist[NBK];
    const int tid = threadIdx.x, blk = blockIdx.x;
    if (tid < NBK) hist[tid] = 0;
    __syncthreads();
    const int e0 = blk * CHUNK;
    #pragma unroll
    for (int u = 0; u < CHUNK / 1024; ++u) {
        int e = e0 + u * 1024 + tid;
        if (e < NE) atomicAdd(&hist[dst[e] >> 8], 1);
    }
    __syncthreads();
    if (tid < NBK) {
        bhist[tid * NCHP + blk] = hist[tid];
        if (blk == 0)                          // zero the scan padding once
            for (int c = NCH; c < NCHP; ++c) bhist[tid * NCHP + c] = 0;
    }
}

__global__ __launch_bounds__(256) void k_bscan(int* __restrict__ bhist,
                                               int* __restrict__ bbeg,
                                               int* __restrict__ row_ptr) {
    __shared__ int wsum[4];
    const int tid = threadIdx.x;
    int4 buf[NCHP / 4];
    int tot = 0;
    if (tid < NBK) {
        const int4* rp = reinterpret_cast<const int4*>(bhist + tid * NCHP);
        #pragma unroll
        for (int u = 0; u < NCHP / 4; ++u) buf[u] = rp[u];     // independent loads
        #pragma unroll
        for (int u = 0; u < NCHP / 4; ++u) {                   // exclusive scan in regs
            int4 v = buf[u], o;
            o.x = tot; tot += v.x;
            o.y = tot; tot += v.y;
            o.z = tot; tot += v.z;
            o.w = tot; tot += v.w;
            buf[u] = o;
        }
    }
    const int lane = tid & 63, wid = tid >> 6;
    int x = tot;
    #pragma unroll
    for (int o = 1; o < 64; o <<= 1) {
        int t = __shfl_up(x, o);
        if (lane >= o) x += t;
    }
    if (lane == 63) wsum[wid] = x;
    __syncthreads();
    int wo = 0;
    for (int k = 0; k < wid; ++k) wo += wsum[k];
    const int excl = x - tot + wo;                // bucket start offset
    if (tid < NBK) {
        bbeg[tid] = excl;
        int4* rp = reinterpret_cast<int4*>(bhist + tid * NCHP);
        #pragma unroll
        for (int u = 0; u < NCHP / 4; ++u) {
            int4 v = buf[u];
            v.x += excl; v.y += excl; v.z += excl; v.w += excl;
            rp[u] = v;
        }
    }
    if (tid == 0) { bbeg[NBK] = NE; row_ptr[NN] = NE; }
}

__global__ __launch_bounds__(1024) void k_binscatter(const int* __restrict__ src,
                                                     const int* __restrict__ dst,
                                                     const float* __restrict__ ew,
                                                     const int* __restrict__ bhist,
                                                     uint2* __restrict__ epk) {
    __shared__ int base[NBK];
    __shared__ int lcur[NBK];
    const int tid = threadIdx.x, blk = blockIdx.x;
    if (tid < NBK) { base[tid] = bhist[tid * NCHP + blk]; lcur[tid] = 0; }
    __syncthreads();
    const int e0 = blk * CHUNK;
    #pragma unroll
    for (int u = 0; u < CHUNK / 1024; ++u) {
        int e = e0 + u * 1024 + tid;
        if (e < NE) {
            int d = dst[e];
            int s = src[e];
            float w = ew[e];
            int b = d >> 8;
            int pos = base[b] + atomicAdd(&lcur[b], 1);   // LDS atomic only
            epk[pos] = make_uint2((uint32_t)s | ((uint32_t)(d & 255) << 16),
                                  __float_as_uint(w));
        }
    }
}

__global__ __launch_bounds__(256) void k_build(const uint2* __restrict__ epk,
                                               const int* __restrict__ bbeg,
                                               int* __restrict__ row_ptr,
                                               unsigned int* __restrict__ cw) {
    __shared__ int cnt[256];
    __shared__ int cur[256];
    __shared__ int wsum[4];
    const int tid = threadIdx.x, b = blockIdx.x;
    const int n0 = b << 8;
    const int ebeg = bbeg[b], eend = bbeg[b + 1];
    cnt[tid] = 0;
    __syncthreads();
    for (int e = ebeg + tid; e < eend; e += 256)
        atomicAdd(&cnt[(epk[e].x >> 16) & 255], 1);
    __syncthreads();
    const int v = cnt[tid];
    const int lane = tid & 63, wid = tid >> 6;
    int x = v;
    #pragma unroll
    for (int o = 1; o < 64; o <<= 1) {
        int t = __shfl_up(x, o);
        if (lane >= o) x += t;
    }
    if (lane == 63) wsum[wid] = x;
    __syncthreads();
    int wo = 0;
    for (int k = 0; k < wid; ++k) wo += wsum[k];
    const int excl = ebeg + x - v + wo;           // node segment start
    if (n0 + tid < NN) row_ptr[n0 + tid] = excl;
    cur[tid] = excl;
    __syncthreads();
    for (int e = ebeg + tid; e < eend; e += 256) {
        uint2 p = epk[e];
        int dl = (p.x >> 16) & 255;
        int pos = atomicAdd(&cur[dl], 1);
        // packed edge: low16 = src, high16 = bf16(edge_weight)
        cw[pos] = (p.x & 0xFFFFu) |
                  ((unsigned int)f2bf(__uint_as_float(p.y)) << 16);
    }
}

// -------------------------------------- fused weight transpose + bf16 split

__global__ void k_split_all(const float* __restrict__ Wlin,
                            const float* __restrict__ Wc,
                            ushort* __restrict__ Th, ushort* __restrict__ Tl) {
    int idx = blockIdx.x * blockDim.x + threadIdx.x;
    const int NLIN = HD * FIN;
    float f;
    if (idx < NLIN) {
        int n = idx / FIN, k = idx - n * FIN;
        f = Wlin[(size_t)k * HD + n];
    } else if (idx < NLIN + 3 * HD * HD) {
        int r = idx - NLIN;
        int l = r / (HD * HD);
        int rr = r - l * (HD * HD);
        int n = rr / HD, k = rr - n * HD;
        f = Wc[(size_t)l * HD * HD + (size_t)k * HD + n];
    } else return;
    ushort hi = f2bf(f);
    Th[idx] = hi;
    Tl[idx] = f2bf(f - bf2f(hi));
}

// ----------------------------------------------------- MFMA bf16 GEMM
// C[M][128] = A[M][K] @ B[K][128] (+bias), 16x16x32 bf16 MFMA.
// ABF16: A already bf16 (exact, 1 A-load) vs fp32 (split hi/lo in-flight).
// WLO:   weights carry a lo residual term (proj GEMM: ~fp32 weights) or
//        pure bf16 (layer GEMMs: hp is uint8-quantized downstream anyway,
//        so the 2^-9 weight rounding is absorbed by the 2^-8 quantizer).
// MFMA terms: Ah*Bh [+ Ah*Bl if WLO] [+ Al*Bh if !ABF16].
// OUT8: uint8 per-row-scaled out (u = rint(val*127/rowmax)+128);
//       asig[row] = {as-dot, rowmax/127}. Else bf16 out.
// B^T staged whole-BK=128 K-tile once into LDS (XOR-swizzled 16B chunks,
// 32 KB if !WLO, 64 KB if WLO), barrier-free main loop, 4 waves x 32 rows.

template <int K, bool ATT, bool ABF16, bool OUT8, bool WLO>
__global__ __launch_bounds__(256) void k_gemm_mfma(
    const float*  __restrict__ Af,     // fp32 A (ABF16=false)
    const ushort* __restrict__ Ab,     // bf16 A (ABF16=true)
    const ushort* __restrict__ Bh,     // [HD][K]
    const ushort* __restrict__ Bl,     // [HD][K] (WLO only)
    const float*  __restrict__ bias,   // null if none
    ushort*       __restrict__ Cb,     // bf16 out (OUT8=false)
    unsigned char* __restrict__ C8,    // uint8 out (OUT8=true)
    const float*  __restrict__ att_s, const float* __restrict__ att_d,
    float2* __restrict__ asig,         // {as-dot, scale} per row (ATT)
    float*  __restrict__ ad_,          // ad-dot per row (ATT)
    int M)
{
    constexpr int BK = 128;
    constexpr int NT = K / BK;
    __shared__ ushort Bs[WLO ? 32768 : 16384];    // hi [0..16383], lo +16384

    const int tid  = threadIdx.x;
    const int lane = tid & 63;
    const int wid  = tid >> 6;
    const int fl   = lane & 15;
    const int fg   = lane >> 4;
    const int rowBase = blockIdx.x * 128 + wid * 32;

    f32x4 acc[2][8] = {};

    for (int t = 0; t < NT; ++t) {
        if (t) __syncthreads();
        #pragma unroll
        for (int u = 0; u < 8; ++u) {
            const int id  = u * 256 + tid;
            const int bcol = id >> 4, c = id & 15;
            const size_t g = (size_t)bcol * K + t * BK + c * 8;
            const int lidx = bcol * 128 + ((c ^ (bcol & 15)) << 3);
            *reinterpret_cast<uint4*>(&Bs[lidx]) =
                *reinterpret_cast<const uint4*>(Bh + g);
            if (WLO)
                *reinterpret_cast<uint4*>(&Bs[16384 + lidx]) =
                    *reinterpret_cast<const uint4*>(Bl + g);
        }
        __syncthreads();

        #pragma unroll
        for (int kt = 0; kt < BK / 32; ++kt) {
            s16x8 a_h[2], a_l[2];
            #pragma unroll
            for (int rt = 0; rt < 2; ++rt) {
                int r = rowBase + rt * 16 + fl;
                if (r >= M) r = M - 1;            // harmless clamp (stores guarded)
                if (ABF16) {
                    a_h[rt] = *reinterpret_cast<const s16x8*>(
                        Ab + (size_t)r * K + t * BK + kt * 32 + fg * 8);
                } else {
                    const float* ap = Af + (size_t)r * K + t * BK + kt * 32 + fg * 8;
                    float4 t0 = *reinterpret_cast<const float4*>(ap);
                    float4 t1 = *reinterpret_cast<const float4*>(ap + 4);
                    float v[8] = {t0.x, t0.y, t0.z, t0.w, t1.x, t1.y, t1.z, t1.w};
                    #pragma unroll
                    for (int u = 0; u < 8; ++u) {
                        ushort h0 = f2bf(v[u]);
                        a_h[rt][u] = (short)h0;
                        a_l[rt][u] = (short)f2bf(v[u] - bf2f(h0));
                    }
                }
            }
            #pragma unroll
            for (int ct = 0; ct < 8; ++ct) {
                const int lidx = (ct * 16 + fl) * 128 + (((kt * 4 + fg) ^ fl) << 3);
                s16x8 b_h = *reinterpret_cast<const s16x8*>(&Bs[lidx]);
                #pragma unroll
                for (int rt = 0; rt < 2; ++rt) {
                    acc[rt][ct] = __builtin_amdgcn_mfma_f32_16x16x32_bf16(a_h[rt], b_h, acc[rt][ct], 0, 0, 0);
                    if (WLO) {
                        s16x8 b_l = *reinterpret_cast<const s16x8*>(&Bs[16384 + lidx]);
                        acc[rt][ct] = __builtin_amdgcn_mfma_f32_16x16x32_bf16(a_h[rt], b_l, acc[rt][ct], 0, 0, 0);
                    }
                    if (!ABF16)
                        acc[rt][ct] = __builtin_amdgcn_mfma_f32_16x16x32_bf16(a_l[rt], b_h, acc[rt][ct], 0, 0, 0);
                }
            }
        }
    }

    // ---- epilogue: C/D layout col = ct*16 + fl, row = base + fg*4 + reg ----
    float bval[8];
    #pragma unroll
    for (int ct = 0; ct < 8; ++ct) bval[ct] = bias ? bias[ct * 16 + fl] : 0.f;
    float asv[8], adv[8];
    if (ATT) {
        #pragma unroll
        for (int ct = 0; ct < 8; ++ct) {
            asv[ct] = att_s[ct * 16 + fl];
            adv[ct] = att_d[ct * 16 + fl];
        }
    }

    #pragma unroll
    for (int rt = 0; rt < 2; ++rt) {
        const int rbase = rowBase + rt * 16 + fg * 4;
        #pragma unroll
        for (int r = 0; r < 4; ++r) {
            const int row = rbase + r;
            const bool ok = row < M;
            float sv = 0.f, dv = 0.f, m = 0.f;
            float val[8];
            #pragma unroll
            for (int ct = 0; ct < 8; ++ct) {
                val[ct] = acc[rt][ct][r] + bval[ct];
                if (ATT) { sv = fmaf(val[ct], asv[ct], sv); dv = fmaf(val[ct], adv[ct], dv); }
                if (OUT8) m = fmaxf(m, fabsf(val[ct]));
            }
            if (OUT8) {
                #pragma unroll
                for (int o = 1; o < 16; o <<= 1) m = fmaxf(m, __shfl_xor(m, o));
                const float qs = 127.f / fmaxf(m, 1e-30f);
                #pragma unroll
                for (int ct = 0; ct < 8; ++ct) {
                    int qv = (int)rintf(val[ct] * qs);
                    qv = qv < -127 ? -127 : (qv > 127 ? 127 : qv);
                    if (ok) C8[(size_t)row * HD + ct * 16 + fl] =
                        (unsigned char)(qv + 128);           // biased uint8
                }
            } else {
                #pragma unroll
                for (int ct = 0; ct < 8; ++ct)
                    if (ok) Cb[(size_t)row * HD + ct * 16 + fl] = f2bf(val[ct]);
            }
            if (ATT) {
                #pragma unroll
                for (int o = 1; o < 16; o <<= 1) {
                    sv += __shfl_xor(sv, o);
                    dv += __shfl_xor(dv, o);
                }
                if (fl == 0 && ok) {
                    asig[row] = make_float2(sv, OUT8 ? m * (1.f / 127.f) : 0.f);
                    ad_[row]  = dv;
                }
            }
        }
    }
}

// ---------------------------------------------- fused softmax-aggregation
// One node per 16-LANE GROUP (4 nodes/wave). All 16 lanes of a group process
// every edge of their node (lane = feature octet) -> feature accumulators
// need no cross-lane folds; only dloc folds (4 shfls). Weight phase is
// lane-parallel over 16-edge passes; (s<<7, we) staged in wave-private LDS;
// 8 edges per batch in flight, edge count rounded up (zero slots = 0).
// hp uint8 per-row-scaled biased +128 (bias removed via 128*sum(we)).
// mode 0: h += agg (no out). mode 1: mx = bf16(max(h_old, h_new)), h += agg.
// mode 2: out = max(bf2f(mx), agg + b), nontemporal write-only out.

__device__ inline void acc8u(float wj, uint2 pv,
                             float& a0, float& a1, float& a2, float& a3,
                             float& a4, float& a5, float& a6, float& a7) {
    a0 = fmaf(wj, (float)( pv.x        & 0xFFu), a0);   // v_cvt_f32_ubyte0
    a1 = fmaf(wj, (float)((pv.x >>  8) & 0xFFu), a1);
    a2 = fmaf(wj, (float)((pv.x >> 16) & 0xFFu), a2);
    a3 = fmaf(wj, (float)( pv.x >> 24         ), a3);
    a4 = fmaf(wj, (float)( pv.y        & 0xFFu), a4);
    a5 = fmaf(wj, (float)((pv.y >>  8) & 0xFFu), a5);
    a6 = fmaf(wj, (float)((pv.y >> 16) & 0xFFu), a6);
    a7 = fmaf(wj, (float)( pv.y >> 24         ), a7);
}

__global__ __launch_bounds__(256) void k_agg(const unsigned char* __restrict__ hp8,
                                             const float2* __restrict__ asig,
                                             ushort* __restrict__ hb,
                                             const float* __restrict__ ad_,
                                             const int* __restrict__ row_ptr,
                                             const unsigned int* __restrict__ cw,
                                             const float* __restrict__ bias,
                                             float* __restrict__ out,
                                             ushort* __restrict__ mx, int mode) {
    __shared__ uint2 swb[4][64];       // per-wave staging: [wave][group*16+slot]
    const int wid  = threadIdx.x >> 6;
    const int lane = threadIdx.x & 63;
    const int g    = lane >> 4;        // group = node slot within wave
    const int hl   = lane & 15;        // feature octet within node row
    const int d    = blockIdx.x * 16 + wid * 4 + g;   // grid 3125 * 16 = NN exact
    const int beg = row_ptr[d], end = row_ptr[d + 1];
    const float adv = ad_[d];
    const int hlo = hl << 3;           // loop-invariant byte offset
    const int sb  = g << 4;            // group staging base

    float a0 = 0.f, a1 = 0.f, a2 = 0.f, a3 = 0.f;
    float a4 = 0.f, a5 = 0.f, a6 = 0.f, a7 = 0.f;
    float dloc = 0.f, wesum = 0.f;

    for (int base = beg; base < end; base += 16) {
        const int n = min(16, end - base);
        // ---- lane-parallel weight phase (one edge per lane) ----
        unsigned soff = 0; float w = 0.f, we = 0.f;
        if (hl < n) {
            unsigned int v = cw[base + hl];
            unsigned s = v & 0xFFFFu;
            float2 ag = asig[s];                   // {as-dot, row scale}
            float l = ag.x + adv;
            l = (l >= 0.f) ? l : NEG_SLOPE * l;
            l = fminf(l, 80.f);                    // overflow guard (no max pass)
            w  = __expf(l) * bf2f((ushort)(v >> 16));
            we = w * ag.y;                         // fold row scale into weight
            soff = s << 7;                         // byte offset of row
        }
        dloc += w;
        swb[wid][sb + hl] = make_uint2(soff, __float_as_uint(we));
        // zero-filled slots (hl >= n) contribute exactly 0 below

        const int nr = (n > 8) ? 16 : 8;           // round up: no tail branches
        for (int i = 0; i < nr; i += 8) {          // 8 edges in flight
            uint2 sw[8]; uint2 pv[8];
            #pragma unroll
            for (int j = 0; j < 8; ++j)
                sw[j] = swb[wid][sb + i + j];      // 16-lane broadcast read
            #pragma unroll
            for (int j = 0; j < 8; ++j)
                pv[j] = *reinterpret_cast<const uint2*>(hp8 + sw[j].x + hlo);
            #pragma unroll
            for (int j = 0; j < 8; ++j) {
                const float wj = __uint_as_float(sw[j].y);
                acc8u(wj, pv[j], a0, a1, a2, a3, a4, a5, a6, a7);
                wesum += wj;
            }
        }
    }
    // dloc: fold within the 16-lane group (weight phase was lane-parallel)
    #pragma unroll
    for (int o = 1; o < 16; o <<= 1) dloc += __shfl_xor(dloc, o);
    // a0..a7 and wesum are already complete per lane (broadcast accumulation)

    const float c = 128.f * wesum;             // remove the +128 bias exactly
    const float inv = 1.f / (dloc + 1e-16f);
    const int f0 = hl * 8;
    float r0 = (a0 - c) * inv + bias[f0 + 0], r1 = (a1 - c) * inv + bias[f0 + 1];
    float r2 = (a2 - c) * inv + bias[f0 + 2], r3 = (a3 - c) * inv + bias[f0 + 3];
    float r4 = (a4 - c) * inv + bias[f0 + 4], r5 = (a5 - c) * inv + bias[f0 + 5];
    float r6 = (a6 - c) * inv + bias[f0 + 6], r7 = (a7 - c) * inv + bias[f0 + 7];

    if (mode == 2) {
        uint4 mv = *reinterpret_cast<const uint4*>(mx + (size_t)d * HD + f0);
        f32x4 o0, o1;
        o0[0] = fmaxf(bf2f((ushort)mv.x),         r0);
        o0[1] = fmaxf(bf2f((ushort)(mv.x >> 16)), r1);
        o0[2] = fmaxf(bf2f((ushort)mv.y),         r2);
        o0[3] = fmaxf(bf2f((ushort)(mv.y >> 16)), r3);
        o1[0] = fmaxf(bf2f((ushort)mv.z),         r4);
        o1[1] = fmaxf(bf2f((ushort)(mv.z >> 16)), r5);
        o1[2] = fmaxf(bf2f((ushort)mv.w),         r6);
        o1[3] = fmaxf(bf2f((ushort)(mv.w >> 16)), r7);
        f32x4* outp = reinterpret_cast<f32x4*>(out + (size_t)d * HD + f0);
        __builtin_nontemporal_store(o0, outp);       // write-only final output:
        __builtin_nontemporal_store(o1, outp + 1);   // don't pollute L2
    } else {
        uint4* hp = reinterpret_cast<uint4*>(hb + (size_t)d * HD + f0);
        uint4 hv = *hp;
        float h0 = bf2f((ushort)hv.x), h1 = bf2f((ushort)(hv.x >> 16));
        float h2 = bf2f((ushort)hv.y), h3 = bf2f((ushort)(hv.y >> 16));
        float h4 = bf2f((ushort)hv.z), h5 = bf2f((ushort)(hv.z >> 16));
        float h6 = bf2f((ushort)hv.w), h7 = bf2f((ushort)(hv.w >> 16));
        float n0 = h0 + r0, n1 = h1 + r1, n2 = h2 + r2, n3 = h3 + r3;
        float n4 = h4 + r4, n5 = h5 + r5, n6 = h6 + r6, n7 = h7 + r7;
        uint4 st;
        st.x = (uint32_t)f2bf(n0) | ((uint32_t)f2bf(n1) << 16);
        st.y = (uint32_t)f2bf(n2) | ((uint32_t)f2bf(n3) << 16);
        st.z = (uint32_t)f2bf(n4) | ((uint32_t)f2bf(n5) << 16);
        st.w = (uint32_t)f2bf(n6) | ((uint32_t)f2bf(n7) << 16);
        *hp = st;
        if (mode == 1) {                        // mx = bf16(max(h1, h2))
            uint4 sm;
            sm.x = (uint32_t)f2bf(fmaxf(h0, n0)) | ((uint32_t)f2bf(fmaxf(h1, n1)) << 16);
            sm.y = (uint32_t)f2bf(fmaxf(h2, n2)) | ((uint32_t)f2bf(fmaxf(h3, n3)) << 16);
            sm.z = (uint32_t)f2bf(fmaxf(h4, n4)) | ((uint32_t)f2bf(fmaxf(h5, n5)) << 16);
            sm.w = (uint32_t)f2bf(fmaxf(h6, n6)) | ((uint32_t)f2bf(fmaxf(h7, n7)) << 16);
            *reinterpret_cast<uint4*>(mx + (size_t)d * HD + f0) = sm;
        }
    }
}

// ---------------------------------------------------------------- launch

extern "C" void kernel_launch(void* const* d_in, const int* in_sizes, int n_in,
                              void* d_out, int out_size, void* d_ws, size_t ws_size,
                              hipStream_t stream) {
    const float* x        = (const float*)d_in[0];          // [NN][FIN]
    const int*   ei       = (const int*)d_in[1];            // [2][NE]
    const float* ew       = (const float*)d_in[2];          // [NE]
    /* d_in[3] = numNode scalar = NN */
    const float* Wlin     = (const float*)d_in[4];          // [FIN][HD]
    const float* blin     = (const float*)d_in[5];          // [HD]
    const float* Wc       = (const float*)d_in[6];          // [3][HD][HD]
    const float* att_src  = (const float*)d_in[7];          // [3][HD]
    const float* att_dst  = (const float*)d_in[8];          // [3][HD]
    const float* bias_c   = (const float*)d_in[9];          // [3][HD]
    float* out = (float*)d_out;                              // [NN][HD]

    const int* src = ei;
    const int* dst = ei + NE;

    // workspace layout (16B-aligned blocks, ~44 MB)
    char* w = (char*)d_ws;
    ushort* hb      = (ushort*)w;  w += (size_t)NN * HD * 2;   // h residual (bf16)
    unsigned char* hp8 = (unsigned char*)w; w += (size_t)NN * HD; // hp (uint8 scaled)
    float2* asig    = (float2*)w;  w += (size_t)NN * 8;        // {as-dot, scale}
    ushort* mx      = (ushort*)w;  w += (size_t)NN * HD * 2;   // running max (bf16)
    float*  ad_     = (float*)w;   w += (size_t)NN * 4;
    int*    row_ptr = (int*)w;     w += (size_t)(NN + 4) * 4;
    unsigned int* cw = (unsigned int*)w; w += (size_t)NE * 4;  // packed col|bf16(ew)
    uint2*  epk     = (uint2*)w;   w += (size_t)NE * 8;
    int*    bhist   = (int*)w;     w += (size_t)NBK * NCHP * 4;
    int*    bbeg    = (int*)w;     w += (size_t)(NBK + 4) * 4;
    ushort* WTh     = (ushort*)w;  w += (size_t)(HD * FIN + 3 * HD * HD) * 2;
    ushort* WTl     = (ushort*)w;  w += (size_t)(HD * FIN + 3 * HD * HD) * 2;
    ushort* WlinTh = WTh,            *WlinTl = WTl;
    ushort* WcTh   = WTh + HD * FIN, *WcTl   = WTl + HD * FIN;

    const int TB = 256;
    const int nblk_w = NN / 16;                      // 3125 (16 nodes per block)
    const int nblk_g = (NN + 127) / 128;             // 391 (128 rows per block)
    const int nsplit = HD * FIN + 3 * HD * HD;       // all weight elements

    // ---- fused weight transpose + split (1 launch) ----
    k_split_all<<<(nsplit + TB - 1) / TB, TB, 0, stream>>>(Wlin, Wc, WTh, WTl);

    // ---- CSR build (atomic-reservation-free binning) ----
    k_bhist<<<NCH, 1024, 0, stream>>>(dst, bhist);
    k_bscan<<<1, 256, 0, stream>>>(bhist, bbeg, row_ptr);
    k_binscatter<<<NCH, 1024, 0, stream>>>(src, dst, ew, bhist, epk);
    k_build<<<NBK, 256, 0, stream>>>(epk, bbeg, row_ptr, cw);

    // ---- input projection: h = x @ Wlin + blin (bf16 out, 3-term split) ----
    k_gemm_mfma<FIN, false, false, false, true><<<nblk_g, TB, 0, stream>>>(
        x, nullptr, WlinTh, WlinTl, blin, hb, nullptr,
        nullptr, nullptr, nullptr, nullptr, NN);

    // ---- 3 GAT layers: A = h bf16 exact, W pure bf16 -> single MFMA term;
    //      hp emitted uint8 (quantizer absorbs the 2^-9 weight rounding) ----
    for (int layer = 0; layer < 3; ++layer) {
        k_gemm_mfma<HD, true, true, true, false><<<nblk_g, TB, 0, stream>>>(
            nullptr, hb, WcTh + (size_t)layer * HD * HD, nullptr,
            nullptr, nullptr, hp8,
            att_src + layer * HD, att_dst + layer * HD, asig, ad_, NN);
        int mode = (layer == 0) ? 0 : (layer == 2 ? 2 : 1);
        k_agg<<<nblk_w, TB, 0, stream>>>(hp8, asig, hb, ad_, row_ptr, cw,
                                         bias_c + layer * HD, out, mx, mode);
    }
}

// Round 22
// 149.004 us; speedup vs baseline: 1.4198x; 1.1427x over previous
//
#include <hip/hip_runtime.h>
#include <cstdint>
#include <cstddef>

// Problem constants (from reference)
#define NN 50000
#define NE 800000
#define FIN 256
#define HD 128
#define NEG_SLOPE 0.2f

// CSR-build binning parameters
#define NBK 196          // buckets of 256 nodes: ceil(50000/256)
#define NCH 98           // edge chunks
#define NCHP 104         // padded chunk count (mult of 4 for int4 scan)
#define CHUNK 8192       // edges per chunk (98*8192 >= 800000)
#define NSPLIT (HD * FIN + 3 * HD * HD)   // 81920 weight elements
#define NSB 80           // split blocks at 1024 threads (81920/1024)
#define NGP 391          // proj-GEMM blocks (128 rows each)

typedef short s16x8 __attribute__((ext_vector_type(8)));   // 8 bf16 (4 VGPRs)
typedef float f32x4 __attribute__((ext_vector_type(4)));   // MFMA acc / nt stores

__device__ inline ushort f2bf(float f) {                   // fp32 -> bf16 RTN-even
    uint32_t u = __float_as_uint(f);
    u += 0x7FFFu + ((u >> 16) & 1u);
    return (ushort)(u >> 16);
}
__device__ inline float bf2f(ushort h) {
    return __uint_as_float(((uint32_t)h) << 16);
}

// ------------------------------------------- fused bhist + weight split
// blocks [0, NCH): per-chunk LDS histogram of dst buckets -> bhist[bucket][chunk]
// blocks [NCH, NCH+NSB): weight transpose + bf16 hi/lo split (independent work)

__global__ __launch_bounds__(1024) void k_pre(const int* __restrict__ dst,
                                              int* __restrict__ bhist,
                                              const float* __restrict__ Wlin,
                                              const float* __restrict__ Wc,
                                              ushort* __restrict__ Th,
                                              ushort* __restrict__ Tl) {
    __shared__ int hist[NBK];
    const int tid = threadIdx.x;
    if (blockIdx.x < NCH) {
        const int blk = blockIdx.x;
        if (tid < NBK) hist[tid] = 0;
        __syncthreads();
        const int e0 = blk * CHUNK;
        #pragma unroll
        for (int u = 0; u < CHUNK / 1024; ++u) {
            int e = e0 + u * 1024 + tid;
            if (e < NE) atomicAdd(&hist[dst[e] >> 8], 1);
        }
        __syncthreads();
        if (tid < NBK) {
            bhist[tid * NCHP + blk] = hist[tid];
            if (blk == 0)                      // zero the scan padding once
                for (int c = NCH; c < NCHP; ++c) bhist[tid * NCHP + c] = 0;
        }
    } else {
        int idx = (blockIdx.x - NCH) * 1024 + tid;
        if (idx >= NSPLIT) return;
        const int NLIN = HD * FIN;
        float f;
        if (idx < NLIN) {
            int n = idx / FIN, k = idx - n * FIN;
            f = Wlin[(size_t)k * HD + n];
        } else {
            int r = idx - NLIN;
            int l = r / (HD * HD);
            int rr = r - l * (HD * HD);
            int n = rr / HD, k = rr - n * HD;
            f = Wc[(size_t)l * HD * HD + (size_t)k * HD + n];
        }
        ushort hi = f2bf(f);
        Th[idx] = hi;
        Tl[idx] = f2bf(f - bf2f(hi));
    }
}

__global__ __launch_bounds__(256) void k_bscan(int* __restrict__ bhist,
                                               int* __restrict__ bbeg,
                                               int* __restrict__ row_ptr) {
    __shared__ int wsum[4];
    const int tid = threadIdx.x;
    int4 buf[NCHP / 4];
    int tot = 0;
    if (tid < NBK) {
        const int4* rp = reinterpret_cast<const int4*>(bhist + tid * NCHP);
        #pragma unroll
        for (int u = 0; u < NCHP / 4; ++u) buf[u] = rp[u];     // independent loads
        #pragma unroll
        for (int u = 0; u < NCHP / 4; ++u) {                   // exclusive scan in regs
            int4 v = buf[u], o;
            o.x = tot; tot += v.x;
            o.y = tot; tot += v.y;
            o.z = tot; tot += v.z;
            o.w = tot; tot += v.w;
            buf[u] = o;
        }
    }
    const int lane = tid & 63, wid = tid >> 6;
    int x = tot;
    #pragma unroll
    for (int o = 1; o < 64; o <<= 1) {
        int t = __shfl_up(x, o);
        if (lane >= o) x += t;
    }
    if (lane == 63) wsum[wid] = x;
    __syncthreads();
    int wo = 0;
    for (int k = 0; k < wid; ++k) wo += wsum[k];
    const int excl = x - tot + wo;                // bucket start offset
    if (tid < NBK) {
        bbeg[tid] = excl;
        int4* rp = reinterpret_cast<int4*>(bhist + tid * NCHP);
        #pragma unroll
        for (int u = 0; u < NCHP / 4; ++u) {
            int4 v = buf[u];
            v.x += excl; v.y += excl; v.z += excl; v.w += excl;
            rp[u] = v;
        }
    }
    if (tid == 0) { bbeg[NBK] = NE; row_ptr[NN] = NE; }
}

// --------------------------- fused proj GEMM + binscatter (independent work)
// blocks [0, NGP): h = x @ Wlin + blin (K=256, fp32 A hi/lo split, weight
//   hi+lo terms, bf16 out) -- the round-8-lineage single-stage-B structure.
// blocks [NGP, NGP+NCH): binscatter chunk (256 threads, 32 iters), LDS
//   cursors carved from the GEMM's shared buffer.

__global__ __launch_bounds__(256) void k_gemmproj_scatter(
    const float*  __restrict__ x,
    const ushort* __restrict__ Bh,     // WlinT hi [HD][FIN]
    const ushort* __restrict__ Bl,     // WlinT lo
    const float*  __restrict__ bias,   // blin
    ushort*       __restrict__ Cb,     // hb (bf16 out)
    const int*    __restrict__ src,
    const int*    __restrict__ dst,
    const float*  __restrict__ ew,
    const int*    __restrict__ bhist,
    uint2*        __restrict__ epk,
    int M)
{
    __shared__ ushort Bs[32768];                  // 64 KB (GEMM); scatter reuses
    const int tid = threadIdx.x;

    if (blockIdx.x < NGP) {
        // ---------------- proj GEMM block ----------------
        constexpr int K = FIN, BK = 128;
        const int lane = tid & 63;
        const int wid  = tid >> 6;
        const int fl   = lane & 15;
        const int fg   = lane >> 4;
        const int rowBase = blockIdx.x * 128 + wid * 32;

        f32x4 acc[2][8] = {};

        for (int t = 0; t < K / BK; ++t) {
            if (t) __syncthreads();
            #pragma unroll
            for (int u = 0; u < 8; ++u) {
                const int id  = u * 256 + tid;
                const int bcol = id >> 4, c = id & 15;
                const size_t g = (size_t)bcol * K + t * BK + c * 8;
                const int lidx = bcol * 128 + ((c ^ (bcol & 15)) << 3);
                *reinterpret_cast<uint4*>(&Bs[lidx]) =
                    *reinterpret_cast<const uint4*>(Bh + g);
                *reinterpret_cast<uint4*>(&Bs[16384 + lidx]) =
                    *reinterpret_cast<const uint4*>(Bl + g);
            }
            __syncthreads();

            #pragma unroll
            for (int kt = 0; kt < BK / 32; ++kt) {
                s16x8 a_h[2], a_l[2];
                #pragma unroll
                for (int rt = 0; rt < 2; ++rt) {
                    int r = rowBase + rt * 16 + fl;
                    if (r >= M) r = M - 1;        // harmless clamp (stores guarded)
                    const float* ap = x + (size_t)r * K + t * BK + kt * 32 + fg * 8;
                    float4 t0 = *reinterpret_cast<const float4*>(ap);
                    float4 t1 = *reinterpret_cast<const float4*>(ap + 4);
                    float v[8] = {t0.x, t0.y, t0.z, t0.w, t1.x, t1.y, t1.z, t1.w};
                    #pragma unroll
                    for (int u = 0; u < 8; ++u) {
                        ushort h0 = f2bf(v[u]);
                        a_h[rt][u] = (short)h0;
                        a_l[rt][u] = (short)f2bf(v[u] - bf2f(h0));
                    }
                }
                #pragma unroll
                for (int ct = 0; ct < 8; ++ct) {
                    const int lidx = (ct * 16 + fl) * 128 + (((kt * 4 + fg) ^ fl) << 3);
                    s16x8 b_h = *reinterpret_cast<const s16x8*>(&Bs[lidx]);
                    s16x8 b_l = *reinterpret_cast<const s16x8*>(&Bs[16384 + lidx]);
                    #pragma unroll
                    for (int rt = 0; rt < 2; ++rt) {
                        acc[rt][ct] = __builtin_amdgcn_mfma_f32_16x16x32_bf16(a_h[rt], b_h, acc[rt][ct], 0, 0, 0);
                        acc[rt][ct] = __builtin_amdgcn_mfma_f32_16x16x32_bf16(a_h[rt], b_l, acc[rt][ct], 0, 0, 0);
                        acc[rt][ct] = __builtin_amdgcn_mfma_f32_16x16x32_bf16(a_l[rt], b_h, acc[rt][ct], 0, 0, 0);
                    }
                }
            }
        }

        float bval[8];
        #pragma unroll
        for (int ct = 0; ct < 8; ++ct) bval[ct] = bias[ct * 16 + fl];
        #pragma unroll
        for (int rt = 0; rt < 2; ++rt) {
            const int rbase = rowBase + rt * 16 + fg * 4;
            #pragma unroll
            for (int r = 0; r < 4; ++r) {
                const int row = rbase + r;
                if (row >= M) continue;
                #pragma unroll
                for (int ct = 0; ct < 8; ++ct)
                    Cb[(size_t)row * HD + ct * 16 + fl] = f2bf(acc[rt][ct][r] + bval[ct]);
            }
        }
    } else {
        // ---------------- binscatter chunk ----------------
        int* base = reinterpret_cast<int*>(Bs);          // [NBK]
        int* lcur = reinterpret_cast<int*>(Bs) + NBK;    // [NBK]
        const int blk = blockIdx.x - NGP;
        if (tid < NBK) { base[tid] = bhist[tid * NCHP + blk]; lcur[tid] = 0; }
        __syncthreads();
        const int e0 = blk * CHUNK;
        #pragma unroll
        for (int u = 0; u < CHUNK / 256; ++u) {
            int e = e0 + u * 256 + tid;
            if (e < NE) {
                int d = dst[e];
                int s = src[e];
                float w = ew[e];
                int b = d >> 8;
                int pos = base[b] + atomicAdd(&lcur[b], 1);   // LDS atomic only
                epk[pos] = make_uint2((uint32_t)s | ((uint32_t)(d & 255) << 16),
                                      __float_as_uint(w));
            }
        }
    }
}

__global__ __launch_bounds__(256) void k_build(const uint2* __restrict__ epk,
                                               const int* __restrict__ bbeg,
                                               int* __restrict__ row_ptr,
                                               unsigned int* __restrict__ cw) {
    __shared__ int cnt[256];
    __shared__ int cur[256];
    __shared__ int wsum[4];
    const int tid = threadIdx.x, b = blockIdx.x;
    const int n0 = b << 8;
    const int ebeg = bbeg[b], eend = bbeg[b + 1];
    cnt[tid] = 0;
    __syncthreads();
    for (int e = ebeg + tid; e < eend; e += 256)
        atomicAdd(&cnt[(epk[e].x >> 16) & 255], 1);
    __syncthreads();
    const int v = cnt[tid];
    const int lane = tid & 63, wid = tid >> 6;
    int x = v;
    #pragma unroll
    for (int o = 1; o < 64; o <<= 1) {
        int t = __shfl_up(x, o);
        if (lane >= o) x += t;
    }
    if (lane == 63) wsum[wid] = x;
    __syncthreads();
    int wo = 0;
    for (int k = 0; k < wid; ++k) wo += wsum[k];
    const int excl = ebeg + x - v + wo;           // node segment start
    if (n0 + tid < NN) row_ptr[n0 + tid] = excl;
    cur[tid] = excl;
    __syncthreads();
    for (int e = ebeg + tid; e < eend; e += 256) {
        uint2 p = epk[e];
        int dl = (p.x >> 16) & 255;
        int pos = atomicAdd(&cur[dl], 1);
        // packed edge: low16 = src, high16 = bf16(edge_weight)
        cw[pos] = (p.x & 0xFFFFu) |
                  ((unsigned int)f2bf(__uint_as_float(p.y)) << 16);
    }
}

// ----------------------------------------------------- MFMA bf16 layer GEMM
// C[M][128] = A[M][128] @ B[128][128], A bf16 exact (1 A-load, 1 MFMA term;
// W pure bf16: hp is uint8-quantized downstream so 2^-9 weight rounding is
// absorbed). Out: uint8 per-row-scaled (u = rint(val*127/rowmax)+128);
// asig[row] = {as-dot, rowmax/127}; ad_[row] = ad-dot. 32 KB LDS B tile,
// barrier-free main loop, 4 waves x 32 rows, grid 391.

__global__ __launch_bounds__(256) void k_gemm_layer(
    const ushort* __restrict__ Ab,     // bf16 A (hb)
    const ushort* __restrict__ Bh,     // [HD][HD]
    unsigned char* __restrict__ C8,    // uint8 out
    const float*  __restrict__ att_s, const float* __restrict__ att_d,
    float2* __restrict__ asig,
    float*  __restrict__ ad_,
    int M)
{
    constexpr int K = HD;
    __shared__ ushort Bs[16384];                  // 32 KB

    const int tid  = threadIdx.x;
    const int lane = tid & 63;
    const int wid  = tid >> 6;
    const int fl   = lane & 15;
    const int fg   = lane >> 4;
    const int rowBase = blockIdx.x * 128 + wid * 32;

    f32x4 acc[2][8] = {};

    #pragma unroll
    for (int u = 0; u < 8; ++u) {
        const int id  = u * 256 + tid;
        const int bcol = id >> 4, c = id & 15;
        const size_t g = (size_t)bcol * K + c * 8;
        const int lidx = bcol * 128 + ((c ^ (bcol & 15)) << 3);
        *reinterpret_cast<uint4*>(&Bs[lidx]) =
            *reinterpret_cast<const uint4*>(Bh + g);
    }
    __syncthreads();

    #pragma unroll
    for (int kt = 0; kt < 4; ++kt) {
        s16x8 a_h[2];
        #pragma unroll
        for (int rt = 0; rt < 2; ++rt) {
            int r = rowBase + rt * 16 + fl;
            if (r >= M) r = M - 1;                // harmless clamp (stores guarded)
            a_h[rt] = *reinterpret_cast<const s16x8*>(
                Ab + (size_t)r * K + kt * 32 + fg * 8);
        }
        #pragma unroll
        for (int ct = 0; ct < 8; ++ct) {
            const int lidx = (ct * 16 + fl) * 128 + (((kt * 4 + fg) ^ fl) << 3);
            s16x8 b_h = *reinterpret_cast<const s16x8*>(&Bs[lidx]);
            #pragma unroll
            for (int rt = 0; rt < 2; ++rt)
                acc[rt][ct] = __builtin_amdgcn_mfma_f32_16x16x32_bf16(a_h[rt], b_h, acc[rt][ct], 0, 0, 0);
        }
    }

    float asv[8], adv[8];
    #pragma unroll
    for (int ct = 0; ct < 8; ++ct) {
        asv[ct] = att_s[ct * 16 + fl];
        adv[ct] = att_d[ct * 16 + fl];
    }

    #pragma unroll
    for (int rt = 0; rt < 2; ++rt) {
        const int rbase = rowBase + rt * 16 + fg * 4;
        #pragma unroll
        for (int r = 0; r < 4; ++r) {
            const int row = rbase + r;
            const bool ok = row < M;
            float sv = 0.f, dv = 0.f, m = 0.f;
            float val[8];
            #pragma unroll
            for (int ct = 0; ct < 8; ++ct) {
                val[ct] = acc[rt][ct][r];
                sv = fmaf(val[ct], asv[ct], sv);
                dv = fmaf(val[ct], adv[ct], dv);
                m = fmaxf(m, fabsf(val[ct]));
            }
            #pragma unroll
            for (int o = 1; o < 16; o <<= 1) m = fmaxf(m, __shfl_xor(m, o));
            const float qs = 127.f / fmaxf(m, 1e-30f);
            #pragma unroll
            for (int ct = 0; ct < 8; ++ct) {
                int qv = (int)rintf(val[ct] * qs);
                qv = qv < -127 ? -127 : (qv > 127 ? 127 : qv);
                if (ok) C8[(size_t)row * HD + ct * 16 + fl] =
                    (unsigned char)(qv + 128);               // biased uint8
            }
            #pragma unroll
            for (int o = 1; o < 16; o <<= 1) {
                sv += __shfl_xor(sv, o);
                dv += __shfl_xor(dv, o);
            }
            if (fl == 0 && ok) {
                asig[row] = make_float2(sv, m * (1.f / 127.f));
                ad_[row]  = dv;
            }
        }
    }
}

// ---------------------------------------------- fused softmax-aggregation
// One node per 16-LANE GROUP (4 nodes/wave). All 16 lanes of a group process
// every edge of their node (lane = feature octet) -> feature accumulators
// need no cross-lane folds; only dloc folds (4 shfls). Weight phase is
// lane-parallel over 16-edge passes; (s<<7, we) staged in wave-private LDS;
// 8 edges per batch in flight, edge count rounded up (zero slots = 0).
// hp uint8 per-row-scaled biased +128 (bias removed via 128*sum(we)).
// mode 0: h += agg (no out). mode 1: mx = bf16(max(h_old, h_new)), h += agg.
// mode 2: out = max(bf2f(mx), agg + b), nontemporal write-only out.

__device__ inline void acc8u(float wj, uint2 pv,
                             float& a0, float& a1, float& a2, float& a3,
                             float& a4, float& a5, float& a6, float& a7) {
    a0 = fmaf(wj, (float)( pv.x        & 0xFFu), a0);   // v_cvt_f32_ubyte0
    a1 = fmaf(wj, (float)((pv.x >>  8) & 0xFFu), a1);
    a2 = fmaf(wj, (float)((pv.x >> 16) & 0xFFu), a2);
    a3 = fmaf(wj, (float)( pv.x >> 24         ), a3);
    a4 = fmaf(wj, (float)( pv.y        & 0xFFu), a4);
    a5 = fmaf(wj, (float)((pv.y >>  8) & 0xFFu), a5);
    a6 = fmaf(wj, (float)((pv.y >> 16) & 0xFFu), a6);
    a7 = fmaf(wj, (float)( pv.y >> 24         ), a7);
}

__global__ __launch_bounds__(256) void k_agg(const unsigned char* __restrict__ hp8,
                                             const float2* __restrict__ asig,
                                             ushort* __restrict__ hb,
                                             const float* __restrict__ ad_,
                                             const int* __restrict__ row_ptr,
                                             const unsigned int* __restrict__ cw,
                                             const float* __restrict__ bias,
                                             float* __restrict__ out,
                                             ushort* __restrict__ mx, int mode) {
    __shared__ uint2 swb[4][64];       // per-wave staging: [wave][group*16+slot]
    const int wid  = threadIdx.x >> 6;
    const int lane = threadIdx.x & 63;
    const int g    = lane >> 4;        // group = node slot within wave
    const int hl   = lane & 15;        // feature octet within node row
    const int d    = blockIdx.x * 16 + wid * 4 + g;   // grid 3125 * 16 = NN exact
    const int beg = row_ptr[d], end = row_ptr[d + 1];
    const float adv = ad_[d];
    const int hlo = hl << 3;           // loop-invariant byte offset
    const int sb  = g << 4;            // group staging base

    float a0 = 0.f, a1 = 0.f, a2 = 0.f, a3 = 0.f;
    float a4 = 0.f, a5 = 0.f, a6 = 0.f, a7 = 0.f;
    float dloc = 0.f, wesum = 0.f;

    for (int base = beg; base < end; base += 16) {
        const int n = min(16, end - base);
        // ---- lane-parallel weight phase (one edge per lane) ----
        unsigned soff = 0; float w = 0.f, we = 0.f;
        if (hl < n) {
            unsigned int v = cw[base + hl];
            unsigned s = v & 0xFFFFu;
            float2 ag = asig[s];                   // {as-dot, row scale}
            float l = ag.x + adv;
            l = (l >= 0.f) ? l : NEG_SLOPE * l;
            l = fminf(l, 80.f);                    // overflow guard (no max pass)
            w  = __expf(l) * bf2f((ushort)(v >> 16));
            we = w * ag.y;                         // fold row scale into weight
            soff = s << 7;                         // byte offset of row
        }
        dloc += w;
        swb[wid][sb + hl] = make_uint2(soff, __float_as_uint(we));
        // zero-filled slots (hl >= n) contribute exactly 0 below

        const int nr = (n > 8) ? 16 : 8;           // round up: no tail branches
        for (int i = 0; i < nr; i += 8) {          // 8 edges in flight
            uint2 sw[8]; uint2 pv[8];
            #pragma unroll
            for (int j = 0; j < 8; ++j)
                sw[j] = swb[wid][sb + i + j];      // 16-lane broadcast read
            #pragma unroll
            for (int j = 0; j < 8; ++j)
                pv[j] = *reinterpret_cast<const uint2*>(hp8 + sw[j].x + hlo);
            #pragma unroll
            for (int j = 0; j < 8; ++j) {
                const float wj = __uint_as_float(sw[j].y);
                acc8u(wj, pv[j], a0, a1, a2, a3, a4, a5, a6, a7);
                wesum += wj;
            }
        }
    }
    // dloc: fold within the 16-lane group (weight phase was lane-parallel)
    #pragma unroll
    for (int o = 1; o < 16; o <<= 1) dloc += __shfl_xor(dloc, o);
    // a0..a7 and wesum are already complete per lane (broadcast accumulation)

    const float c = 128.f * wesum;             // remove the +128 bias exactly
    const float inv = 1.f / (dloc + 1e-16f);
    const int f0 = hl * 8;
    float r0 = (a0 - c) * inv + bias[f0 + 0], r1 = (a1 - c) * inv + bias[f0 + 1];
    float r2 = (a2 - c) * inv + bias[f0 + 2], r3 = (a3 - c) * inv + bias[f0 + 3];
    float r4 = (a4 - c) * inv + bias[f0 + 4], r5 = (a5 - c) * inv + bias[f0 + 5];
    float r6 = (a6 - c) * inv + bias[f0 + 6], r7 = (a7 - c) * inv + bias[f0 + 7];

    if (mode == 2) {
        uint4 mv = *reinterpret_cast<const uint4*>(mx + (size_t)d * HD + f0);
        f32x4 o0, o1;
        o0[0] = fmaxf(bf2f((ushort)mv.x),         r0);
        o0[1] = fmaxf(bf2f((ushort)(mv.x >> 16)), r1);
        o0[2] = fmaxf(bf2f((ushort)mv.y),         r2);
        o0[3] = fmaxf(bf2f((ushort)(mv.y >> 16)), r3);
        o1[0] = fmaxf(bf2f((ushort)mv.z),         r4);
        o1[1] = fmaxf(bf2f((ushort)(mv.z >> 16)), r5);
        o1[2] = fmaxf(bf2f((ushort)mv.w),         r6);
        o1[3] = fmaxf(bf2f((ushort)(mv.w >> 16)), r7);
        f32x4* outp = reinterpret_cast<f32x4*>(out + (size_t)d * HD + f0);
        __builtin_nontemporal_store(o0, outp);       // write-only final output:
        __builtin_nontemporal_store(o1, outp + 1);   // don't pollute L2
    } else {
        uint4* hp = reinterpret_cast<uint4*>(hb + (size_t)d * HD + f0);
        uint4 hv = *hp;
        float h0 = bf2f((ushort)hv.x), h1 = bf2f((ushort)(hv.x >> 16));
        float h2 = bf2f((ushort)hv.y), h3 = bf2f((ushort)(hv.y >> 16));
        float h4 = bf2f((ushort)hv.z), h5 = bf2f((ushort)(hv.z >> 16));
        float h6 = bf2f((ushort)hv.w), h7 = bf2f((ushort)(hv.w >> 16));
        float n0 = h0 + r0, n1 = h1 + r1, n2 = h2 + r2, n3 = h3 + r3;
        float n4 = h4 + r4, n5 = h5 + r5, n6 = h6 + r6, n7 = h7 + r7;
        uint4 st;
        st.x = (uint32_t)f2bf(n0) | ((uint32_t)f2bf(n1) << 16);
        st.y = (uint32_t)f2bf(n2) | ((uint32_t)f2bf(n3) << 16);
        st.z = (uint32_t)f2bf(n4) | ((uint32_t)f2bf(n5) << 16);
        st.w = (uint32_t)f2bf(n6) | ((uint32_t)f2bf(n7) << 16);
        *hp = st;
        if (mode == 1) {                        // mx = bf16(max(h1, h2))
            uint4 sm;
            sm.x = (uint32_t)f2bf(fmaxf(h0, n0)) | ((uint32_t)f2bf(fmaxf(h1, n1)) << 16);
            sm.y = (uint32_t)f2bf(fmaxf(h2, n2)) | ((uint32_t)f2bf(fmaxf(h3, n3)) << 16);
            sm.z = (uint32_t)f2bf(fmaxf(h4, n4)) | ((uint32_t)f2bf(fmaxf(h5, n5)) << 16);
            sm.w = (uint32_t)f2bf(fmaxf(h6, n6)) | ((uint32_t)f2bf(fmaxf(h7, n7)) << 16);
            *reinterpret_cast<uint4*>(mx + (size_t)d * HD + f0) = sm;
        }
    }
}

// ---------------------------------------------------------------- launch

extern "C" void kernel_launch(void* const* d_in, const int* in_sizes, int n_in,
                              void* d_out, int out_size, void* d_ws, size_t ws_size,
                              hipStream_t stream) {
    const float* x        = (const float*)d_in[0];          // [NN][FIN]
    const int*   ei       = (const int*)d_in[1];            // [2][NE]
    const float* ew       = (const float*)d_in[2];          // [NE]
    /* d_in[3] = numNode scalar = NN */
    const float* Wlin     = (const float*)d_in[4];          // [FIN][HD]
    const float* blin     = (const float*)d_in[5];          // [HD]
    const float* Wc       = (const float*)d_in[6];          // [3][HD][HD]
    const float* att_src  = (const float*)d_in[7];          // [3][HD]
    const float* att_dst  = (const float*)d_in[8];          // [3][HD]
    const float* bias_c   = (const float*)d_in[9];          // [3][HD]
    float* out = (float*)d_out;                              // [NN][HD]

    const int* src = ei;
    const int* dst = ei + NE;

    // workspace layout (16B-aligned blocks, ~44 MB)
    char* w = (char*)d_ws;
    ushort* hb      = (ushort*)w;  w += (size_t)NN * HD * 2;   // h residual (bf16)
    unsigned char* hp8 = (unsigned char*)w; w += (size_t)NN * HD; // hp (uint8 scaled)
    float2* asig    = (float2*)w;  w += (size_t)NN * 8;        // {as-dot, scale}
    ushort* mx      = (ushort*)w;  w += (size_t)NN * HD * 2;   // running max (bf16)
    float*  ad_     = (float*)w;   w += (size_t)NN * 4;
    int*    row_ptr = (int*)w;     w += (size_t)(NN + 4) * 4;
    unsigned int* cw = (unsigned int*)w; w += (size_t)NE * 4;  // packed col|bf16(ew)
    uint2*  epk     = (uint2*)w;   w += (size_t)NE * 8;
    int*    bhist   = (int*)w;     w += (size_t)NBK * NCHP * 4;
    int*    bbeg    = (int*)w;     w += (size_t)(NBK + 4) * 4;
    ushort* WTh     = (ushort*)w;  w += (size_t)NSPLIT * 2;
    ushort* WTl     = (ushort*)w;  w += (size_t)NSPLIT * 2;
    ushort* WlinTh = WTh,            *WlinTl = WTl;
    ushort* WcTh   = WTh + HD * FIN;

    const int TB = 256;
    const int nblk_w = NN / 16;                      // 3125 (16 nodes per block)
    const int nblk_g = NGP;                          // 391 (128 rows per block)

    // ---- fused: bhist || weight split ----
    k_pre<<<NCH + NSB, 1024, 0, stream>>>(dst, bhist, Wlin, Wc, WTh, WTl);

    // ---- bucket scan ----
    k_bscan<<<1, 256, 0, stream>>>(bhist, bbeg, row_ptr);

    // ---- fused: proj GEMM (h = x @ Wlin + blin) || binscatter ----
    k_gemmproj_scatter<<<NGP + NCH, TB, 0, stream>>>(
        x, WlinTh, WlinTl, blin, hb, src, dst, ew, bhist, epk, NN);

    // ---- per-bucket CSR finalize ----
    k_build<<<NBK, TB, 0, stream>>>(epk, bbeg, row_ptr, cw);

    // ---- 3 GAT layers ----
    for (int layer = 0; layer < 3; ++layer) {
        k_gemm_layer<<<nblk_g, TB, 0, stream>>>(
            hb, WcTh + (size_t)layer * HD * HD, hp8,
            att_src + layer * HD, att_dst + layer * HD, asig, ad_, NN);
        int mode = (layer == 0) ? 0 : (layer == 2 ? 2 : 1);
        k_agg<<<nblk_w, TB, 0, stream>>>(hp8, asig, hb, ad_, row_ptr, cw,
                                         bias_c + layer * HD, out, mx, mode);
    }
}

// Round 23
// 142.029 us; speedup vs baseline: 1.4895x; 1.0491x over previous
//
#include <hip/hip_runtime.h>
#include <cstdint>
#include <cstddef>

// Problem constants (from reference)
#define NN 50000
#define NE 800000
#define FIN 256
#define HD 128
#define NEG_SLOPE 0.2f

// CSR-build binning parameters
#define NBK 196          // buckets of 256 nodes: ceil(50000/256)
#define NCH 98           // edge chunks
#define NCHP 104         // padded chunk count (mult of 4 for int4 scan)
#define CHUNK 8192       // edges per chunk (98*8192 >= 800000)
#define NSPLIT (HD * FIN + 3 * HD * HD)   // 81920 weight elements
#define NSB 80           // split blocks at 1024 threads (81920/1024)
#define NGP 391          // proj/layer-GEMM blocks (128 rows each)

typedef short s16x8 __attribute__((ext_vector_type(8)));   // 8 bf16 (4 VGPRs)
typedef float f32x4 __attribute__((ext_vector_type(4)));   // MFMA acc / nt stores

__device__ inline ushort f2bf(float f) {                   // fp32 -> bf16 RTN-even
    uint32_t u = __float_as_uint(f);
    u += 0x7FFFu + ((u >> 16) & 1u);
    return (ushort)(u >> 16);
}
__device__ inline float bf2f(ushort h) {
    return __uint_as_float(((uint32_t)h) << 16);
}

// ------------------------------------------- fused bhist + weight split
// blocks [0, NCH): per-chunk LDS histogram of dst buckets -> bhist[bucket][chunk]
// blocks [NCH, NCH+NSB): weight transpose + bf16 hi/lo split (independent work)

__global__ __launch_bounds__(1024) void k_pre(const int* __restrict__ dst,
                                              int* __restrict__ bhist,
                                              const float* __restrict__ Wlin,
                                              const float* __restrict__ Wc,
                                              ushort* __restrict__ Th,
                                              ushort* __restrict__ Tl) {
    __shared__ int hist[NBK];
    const int tid = threadIdx.x;
    if (blockIdx.x < NCH) {
        const int blk = blockIdx.x;
        if (tid < NBK) hist[tid] = 0;
        __syncthreads();
        const int e0 = blk * CHUNK;
        #pragma unroll
        for (int u = 0; u < CHUNK / 1024; ++u) {
            int e = e0 + u * 1024 + tid;
            if (e < NE) atomicAdd(&hist[dst[e] >> 8], 1);
        }
        __syncthreads();
        if (tid < NBK) {
            bhist[tid * NCHP + blk] = hist[tid];
            if (blk == 0)                      // zero the scan padding once
                for (int c = NCH; c < NCHP; ++c) bhist[tid * NCHP + c] = 0;
        }
    } else {
        int idx = (blockIdx.x - NCH) * 1024 + tid;
        if (idx >= NSPLIT) return;
        const int NLIN = HD * FIN;
        float f;
        if (idx < NLIN) {
            int n = idx / FIN, k = idx - n * FIN;
            f = Wlin[(size_t)k * HD + n];
        } else {
            int r = idx - NLIN;
            int l = r / (HD * HD);
            int rr = r - l * (HD * HD);
            int n = rr / HD, k = rr - n * HD;
            f = Wc[(size_t)l * HD * HD + (size_t)k * HD + n];
        }
        ushort hi = f2bf(f);
        Th[idx] = hi;
        Tl[idx] = f2bf(f - bf2f(hi));
    }
}

__global__ __launch_bounds__(256) void k_bscan(int* __restrict__ bhist,
                                               int* __restrict__ bbeg,
                                               int* __restrict__ row_ptr) {
    __shared__ int wsum[4];
    const int tid = threadIdx.x;
    int4 buf[NCHP / 4];
    int tot = 0;
    if (tid < NBK) {
        const int4* rp = reinterpret_cast<const int4*>(bhist + tid * NCHP);
        #pragma unroll
        for (int u = 0; u < NCHP / 4; ++u) buf[u] = rp[u];     // independent loads
        #pragma unroll
        for (int u = 0; u < NCHP / 4; ++u) {                   // exclusive scan in regs
            int4 v = buf[u], o;
            o.x = tot; tot += v.x;
            o.y = tot; tot += v.y;
            o.z = tot; tot += v.z;
            o.w = tot; tot += v.w;
            buf[u] = o;
        }
    }
    const int lane = tid & 63, wid = tid >> 6;
    int x = tot;
    #pragma unroll
    for (int o = 1; o < 64; o <<= 1) {
        int t = __shfl_up(x, o);
        if (lane >= o) x += t;
    }
    if (lane == 63) wsum[wid] = x;
    __syncthreads();
    int wo = 0;
    for (int k = 0; k < wid; ++k) wo += wsum[k];
    const int excl = x - tot + wo;                // bucket start offset
    if (tid < NBK) {
        bbeg[tid] = excl;
        int4* rp = reinterpret_cast<int4*>(bhist + tid * NCHP);
        #pragma unroll
        for (int u = 0; u < NCHP / 4; ++u) {
            int4 v = buf[u];
            v.x += excl; v.y += excl; v.z += excl; v.w += excl;
            rp[u] = v;
        }
    }
    if (tid == 0) { bbeg[NBK] = NE; row_ptr[NN] = NE; }
}

// --------------------------- fused proj GEMM + binscatter (independent work)
// blocks [0, NGP): h = x @ Wlin + blin (K=256, fp32 A hi/lo split, weight
//   hi+lo terms, bf16 out). blocks [NGP, NGP+NCH): binscatter chunk.

__global__ __launch_bounds__(256) void k_gemmproj_scatter(
    const float*  __restrict__ x,
    const ushort* __restrict__ Bh,     // WlinT hi [HD][FIN]
    const ushort* __restrict__ Bl,     // WlinT lo
    const float*  __restrict__ bias,   // blin
    ushort*       __restrict__ Cb,     // hb (bf16 out)
    const int*    __restrict__ src,
    const int*    __restrict__ dst,
    const float*  __restrict__ ew,
    const int*    __restrict__ bhist,
    uint2*        __restrict__ epk,
    int M)
{
    __shared__ ushort Bs[32768];                  // 64 KB (GEMM); scatter reuses
    const int tid = threadIdx.x;

    if (blockIdx.x < NGP) {
        // ---------------- proj GEMM block ----------------
        constexpr int K = FIN, BK = 128;
        const int lane = tid & 63;
        const int wid  = tid >> 6;
        const int fl   = lane & 15;
        const int fg   = lane >> 4;
        const int rowBase = blockIdx.x * 128 + wid * 32;

        f32x4 acc[2][8] = {};

        for (int t = 0; t < K / BK; ++t) {
            if (t) __syncthreads();
            #pragma unroll
            for (int u = 0; u < 8; ++u) {
                const int id  = u * 256 + tid;
                const int bcol = id >> 4, c = id & 15;
                const size_t g = (size_t)bcol * K + t * BK + c * 8;
                const int lidx = bcol * 128 + ((c ^ (bcol & 15)) << 3);
                *reinterpret_cast<uint4*>(&Bs[lidx]) =
                    *reinterpret_cast<const uint4*>(Bh + g);
                *reinterpret_cast<uint4*>(&Bs[16384 + lidx]) =
                    *reinterpret_cast<const uint4*>(Bl + g);
            }
            __syncthreads();

            #pragma unroll
            for (int kt = 0; kt < BK / 32; ++kt) {
                s16x8 a_h[2], a_l[2];
                #pragma unroll
                for (int rt = 0; rt < 2; ++rt) {
                    int r = rowBase + rt * 16 + fl;
                    if (r >= M) r = M - 1;        // harmless clamp (stores guarded)
                    const float* ap = x + (size_t)r * K + t * BK + kt * 32 + fg * 8;
                    float4 t0 = *reinterpret_cast<const float4*>(ap);
                    float4 t1 = *reinterpret_cast<const float4*>(ap + 4);
                    float v[8] = {t0.x, t0.y, t0.z, t0.w, t1.x, t1.y, t1.z, t1.w};
                    #pragma unroll
                    for (int u = 0; u < 8; ++u) {
                        ushort h0 = f2bf(v[u]);
                        a_h[rt][u] = (short)h0;
                        a_l[rt][u] = (short)f2bf(v[u] - bf2f(h0));
                    }
                }
                #pragma unroll
                for (int ct = 0; ct < 8; ++ct) {
                    const int lidx = (ct * 16 + fl) * 128 + (((kt * 4 + fg) ^ fl) << 3);
                    s16x8 b_h = *reinterpret_cast<const s16x8*>(&Bs[lidx]);
                    s16x8 b_l = *reinterpret_cast<const s16x8*>(&Bs[16384 + lidx]);
                    #pragma unroll
                    for (int rt = 0; rt < 2; ++rt) {
                        acc[rt][ct] = __builtin_amdgcn_mfma_f32_16x16x32_bf16(a_h[rt], b_h, acc[rt][ct], 0, 0, 0);
                        acc[rt][ct] = __builtin_amdgcn_mfma_f32_16x16x32_bf16(a_h[rt], b_l, acc[rt][ct], 0, 0, 0);
                        acc[rt][ct] = __builtin_amdgcn_mfma_f32_16x16x32_bf16(a_l[rt], b_h, acc[rt][ct], 0, 0, 0);
                    }
                }
            }
        }

        float bval[8];
        #pragma unroll
        for (int ct = 0; ct < 8; ++ct) bval[ct] = bias[ct * 16 + fl];
        #pragma unroll
        for (int rt = 0; rt < 2; ++rt) {
            const int rbase = rowBase + rt * 16 + fg * 4;
            #pragma unroll
            for (int r = 0; r < 4; ++r) {
                const int row = rbase + r;
                if (row >= M) continue;
                #pragma unroll
                for (int ct = 0; ct < 8; ++ct)
                    Cb[(size_t)row * HD + ct * 16 + fl] = f2bf(acc[rt][ct][r] + bval[ct]);
            }
        }
    } else {
        // ---------------- binscatter chunk ----------------
        int* base = reinterpret_cast<int*>(Bs);          // [NBK]
        int* lcur = reinterpret_cast<int*>(Bs) + NBK;    // [NBK]
        const int blk = blockIdx.x - NGP;
        if (tid < NBK) { base[tid] = bhist[tid * NCHP + blk]; lcur[tid] = 0; }
        __syncthreads();
        const int e0 = blk * CHUNK;
        #pragma unroll
        for (int u = 0; u < CHUNK / 256; ++u) {
            int e = e0 + u * 256 + tid;
            if (e < NE) {
                int d = dst[e];
                int s = src[e];
                float w = ew[e];
                int b = d >> 8;
                int pos = base[b] + atomicAdd(&lcur[b], 1);   // LDS atomic only
                epk[pos] = make_uint2((uint32_t)s | ((uint32_t)(d & 255) << 16),
                                      __float_as_uint(w));
            }
        }
    }
}

// ---------------- fused CSR finalize + layer GEMM (independent work) ----
// blocks [0, NBK): per-bucket node counts + scan -> row_ptr, then packed
//   cw scatter (LDS cursors carved from the GEMM's shared buffer).
// blocks [NBK, NBK+NGP): layer GEMM (A bf16 exact, W pure bf16, 1 MFMA
//   term; uint8 per-row-scaled out + asig/ad_ epilogue).

__global__ __launch_bounds__(256) void k_build_gemm(
    const uint2*  __restrict__ epk,
    const int*    __restrict__ bbeg,
    int*          __restrict__ row_ptr,
    unsigned int* __restrict__ cw,
    const ushort* __restrict__ Ab,     // bf16 A (hb)
    const ushort* __restrict__ Bh,     // [HD][HD] layer weights
    unsigned char* __restrict__ C8,    // uint8 out
    const float*  __restrict__ att_s, const float* __restrict__ att_d,
    float2* __restrict__ asig,
    float*  __restrict__ ad_,
    int M)
{
    __shared__ ushort Bs[16384];                  // 32 KB (GEMM); build reuses
    const int tid = threadIdx.x;

    if (blockIdx.x < NBK) {
        // ---------------- CSR finalize bucket ----------------
        int* cnt   = reinterpret_cast<int*>(Bs);           // [256]
        int* cur   = reinterpret_cast<int*>(Bs) + 256;     // [256]
        int* wsum4 = reinterpret_cast<int*>(Bs) + 512;     // [4]
        const int b = blockIdx.x;
        const int n0 = b << 8;
        const int ebeg = bbeg[b], eend = bbeg[b + 1];
        cnt[tid] = 0;
        __syncthreads();
        for (int e = ebeg + tid; e < eend; e += 256)
            atomicAdd(&cnt[(epk[e].x >> 16) & 255], 1);
        __syncthreads();
        const int v = cnt[tid];
        const int lane = tid & 63, wid = tid >> 6;
        int x = v;
        #pragma unroll
        for (int o = 1; o < 64; o <<= 1) {
            int t = __shfl_up(x, o);
            if (lane >= o) x += t;
        }
        if (lane == 63) wsum4[wid] = x;
        __syncthreads();
        int wo = 0;
        for (int k = 0; k < wid; ++k) wo += wsum4[k];
        const int excl = ebeg + x - v + wo;       // node segment start
        if (n0 + tid < NN) row_ptr[n0 + tid] = excl;
        cur[tid] = excl;
        __syncthreads();
        for (int e = ebeg + tid; e < eend; e += 256) {
            uint2 p = epk[e];
            int dl = (p.x >> 16) & 255;
            int pos = atomicAdd(&cur[dl], 1);
            // packed edge: low16 = src, high16 = bf16(edge_weight)
            cw[pos] = (p.x & 0xFFFFu) |
                      ((unsigned int)f2bf(__uint_as_float(p.y)) << 16);
        }
    } else {
        // ---------------- layer GEMM block ----------------
        constexpr int K = HD;
        const int lane = tid & 63;
        const int wid  = tid >> 6;
        const int fl   = lane & 15;
        const int fg   = lane >> 4;
        const int rowBase = (blockIdx.x - NBK) * 128 + wid * 32;

        f32x4 acc[2][8] = {};

        #pragma unroll
        for (int u = 0; u < 8; ++u) {
            const int id  = u * 256 + tid;
            const int bcol = id >> 4, c = id & 15;
            const size_t g = (size_t)bcol * K + c * 8;
            const int lidx = bcol * 128 + ((c ^ (bcol & 15)) << 3);
            *reinterpret_cast<uint4*>(&Bs[lidx]) =
                *reinterpret_cast<const uint4*>(Bh + g);
        }
        __syncthreads();

        #pragma unroll
        for (int kt = 0; kt < 4; ++kt) {
            s16x8 a_h[2];
            #pragma unroll
            for (int rt = 0; rt < 2; ++rt) {
                int r = rowBase + rt * 16 + fl;
                if (r >= M) r = M - 1;            // harmless clamp (stores guarded)
                a_h[rt] = *reinterpret_cast<const s16x8*>(
                    Ab + (size_t)r * K + kt * 32 + fg * 8);
            }
            #pragma unroll
            for (int ct = 0; ct < 8; ++ct) {
                const int lidx = (ct * 16 + fl) * 128 + (((kt * 4 + fg) ^ fl) << 3);
                s16x8 b_h = *reinterpret_cast<const s16x8*>(&Bs[lidx]);
                #pragma unroll
                for (int rt = 0; rt < 2; ++rt)
                    acc[rt][ct] = __builtin_amdgcn_mfma_f32_16x16x32_bf16(a_h[rt], b_h, acc[rt][ct], 0, 0, 0);
            }
        }

        float asv[8], adv[8];
        #pragma unroll
        for (int ct = 0; ct < 8; ++ct) {
            asv[ct] = att_s[ct * 16 + fl];
            adv[ct] = att_d[ct * 16 + fl];
        }

        #pragma unroll
        for (int rt = 0; rt < 2; ++rt) {
            const int rbase = rowBase + rt * 16 + fg * 4;
            #pragma unroll
            for (int r = 0; r < 4; ++r) {
                const int row = rbase + r;
                const bool ok = row < M;
                float sv = 0.f, dv = 0.f, m = 0.f;
                float val[8];
                #pragma unroll
                for (int ct = 0; ct < 8; ++ct) {
                    val[ct] = acc[rt][ct][r];
                    sv = fmaf(val[ct], asv[ct], sv);
                    dv = fmaf(val[ct], adv[ct], dv);
                    m = fmaxf(m, fabsf(val[ct]));
                }
                #pragma unroll
                for (int o = 1; o < 16; o <<= 1) m = fmaxf(m, __shfl_xor(m, o));
                const float qs = 127.f / fmaxf(m, 1e-30f);
                #pragma unroll
                for (int ct = 0; ct < 8; ++ct) {
                    int qv = (int)rintf(val[ct] * qs);
                    qv = qv < -127 ? -127 : (qv > 127 ? 127 : qv);
                    if (ok) C8[(size_t)row * HD + ct * 16 + fl] =
                        (unsigned char)(qv + 128);           // biased uint8
                }
                #pragma unroll
                for (int o = 1; o < 16; o <<= 1) {
                    sv += __shfl_xor(sv, o);
                    dv += __shfl_xor(dv, o);
                }
                if (fl == 0 && ok) {
                    asig[row] = make_float2(sv, m * (1.f / 127.f));
                    ad_[row]  = dv;
                }
            }
        }
    }
}

// ----------------------------------------------------- standalone layer GEMM
// (layers 1 and 2: no concurrent CSR work left)

__global__ __launch_bounds__(256) void k_gemm_layer(
    const ushort* __restrict__ Ab,     // bf16 A (hb)
    const ushort* __restrict__ Bh,     // [HD][HD]
    unsigned char* __restrict__ C8,    // uint8 out
    const float*  __restrict__ att_s, const float* __restrict__ att_d,
    float2* __restrict__ asig,
    float*  __restrict__ ad_,
    int M)
{
    constexpr int K = HD;
    __shared__ ushort Bs[16384];                  // 32 KB

    const int tid  = threadIdx.x;
    const int lane = tid & 63;
    const int wid  = tid >> 6;
    const int fl   = lane & 15;
    const int fg   = lane >> 4;
    const int rowBase = blockIdx.x * 128 + wid * 32;

    f32x4 acc[2][8] = {};

    #pragma unroll
    for (int u = 0; u < 8; ++u) {
        const int id  = u * 256 + tid;
        const int bcol = id >> 4, c = id & 15;
        const size_t g = (size_t)bcol * K + c * 8;
        const int lidx = bcol * 128 + ((c ^ (bcol & 15)) << 3);
        *reinterpret_cast<uint4*>(&Bs[lidx]) =
            *reinterpret_cast<const uint4*>(Bh + g);
    }
    __syncthreads();

    #pragma unroll
    for (int kt = 0; kt < 4; ++kt) {
        s16x8 a_h[2];
        #pragma unroll
        for (int rt = 0; rt < 2; ++rt) {
            int r = rowBase + rt * 16 + fl;
            if (r >= M) r = M - 1;                // harmless clamp (stores guarded)
            a_h[rt] = *reinterpret_cast<const s16x8*>(
                Ab + (size_t)r * K + kt * 32 + fg * 8);
        }
        #pragma unroll
        for (int ct = 0; ct < 8; ++ct) {
            const int lidx = (ct * 16 + fl) * 128 + (((kt * 4 + fg) ^ fl) << 3);
            s16x8 b_h = *reinterpret_cast<const s16x8*>(&Bs[lidx]);
            #pragma unroll
            for (int rt = 0; rt < 2; ++rt)
                acc[rt][ct] = __builtin_amdgcn_mfma_f32_16x16x32_bf16(a_h[rt], b_h, acc[rt][ct], 0, 0, 0);
        }
    }

    float asv[8], adv[8];
    #pragma unroll
    for (int ct = 0; ct < 8; ++ct) {
        asv[ct] = att_s[ct * 16 + fl];
        adv[ct] = att_d[ct * 16 + fl];
    }

    #pragma unroll
    for (int rt = 0; rt < 2; ++rt) {
        const int rbase = rowBase + rt * 16 + fg * 4;
        #pragma unroll
        for (int r = 0; r < 4; ++r) {
            const int row = rbase + r;
            const bool ok = row < M;
            float sv = 0.f, dv = 0.f, m = 0.f;
            float val[8];
            #pragma unroll
            for (int ct = 0; ct < 8; ++ct) {
                val[ct] = acc[rt][ct][r];
                sv = fmaf(val[ct], asv[ct], sv);
                dv = fmaf(val[ct], adv[ct], dv);
                m = fmaxf(m, fabsf(val[ct]));
            }
            #pragma unroll
            for (int o = 1; o < 16; o <<= 1) m = fmaxf(m, __shfl_xor(m, o));
            const float qs = 127.f / fmaxf(m, 1e-30f);
            #pragma unroll
            for (int ct = 0; ct < 8; ++ct) {
                int qv = (int)rintf(val[ct] * qs);
                qv = qv < -127 ? -127 : (qv > 127 ? 127 : qv);
                if (ok) C8[(size_t)row * HD + ct * 16 + fl] =
                    (unsigned char)(qv + 128);               // biased uint8
            }
            #pragma unroll
            for (int o = 1; o < 16; o <<= 1) {
                sv += __shfl_xor(sv, o);
                dv += __shfl_xor(dv, o);
            }
            if (fl == 0 && ok) {
                asig[row] = make_float2(sv, m * (1.f / 127.f));
                ad_[row]  = dv;
            }
        }
    }
}

// ---------------------------------------------- fused softmax-aggregation
// One node per 16-LANE GROUP (4 nodes/wave). All 16 lanes of a group process
// every edge of their node (lane = feature octet) -> feature accumulators
// need no cross-lane folds; only dloc folds (4 shfls). Weight phase is
// lane-parallel over 16-edge passes; (s<<7, we) staged in wave-private LDS;
// 8 edges per batch in flight, edge count rounded up (zero slots = 0).
// hp uint8 per-row-scaled biased +128 (bias removed via 128*sum(we)).
// mode 0: h += agg (no out). mode 1: mx = bf16(max(h_old, h_new)), h += agg.
// mode 2: out = max(bf2f(mx), agg + b), nontemporal write-only out.

__device__ inline void acc8u(float wj, uint2 pv,
                             float& a0, float& a1, float& a2, float& a3,
                             float& a4, float& a5, float& a6, float& a7) {
    a0 = fmaf(wj, (float)( pv.x        & 0xFFu), a0);   // v_cvt_f32_ubyte0
    a1 = fmaf(wj, (float)((pv.x >>  8) & 0xFFu), a1);
    a2 = fmaf(wj, (float)((pv.x >> 16) & 0xFFu), a2);
    a3 = fmaf(wj, (float)( pv.x >> 24         ), a3);
    a4 = fmaf(wj, (float)( pv.y        & 0xFFu), a4);
    a5 = fmaf(wj, (float)((pv.y >>  8) & 0xFFu), a5);
    a6 = fmaf(wj, (float)((pv.y >> 16) & 0xFFu), a6);
    a7 = fmaf(wj, (float)( pv.y >> 24         ), a7);
}

__global__ __launch_bounds__(256) void k_agg(const unsigned char* __restrict__ hp8,
                                             const float2* __restrict__ asig,
                                             ushort* __restrict__ hb,
                                             const float* __restrict__ ad_,
                                             const int* __restrict__ row_ptr,
                                             const unsigned int* __restrict__ cw,
                                             const float* __restrict__ bias,
                                             float* __restrict__ out,
                                             ushort* __restrict__ mx, int mode) {
    __shared__ uint2 swb[4][64];       // per-wave staging: [wave][group*16+slot]
    const int wid  = threadIdx.x >> 6;
    const int lane = threadIdx.x & 63;
    const int g    = lane >> 4;        // group = node slot within wave
    const int hl   = lane & 15;        // feature octet within node row
    const int d    = blockIdx.x * 16 + wid * 4 + g;   // grid 3125 * 16 = NN exact
    const int beg = row_ptr[d], end = row_ptr[d + 1];
    const float adv = ad_[d];
    const int hlo = hl << 3;           // loop-invariant byte offset
    const int sb  = g << 4;            // group staging base

    float a0 = 0.f, a1 = 0.f, a2 = 0.f, a3 = 0.f;
    float a4 = 0.f, a5 = 0.f, a6 = 0.f, a7 = 0.f;
    float dloc = 0.f, wesum = 0.f;

    for (int base = beg; base < end; base += 16) {
        const int n = min(16, end - base);
        // ---- lane-parallel weight phase (one edge per lane) ----
        unsigned soff = 0; float w = 0.f, we = 0.f;
        if (hl < n) {
            unsigned int v = cw[base + hl];
            unsigned s = v & 0xFFFFu;
            float2 ag = asig[s];                   // {as-dot, row scale}
            float l = ag.x + adv;
            l = (l >= 0.f) ? l : NEG_SLOPE * l;
            l = fminf(l, 80.f);                    // overflow guard (no max pass)
            w  = __expf(l) * bf2f((ushort)(v >> 16));
            we = w * ag.y;                         // fold row scale into weight
            soff = s << 7;                         // byte offset of row
        }
        dloc += w;
        swb[wid][sb + hl] = make_uint2(soff, __float_as_uint(we));
        // zero-filled slots (hl >= n) contribute exactly 0 below

        const int nr = (n > 8) ? 16 : 8;           // round up: no tail branches
        for (int i = 0; i < nr; i += 8) {          // 8 edges in flight
            uint2 sw[8]; uint2 pv[8];
            #pragma unroll
            for (int j = 0; j < 8; ++j)
                sw[j] = swb[wid][sb + i + j];      // 16-lane broadcast read
            #pragma unroll
            for (int j = 0; j < 8; ++j)
                pv[j] = *reinterpret_cast<const uint2*>(hp8 + sw[j].x + hlo);
            #pragma unroll
            for (int j = 0; j < 8; ++j) {
                const float wj = __uint_as_float(sw[j].y);
                acc8u(wj, pv[j], a0, a1, a2, a3, a4, a5, a6, a7);
                wesum += wj;
            }
        }
    }
    // dloc: fold within the 16-lane group (weight phase was lane-parallel)
    #pragma unroll
    for (int o = 1; o < 16; o <<= 1) dloc += __shfl_xor(dloc, o);
    // a0..a7 and wesum are already complete per lane (broadcast accumulation)

    const float c = 128.f * wesum;             // remove the +128 bias exactly
    const float inv = 1.f / (dloc + 1e-16f);
    const int f0 = hl * 8;
    float r0 = (a0 - c) * inv + bias[f0 + 0], r1 = (a1 - c) * inv + bias[f0 + 1];
    float r2 = (a2 - c) * inv + bias[f0 + 2], r3 = (a3 - c) * inv + bias[f0 + 3];
    float r4 = (a4 - c) * inv + bias[f0 + 4], r5 = (a5 - c) * inv + bias[f0 + 5];
    float r6 = (a6 - c) * inv + bias[f0 + 6], r7 = (a7 - c) * inv + bias[f0 + 7];

    if (mode == 2) {
        uint4 mv = *reinterpret_cast<const uint4*>(mx + (size_t)d * HD + f0);
        f32x4 o0, o1;
        o0[0] = fmaxf(bf2f((ushort)mv.x),         r0);
        o0[1] = fmaxf(bf2f((ushort)(mv.x >> 16)), r1);
        o0[2] = fmaxf(bf2f((ushort)mv.y),         r2);
        o0[3] = fmaxf(bf2f((ushort)(mv.y >> 16)), r3);
        o1[0] = fmaxf(bf2f((ushort)mv.z),         r4);
        o1[1] = fmaxf(bf2f((ushort)(mv.z >> 16)), r5);
        o1[2] = fmaxf(bf2f((ushort)mv.w),         r6);
        o1[3] = fmaxf(bf2f((ushort)(mv.w >> 16)), r7);
        f32x4* outp = reinterpret_cast<f32x4*>(out + (size_t)d * HD + f0);
        __builtin_nontemporal_store(o0, outp);       // write-only final output:
        __builtin_nontemporal_store(o1, outp + 1);   // don't pollute L2
    } else {
        uint4* hp = reinterpret_cast<uint4*>(hb + (size_t)d * HD + f0);
        uint4 hv = *hp;
        float h0 = bf2f((ushort)hv.x), h1 = bf2f((ushort)(hv.x >> 16));
        float h2 = bf2f((ushort)hv.y), h3 = bf2f((ushort)(hv.y >> 16));
        float h4 = bf2f((ushort)hv.z), h5 = bf2f((ushort)(hv.z >> 16));
        float h6 = bf2f((ushort)hv.w), h7 = bf2f((ushort)(hv.w >> 16));
        float n0 = h0 + r0, n1 = h1 + r1, n2 = h2 + r2, n3 = h3 + r3;
        float n4 = h4 + r4, n5 = h5 + r5, n6 = h6 + r6, n7 = h7 + r7;
        uint4 st;
        st.x = (uint32_t)f2bf(n0) | ((uint32_t)f2bf(n1) << 16);
        st.y = (uint32_t)f2bf(n2) | ((uint32_t)f2bf(n3) << 16);
        st.z = (uint32_t)f2bf(n4) | ((uint32_t)f2bf(n5) << 16);
        st.w = (uint32_t)f2bf(n6) | ((uint32_t)f2bf(n7) << 16);
        *hp = st;
        if (mode == 1) {                        // mx = bf16(max(h1, h2))
            uint4 sm;
            sm.x = (uint32_t)f2bf(fmaxf(h0, n0)) | ((uint32_t)f2bf(fmaxf(h1, n1)) << 16);
            sm.y = (uint32_t)f2bf(fmaxf(h2, n2)) | ((uint32_t)f2bf(fmaxf(h3, n3)) << 16);
            sm.z = (uint32_t)f2bf(fmaxf(h4, n4)) | ((uint32_t)f2bf(fmaxf(h5, n5)) << 16);
            sm.w = (uint32_t)f2bf(fmaxf(h6, n6)) | ((uint32_t)f2bf(fmaxf(h7, n7)) << 16);
            *reinterpret_cast<uint4*>(mx + (size_t)d * HD + f0) = sm;
        }
    }
}

// ---------------------------------------------------------------- launch

extern "C" void kernel_launch(void* const* d_in, const int* in_sizes, int n_in,
                              void* d_out, int out_size, void* d_ws, size_t ws_size,
                              hipStream_t stream) {
    const float* x        = (const float*)d_in[0];          // [NN][FIN]
    const int*   ei       = (const int*)d_in[1];            // [2][NE]
    const float* ew       = (const float*)d_in[2];          // [NE]
    /* d_in[3] = numNode scalar = NN */
    const float* Wlin     = (const float*)d_in[4];          // [FIN][HD]
    const float* blin     = (const float*)d_in[5];          // [HD]
    const float* Wc       = (const float*)d_in[6];          // [3][HD][HD]
    const float* att_src  = (const float*)d_in[7];          // [3][HD]
    const float* att_dst  = (const float*)d_in[8];          // [3][HD]
    const float* bias_c   = (const float*)d_in[9];          // [3][HD]
    float* out = (float*)d_out;                              // [NN][HD]

    const int* src = ei;
    const int* dst = ei + NE;

    // workspace layout (16B-aligned blocks, ~44 MB)
    char* w = (char*)d_ws;
    ushort* hb      = (ushort*)w;  w += (size_t)NN * HD * 2;   // h residual (bf16)
    unsigned char* hp8 = (unsigned char*)w; w += (size_t)NN * HD; // hp (uint8 scaled)
    float2* asig    = (float2*)w;  w += (size_t)NN * 8;        // {as-dot, scale}
    ushort* mx      = (ushort*)w;  w += (size_t)NN * HD * 2;   // running max (bf16)
    float*  ad_     = (float*)w;   w += (size_t)NN * 4;
    int*    row_ptr = (int*)w;     w += (size_t)(NN + 4) * 4;
    unsigned int* cw = (unsigned int*)w; w += (size_t)NE * 4;  // packed col|bf16(ew)
    uint2*  epk     = (uint2*)w;   w += (size_t)NE * 8;
    int*    bhist   = (int*)w;     w += (size_t)NBK * NCHP * 4;
    int*    bbeg    = (int*)w;     w += (size_t)(NBK + 4) * 4;
    ushort* WTh     = (ushort*)w;  w += (size_t)NSPLIT * 2;
    ushort* WTl     = (ushort*)w;  w += (size_t)NSPLIT * 2;
    ushort* WlinTh = WTh,            *WlinTl = WTl;
    ushort* WcTh   = WTh + HD * FIN;

    const int TB = 256;
    const int nblk_w = NN / 16;                      // 3125 (16 nodes per block)

    // ---- fused: bhist || weight split ----
    k_pre<<<NCH + NSB, 1024, 0, stream>>>(dst, bhist, Wlin, Wc, WTh, WTl);

    // ---- bucket scan ----
    k_bscan<<<1, 256, 0, stream>>>(bhist, bbeg, row_ptr);

    // ---- fused: proj GEMM (h = x @ Wlin + blin) || binscatter ----
    k_gemmproj_scatter<<<NGP + NCH, TB, 0, stream>>>(
        x, WlinTh, WlinTl, blin, hb, src, dst, ew, bhist, epk, NN);

    // ---- fused: CSR finalize || layer-0 GEMM (independent) ----
    k_build_gemm<<<NBK + NGP, TB, 0, stream>>>(
        epk, bbeg, row_ptr, cw,
        hb, WcTh, hp8, att_src, att_dst, asig, ad_, NN);
    k_agg<<<nblk_w, TB, 0, stream>>>(hp8, asig, hb, ad_, row_ptr, cw,
                                     bias_c, out, mx, 0);

    // ---- layers 1, 2 ----
    for (int layer = 1; layer < 3; ++layer) {
        k_gemm_layer<<<NGP, TB, 0, stream>>>(
            hb, WcTh + (size_t)layer * HD * HD, hp8,
            att_src + layer * HD, att_dst + layer * HD, asig, ad_, NN);
        int mode = (layer == 2) ? 2 : 1;
        k_agg<<<nblk_w, TB, 0, stream>>>(hp8, asig, hb, ad_, row_ptr, cw,
                                         bias_c + layer * HD, out, mx, mode);
    }
}